// Round 1
// baseline (1108.657 us; speedup 1.0000x reference)
//
#include <hip/hip_runtime.h>
#include <math.h>

#define BB   16
#define CIN  16
#define LL   1024
#define DD   128
#define NHH  8
#define DHH  16
#define DF   512

#define INVS 0.9999950000374998f   // 1/sqrt(1+1e-5)

__device__ __forceinline__ float geluf(float v) {
    return 0.5f * v * (1.0f + erff(v * 0.70710678118654752440f));
}

// ---------- fused conv1+BN+GELU -> conv2 partial GEMM (K-split over o) ----------
__global__ __launch_bounds__(256) void k_conv(
    const float* __restrict__ x,   const float* __restrict__ w1,
    const float* __restrict__ c1b, const float* __restrict__ g1,
    const float* __restrict__ bb1, const float* __restrict__ w2,
    float* __restrict__ part)
{
    const int lt = blockIdx.x;      // 8 tiles of 128 l
    const int b  = blockIdx.y;      // 16
    const int oh = blockIdx.z;      // 2  (o-halves of 256)
    const int t  = threadIdx.x;
    const int l0 = lt * 128;

    __shared__ float xs[CIN][136];
    __shared__ float w1s[DF][8];
    __shared__ float abA[DF];
    __shared__ float abB[DF];
    __shared__ float h1c[CIN][132];
    __shared__ float w2t[CIN][132];

    for (int idx = t; idx < CIN * 134; idx += 256) {
        int c = idx / 134, i = idx % 134;
        int l = l0 - 3 + i;
        xs[c][i] = (l >= 0 && l < LL) ? x[(b * CIN + c) * LL + l] : 0.0f;
    }
    for (int idx = t; idx < DF * 7; idx += 256)
        w1s[idx / 7][idx % 7] = w1[idx];
    for (int o = t; o < DF; o += 256) {
        float A = g1[o] * INVS;
        abA[o] = A;
        abB[o] = c1b[o] * A + bb1[o];
    }
    __syncthreads();

    float acc[8][8];
    #pragma unroll
    for (int i = 0; i < 8; i++)
        #pragma unroll
        for (int j = 0; j < 8; j++) acc[i][j] = 0.0f;

    const int lg  = t >> 4, dg = t & 15;
    const int lth = lg * 8, dth = dg * 8;
    const int ca  = t >> 4;
    const int la  = (t & 15) * 8;

    for (int o = 0; o < 256; ++o) {
        const int og = oh * 256 + o;
        // phase A: h1 slice for channel og  (16 c x 128 l)
        {
            float xw[16];
            *(float4*)&xw[0]  = *(const float4*)&xs[ca][la];
            *(float4*)&xw[4]  = *(const float4*)&xs[ca][la + 4];
            *(float4*)&xw[8]  = *(const float4*)&xs[ca][la + 8];
            *(float4*)&xw[12] = *(const float4*)&xs[ca][la + 12];
            float wv[7];
            #pragma unroll
            for (int tp = 0; tp < 7; tp++) wv[tp] = w1s[og][tp];
            float A = abA[og], Bo = abB[og];
            float hv[8];
            #pragma unroll
            for (int j = 0; j < 8; j++) {
                float s = xw[j] * wv[0];
                #pragma unroll
                for (int tp = 1; tp < 7; tp++) s += xw[j + tp] * wv[tp];
                hv[j] = geluf(s * A + Bo);
            }
            *(float4*)&h1c[ca][la]     = *(float4*)&hv[0];
            *(float4*)&h1c[ca][la + 4] = *(float4*)&hv[4];
        }
        // phase B: stage w2[:, og, :] transposed -> w2t[c][d]
        {
            int d = t >> 1, c0 = (t & 1) * 8;
            const float* src = &w2[((size_t)d * DF + og) * CIN + c0];
            float4 v0 = *(const float4*)src;
            float4 v1 = *(const float4*)(src + 4);
            w2t[c0 + 0][d] = v0.x; w2t[c0 + 1][d] = v0.y;
            w2t[c0 + 2][d] = v0.z; w2t[c0 + 3][d] = v0.w;
            w2t[c0 + 4][d] = v1.x; w2t[c0 + 5][d] = v1.y;
            w2t[c0 + 6][d] = v1.z; w2t[c0 + 7][d] = v1.w;
        }
        __syncthreads();
        // phase C: rank-16 update of 128x128 tile (8x8 per thread)
        #pragma unroll
        for (int c = 0; c < CIN; c++) {
            float hv[8], wv2[8];
            *(float4*)&hv[0]  = *(const float4*)&h1c[c][lth];
            *(float4*)&hv[4]  = *(const float4*)&h1c[c][lth + 4];
            *(float4*)&wv2[0] = *(const float4*)&w2t[c][dth];
            *(float4*)&wv2[4] = *(const float4*)&w2t[c][dth + 4];
            #pragma unroll
            for (int i = 0; i < 8; i++)
                #pragma unroll
                for (int j = 0; j < 8; j++)
                    acc[i][j] += hv[i] * wv2[j];
        }
        __syncthreads();
    }
    float* pp = part + (size_t)oh * (BB * LL * DD);
    #pragma unroll
    for (int i = 0; i < 8; i++) {
        float* dst = &pp[((size_t)b * LL + l0 + lth + i) * DD + dth];
        float4 o0 = {acc[i][0], acc[i][1], acc[i][2], acc[i][3]};
        float4 o1 = {acc[i][4], acc[i][5], acc[i][6], acc[i][7]};
        *(float4*)dst = o0;
        *(float4*)(dst + 4) = o1;
    }
}

// ---------- combine K-split partials + bias + BN + GELU -> x_src ----------
__global__ __launch_bounds__(256) void k_convfin(
    const float* __restrict__ part, const float* __restrict__ c2b,
    const float* __restrict__ g2,   const float* __restrict__ bb2,
    float* __restrict__ xsrc)
{
    size_t i = ((size_t)blockIdx.x * 256 + threadIdx.x) * 4;
    if (i >= (size_t)BB * LL * DD) return;
    int d0 = (int)(i & (DD - 1));
    float4 p0 = *(const float4*)&part[i];
    float4 p1 = *(const float4*)&part[(size_t)BB * LL * DD + i];
    float4 gv = *(const float4*)&g2[d0];
    float4 cb = *(const float4*)&c2b[d0];
    float4 bv = *(const float4*)&bb2[d0];
    float pv[4] = {p0.x + p1.x, p0.y + p1.y, p0.z + p1.z, p0.w + p1.w};
    float gg[4] = {gv.x, gv.y, gv.z, gv.w};
    float cc[4] = {cb.x, cb.y, cb.z, cb.w};
    float bb_[4] = {bv.x, bv.y, bv.z, bv.w};
    float r[4];
    #pragma unroll
    for (int j = 0; j < 4; j++) {
        float A = gg[j] * INVS;
        r[j] = geluf(pv[j] * A + (cc[j] * A + bb_[j]));
    }
    float4 o = {r[0], r[1], r[2], r[3]};
    *(float4*)&xsrc[i] = o;
}

// ---------- x_pos = x_src + PE ; q/k/v = x_pos @ W^T  -> (B,H,L,16) ----------
__global__ __launch_bounds__(256) void k_qkv(
    const float* __restrict__ xsrc, const float* __restrict__ wq,
    const float* __restrict__ wk,   const float* __restrict__ wv,
    float* __restrict__ qo, float* __restrict__ ko, float* __restrict__ vo)
{
    const int lt = blockIdx.x, b = blockIdx.y, wsel = blockIdx.z;
    const int t = threadIdx.x;
    const int l0 = lt * 64;
    const float* w = (wsel == 0) ? wq : ((wsel == 1) ? wk : wv);
    float* out = (wsel == 0) ? qo : ((wsel == 1) ? ko : vo);

    __shared__ float xp[64][132];
    __shared__ float wt[16][132];

    #pragma unroll
    for (int u = 0; u < 8; u++) {
        int e = t * 8 + u;                 // f4 index, 2048 total
        int l = e >> 5, d0 = (e & 31) * 4;
        float4 xv = *(const float4*)&xsrc[((size_t)b * LL + l0 + l) * DD + d0];
        int j0 = d0 >> 1;
        float posf = (float)(l0 + l);
        float a0 = posf * expf(-0.14391156831212787f * (float)j0) * 0.125f;
        float a1 = posf * expf(-0.14391156831212787f * (float)(j0 + 1)) * 0.125f;
        xv.x += sinf(a0); xv.y += cosf(a0);
        xv.z += sinf(a1); xv.w += cosf(a1);
        *(float4*)&xp[l][d0] = xv;
    }
    __syncthreads();

    const int lg = t >> 4, dg = t & 15;
    const int lth = lg * 4, dth = dg * 8;
    float acc[4][8];
    #pragma unroll
    for (int i = 0; i < 4; i++)
        #pragma unroll
        for (int j = 0; j < 8; j++) acc[i][j] = 0.0f;

    for (int kc = 0; kc < 8; kc++) {
        {
            int d = t >> 1, kk0 = (t & 1) * 8;
            const float* src = &w[(size_t)d * DD + kc * 16 + kk0];
            float4 v0 = *(const float4*)src;
            float4 v1 = *(const float4*)(src + 4);
            wt[kk0 + 0][d] = v0.x; wt[kk0 + 1][d] = v0.y;
            wt[kk0 + 2][d] = v0.z; wt[kk0 + 3][d] = v0.w;
            wt[kk0 + 4][d] = v1.x; wt[kk0 + 5][d] = v1.y;
            wt[kk0 + 6][d] = v1.z; wt[kk0 + 7][d] = v1.w;
        }
        __syncthreads();
        #pragma unroll
        for (int kk = 0; kk < 16; kk++) {
            int k = kc * 16 + kk;
            float a0 = xp[lth + 0][k], a1 = xp[lth + 1][k];
            float a2 = xp[lth + 2][k], a3 = xp[lth + 3][k];
            float wvv[8];
            *(float4*)&wvv[0] = *(const float4*)&wt[kk][dth];
            *(float4*)&wvv[4] = *(const float4*)&wt[kk][dth + 4];
            #pragma unroll
            for (int j = 0; j < 8; j++) {
                acc[0][j] += a0 * wvv[j];
                acc[1][j] += a1 * wvv[j];
                acc[2][j] += a2 * wvv[j];
                acc[3][j] += a3 * wvv[j];
            }
        }
        __syncthreads();
    }
    int h = dth >> 4, dh0 = dth & 15;
    #pragma unroll
    for (int i = 0; i < 4; i++) {
        float* dst = &out[(((size_t)b * NHH + h) * LL + l0 + lth + i) * DHH + dh0];
        float4 o0 = {acc[i][0], acc[i][1], acc[i][2], acc[i][3]};
        float4 o1 = {acc[i][4], acc[i][5], acc[i][6], acc[i][7]};
        *(float4*)dst = o0;
        *(float4*)(dst + 4) = o1;
    }
}

// ---------- attention: softmax(QK^T*s)@V + relbias@V  (flash, 2 accumulators) ----------
__global__ __launch_bounds__(256) void k_attn(
    const float* __restrict__ q, const float* __restrict__ k,
    const float* __restrict__ v, const float* __restrict__ rel,
    float* __restrict__ out)
{
    const int qt = blockIdx.x;           // 16
    const int bh = blockIdx.y;           // 128
    const int h  = bh & 7;
    const int t  = threadIdx.x;
    const int q0 = qt * 64;

    __shared__ float qs[64][20];
    __shared__ float kst[16 * 160];      // (i, k): i*160 + (k>>4)*20 + (k&15)
    __shared__ float vst[8 * 324];       // (k, i): (k>>4)*324 + (k&15)*20 + i
    __shared__ float tbl[2048];

    const float scale = 0.08838834764831845f;  // 1/sqrt(128)

    for (int i = t; i < 2047; i += 256) tbl[i] = rel[(size_t)i * 8 + h];
    {
        int e = t * 4; int r = e >> 4, i0 = e & 15;
        float4 qv = *(const float4*)&q[((size_t)bh * LL + q0 + r) * DHH + i0];
        qv.x *= scale; qv.y *= scale; qv.z *= scale; qv.w *= scale;
        *(float4*)&qs[r][i0] = qv;
    }
    __syncthreads();

    const int rg = t >> 3, kg = t & 7;
    const int r0 = rg * 2;
    float qr[2][16];
    #pragma unroll
    for (int rr = 0; rr < 2; rr++)
        #pragma unroll
        for (int i = 0; i < 16; i += 4)
            *(float4*)&qr[rr][i] = *(const float4*)&qs[r0 + rr][i];

    float accp[2][16], accb[2][16];
    #pragma unroll
    for (int rr = 0; rr < 2; rr++)
        #pragma unroll
        for (int i = 0; i < 16; i++) { accp[rr][i] = 0.f; accb[rr][i] = 0.f; }
    float mrow[2] = {-INFINITY, -INFINITY};
    float lrow[2] = {0.f, 0.f};

    for (int kt = 0; kt < 8; kt++) {
        const int k0 = kt * 128;
        {
            int e = t * 8;
            int row = e >> 4, i0 = e & 15;       // i0 in {0,8}
            const float* kp = &k[((size_t)bh * LL + k0 + row) * DHH + i0];
            float4 a0 = *(const float4*)kp;
            float4 a1 = *(const float4*)(kp + 4);
            int blk = row >> 4, rr_ = row & 15;
            kst[(i0 + 0) * 160 + blk * 20 + rr_] = a0.x;
            kst[(i0 + 1) * 160 + blk * 20 + rr_] = a0.y;
            kst[(i0 + 2) * 160 + blk * 20 + rr_] = a0.z;
            kst[(i0 + 3) * 160 + blk * 20 + rr_] = a0.w;
            kst[(i0 + 4) * 160 + blk * 20 + rr_] = a1.x;
            kst[(i0 + 5) * 160 + blk * 20 + rr_] = a1.y;
            kst[(i0 + 6) * 160 + blk * 20 + rr_] = a1.z;
            kst[(i0 + 7) * 160 + blk * 20 + rr_] = a1.w;
            const float* vp = &v[((size_t)bh * LL + k0 + row) * DHH + i0];
            float4 b0 = *(const float4*)vp;
            float4 b1 = *(const float4*)(vp + 4);
            *(float4*)&vst[blk * 324 + rr_ * 20 + i0]     = b0;
            *(float4*)&vst[blk * 324 + rr_ * 20 + i0 + 4] = b1;
        }
        __syncthreads();

        float s[2][16];
        #pragma unroll
        for (int rr = 0; rr < 2; rr++)
            #pragma unroll
            for (int kk = 0; kk < 16; kk++) s[rr][kk] = 0.f;
        #pragma unroll
        for (int i = 0; i < 16; i++) {
            float kv[16];
            const float* base = &kst[i * 160 + kg * 20];
            *(float4*)&kv[0]  = *(const float4*)(base);
            *(float4*)&kv[4]  = *(const float4*)(base + 4);
            *(float4*)&kv[8]  = *(const float4*)(base + 8);
            *(float4*)&kv[12] = *(const float4*)(base + 12);
            #pragma unroll
            for (int kk = 0; kk < 16; kk++) {
                s[0][kk] += qr[0][i] * kv[kk];
                s[1][kk] += qr[1][i] * kv[kk];
            }
        }
        #pragma unroll
        for (int rr = 0; rr < 2; rr++) {
            float mt = s[rr][0];
            #pragma unroll
            for (int kk = 1; kk < 16; kk++) mt = fmaxf(mt, s[rr][kk]);
            mt = fmaxf(mt, __shfl_xor(mt, 1, 8));
            mt = fmaxf(mt, __shfl_xor(mt, 2, 8));
            mt = fmaxf(mt, __shfl_xor(mt, 4, 8));
            float mnew = fmaxf(mrow[rr], mt);
            float sf = __expf(mrow[rr] - mnew);
            mrow[rr] = mnew;
            lrow[rr] *= sf;
            #pragma unroll
            for (int i = 0; i < 16; i++) accp[rr][i] *= sf;
            float ls = 0.f;
            #pragma unroll
            for (int kk = 0; kk < 16; kk++) {
                float p = __expf(s[rr][kk] - mnew);
                s[rr][kk] = p;
                ls += p;
            }
            ls += __shfl_xor(ls, 1, 8);
            ls += __shfl_xor(ls, 2, 8);
            ls += __shfl_xor(ls, 4, 8);
            lrow[rr] += ls;
        }
        #pragma unroll
        for (int kk = 0; kk < 16; kk++) {
            int kidx = k0 + kg * 16 + kk;
            float vv[16];
            const float* vb = &vst[kg * 324 + kk * 20];
            *(float4*)&vv[0]  = *(const float4*)(vb);
            *(float4*)&vv[4]  = *(const float4*)(vb + 4);
            *(float4*)&vv[8]  = *(const float4*)(vb + 8);
            *(float4*)&vv[12] = *(const float4*)(vb + 12);
            float bc0 = tbl[q0 + r0     - kidx + 1023];
            float bc1 = tbl[q0 + r0 + 1 - kidx + 1023];
            float p0 = s[0][kk], p1 = s[1][kk];
            #pragma unroll
            for (int i = 0; i < 16; i++) {
                accp[0][i] += p0 * vv[i];
                accp[1][i] += p1 * vv[i];
                accb[0][i] += bc0 * vv[i];
                accb[1][i] += bc1 * vv[i];
            }
        }
        __syncthreads();
    }

    #pragma unroll
    for (int rr = 0; rr < 2; rr++) {
        float inv = 1.0f / lrow[rr];
        #pragma unroll
        for (int i = 0; i < 16; i++) {
            float a = accp[rr][i];
            a += __shfl_xor(a, 1, 8);
            a += __shfl_xor(a, 2, 8);
            a += __shfl_xor(a, 4, 8);
            float bs = accb[rr][i];
            bs += __shfl_xor(bs, 1, 8);
            bs += __shfl_xor(bs, 2, 8);
            bs += __shfl_xor(bs, 4, 8);
            accp[rr][i] = a * inv + bs;
        }
        float2 o = {accp[rr][kg * 2], accp[rr][kg * 2 + 1]};
        *(float2*)&out[((size_t)bh * LL + q0 + r0 + rr) * DHH + kg * 2] = o;
    }
}

// ---------- LN(attn_out) ; att = LN(x_src + .) ----------
__global__ __launch_bounds__(256) void k_ln(
    const float* __restrict__ ao,  const float* __restrict__ xsrc,
    const float* __restrict__ lag, const float* __restrict__ lab,
    const float* __restrict__ l1g, const float* __restrict__ l1b,
    float* __restrict__ att)
{
    const int lt = blockIdx.x, b = blockIdx.y;
    const int t = threadIdx.x;
    const int l0 = lt * 64;
    __shared__ float tile[64][132];

    #pragma unroll
    for (int u = 0; u < 4; u++) {
        int cid = u * 256 + t;               // 1024 chunks of 8
        int hh = cid >> 7, rem = cid & 127;
        int l = rem >> 1, dh0 = (rem & 1) * 8;
        const float* src = &ao[(((size_t)b * NHH + hh) * LL + l0 + l) * DHH + dh0];
        float4 a0 = *(const float4*)src;
        float4 a1 = *(const float4*)(src + 4);
        *(float4*)&tile[l][hh * 16 + dh0]     = a0;
        *(float4*)&tile[l][hh * 16 + dh0 + 4] = a1;
    }
    __syncthreads();

    const int wid = t >> 6, lane = t & 63;
    float2 ga  = *(const float2*)&lag[lane * 2];
    float2 ba  = *(const float2*)&lab[lane * 2];
    float2 g1v = *(const float2*)&l1g[lane * 2];
    float2 b1v = *(const float2*)&l1b[lane * 2];

    for (int rr = 0; rr < 16; rr++) {
        int r = wid * 16 + rr;
        float2 vv = *(const float2*)&tile[r][lane * 2];
        float s = vv.x + vv.y, s2 = vv.x * vv.x + vv.y * vv.y;
        #pragma unroll
        for (int m = 1; m < 64; m <<= 1) { s += __shfl_xor(s, m, 64); s2 += __shfl_xor(s2, m, 64); }
        float mu = s * (1.f / 128.f);
        float var = s2 * (1.f / 128.f) - mu * mu;
        float rs = rsqrtf(var + 1e-5f);
        float o0 = (vv.x - mu) * rs * ga.x + ba.x;
        float o1 = (vv.y - mu) * rs * ga.y + ba.y;
        float2 xv = *(const float2*)&xsrc[((size_t)b * LL + l0 + r) * DD + lane * 2];
        float t0 = xv.x + o0, t1 = xv.y + o1;
        s = t0 + t1; s2 = t0 * t0 + t1 * t1;
        #pragma unroll
        for (int m = 1; m < 64; m <<= 1) { s += __shfl_xor(s, m, 64); s2 += __shfl_xor(s2, m, 64); }
        mu = s * (1.f / 128.f);
        var = s2 * (1.f / 128.f) - mu * mu;
        rs = rsqrtf(var + 1e-5f);
        float a0 = (t0 - mu) * rs * g1v.x + b1v.x;
        float a1 = (t1 - mu) * rs * g1v.y + b1v.y;
        float2 o = {a0, a1};
        *(float2*)&att[((size_t)b * LL + l0 + r) * DD + lane * 2] = o;
    }
}

// ---------- ff1 = relu(att @ w1^T + b1) ----------
__global__ __launch_bounds__(256) void k_ff1(
    const float* __restrict__ att, const float* __restrict__ w1f,
    const float* __restrict__ b1f, float* __restrict__ ff1)
{
    const int lt = blockIdx.x, b = blockIdx.y, ng = blockIdx.z;
    const int l0 = lt * 64, n0 = ng * 128;
    const int t = threadIdx.x;
    __shared__ float xt[64][132];
    __shared__ float wt[16][132];

    #pragma unroll
    for (int u = 0; u < 8; u++) {
        int e = u * 256 + t;                  // 2048 f4
        int l = e >> 5, d0 = (e & 31) * 4;
        *(float4*)&xt[l][d0] = *(const float4*)&att[((size_t)b * LL + l0 + l) * DD + d0];
    }
    __syncthreads();

    const int lg = t >> 4, dg = t & 15;
    const int lth = lg * 4, nth = dg * 8;
    float acc[4][8];
    #pragma unroll
    for (int i = 0; i < 4; i++)
        #pragma unroll
        for (int j = 0; j < 8; j++) acc[i][j] = 0.0f;

    for (int kc = 0; kc < 8; kc++) {
        {
            int d = t >> 1, kk0 = (t & 1) * 8;
            const float* src = &w1f[(size_t)(n0 + d) * DD + kc * 16 + kk0];
            float4 v0 = *(const float4*)src;
            float4 v1 = *(const float4*)(src + 4);
            wt[kk0 + 0][d] = v0.x; wt[kk0 + 1][d] = v0.y;
            wt[kk0 + 2][d] = v0.z; wt[kk0 + 3][d] = v0.w;
            wt[kk0 + 4][d] = v1.x; wt[kk0 + 5][d] = v1.y;
            wt[kk0 + 6][d] = v1.z; wt[kk0 + 7][d] = v1.w;
        }
        __syncthreads();
        #pragma unroll
        for (int kk = 0; kk < 16; kk++) {
            int kx = kc * 16 + kk;
            float a0 = xt[lth + 0][kx], a1 = xt[lth + 1][kx];
            float a2 = xt[lth + 2][kx], a3 = xt[lth + 3][kx];
            float wvv[8];
            *(float4*)&wvv[0] = *(const float4*)&wt[kk][nth];
            *(float4*)&wvv[4] = *(const float4*)&wt[kk][nth + 4];
            #pragma unroll
            for (int j = 0; j < 8; j++) {
                acc[0][j] += a0 * wvv[j];
                acc[1][j] += a1 * wvv[j];
                acc[2][j] += a2 * wvv[j];
                acc[3][j] += a3 * wvv[j];
            }
        }
        __syncthreads();
    }
    float bvv[8];
    *(float4*)&bvv[0] = *(const float4*)&b1f[n0 + nth];
    *(float4*)&bvv[4] = *(const float4*)&b1f[n0 + nth + 4];
    #pragma unroll
    for (int i = 0; i < 4; i++) {
        float r[8];
        #pragma unroll
        for (int j = 0; j < 8; j++) r[j] = fmaxf(acc[i][j] + bvv[j], 0.0f);
        float* dst = &ff1[((size_t)b * LL + l0 + lth + i) * DF + n0 + nth];
        float4 o0 = {r[0], r[1], r[2], r[3]};
        float4 o1 = {r[4], r[5], r[6], r[7]};
        *(float4*)dst = o0;
        *(float4*)(dst + 4) = o1;
    }
}

// ---------- ff2 + residual + LN2 + transpose-store ----------
__global__ __launch_bounds__(256) void k_ff2(
    const float* __restrict__ ff1, const float* __restrict__ w2f,
    const float* __restrict__ b2f, const float* __restrict__ att,
    const float* __restrict__ l2g, const float* __restrict__ l2b,
    float* __restrict__ y)
{
    const int lt = blockIdx.x, b = blockIdx.y;
    const int l0 = lt * 64;
    const int t = threadIdx.x;
    __shared__ float fc[64][36];
    __shared__ float wt[32][132];
    __shared__ float yl[64][132];

    const int lg = t >> 4, dg = t & 15;
    const int lth = lg * 4, dth = dg * 8;
    float acc[4][8];
    #pragma unroll
    for (int i = 0; i < 4; i++)
        #pragma unroll
        for (int j = 0; j < 8; j++) acc[i][j] = 0.0f;

    for (int kc = 0; kc < 16; kc++) {
        {
            int l = t >> 2, k0 = (t & 3) * 8;
            const float* src = &ff1[((size_t)b * LL + l0 + l) * DF + kc * 32 + k0];
            float4 a0 = *(const float4*)src;
            float4 a1 = *(const float4*)(src + 4);
            *(float4*)&fc[l][k0]     = a0;
            *(float4*)&fc[l][k0 + 4] = a1;
        }
        {
            int d = t >> 1, kk0 = (t & 1) * 16;
            const float* src = &w2f[(size_t)d * DF + kc * 32 + kk0];
            float4 v0 = *(const float4*)src;
            float4 v1 = *(const float4*)(src + 4);
            float4 v2 = *(const float4*)(src + 8);
            float4 v3 = *(const float4*)(src + 12);
            wt[kk0 +  0][d] = v0.x; wt[kk0 +  1][d] = v0.y;
            wt[kk0 +  2][d] = v0.z; wt[kk0 +  3][d] = v0.w;
            wt[kk0 +  4][d] = v1.x; wt[kk0 +  5][d] = v1.y;
            wt[kk0 +  6][d] = v1.z; wt[kk0 +  7][d] = v1.w;
            wt[kk0 +  8][d] = v2.x; wt[kk0 +  9][d] = v2.y;
            wt[kk0 + 10][d] = v2.z; wt[kk0 + 11][d] = v2.w;
            wt[kk0 + 12][d] = v3.x; wt[kk0 + 13][d] = v3.y;
            wt[kk0 + 14][d] = v3.z; wt[kk0 + 15][d] = v3.w;
        }
        __syncthreads();
        #pragma unroll
        for (int kk = 0; kk < 32; kk++) {
            float a0 = fc[lth + 0][kk], a1 = fc[lth + 1][kk];
            float a2 = fc[lth + 2][kk], a3 = fc[lth + 3][kk];
            float wvv[8];
            *(float4*)&wvv[0] = *(const float4*)&wt[kk][dth];
            *(float4*)&wvv[4] = *(const float4*)&wt[kk][dth + 4];
            #pragma unroll
            for (int j = 0; j < 8; j++) {
                acc[0][j] += a0 * wvv[j];
                acc[1][j] += a1 * wvv[j];
                acc[2][j] += a2 * wvv[j];
                acc[3][j] += a3 * wvv[j];
            }
        }
        __syncthreads();
    }

    float bvv[8];
    *(float4*)&bvv[0] = *(const float4*)&b2f[dth];
    *(float4*)&bvv[4] = *(const float4*)&b2f[dth + 4];
    #pragma unroll
    for (int i = 0; i < 4; i++) {
        const float* ar = &att[((size_t)b * LL + l0 + lth + i) * DD + dth];
        float4 r0 = *(const float4*)ar;
        float4 r1 = *(const float4*)(ar + 4);
        float rv[8] = {r0.x, r0.y, r0.z, r0.w, r1.x, r1.y, r1.z, r1.w};
        #pragma unroll
        for (int j = 0; j < 8; j++)
            yl[lth + i][dth + j] = acc[i][j] + bvv[j] + rv[j];
    }
    __syncthreads();

    const int wid = t >> 6, lane = t & 63;
    float2 gv = *(const float2*)&l2g[lane * 2];
    float2 bv = *(const float2*)&l2b[lane * 2];
    for (int rr = 0; rr < 16; rr++) {
        int r = wid * 16 + rr;
        float2 vv = *(const float2*)&yl[r][lane * 2];
        float s = vv.x + vv.y, s2 = vv.x * vv.x + vv.y * vv.y;
        #pragma unroll
        for (int m = 1; m < 64; m <<= 1) { s += __shfl_xor(s, m, 64); s2 += __shfl_xor(s2, m, 64); }
        float mu = s * (1.f / 128.f);
        float var = s2 * (1.f / 128.f) - mu * mu;
        float rs = rsqrtf(var + 1e-5f);
        float o0 = (vv.x - mu) * rs * gv.x + bv.x;
        float o1 = (vv.y - mu) * rs * gv.y + bv.y;
        yl[r][lane * 2]     = o0;
        yl[r][lane * 2 + 1] = o1;
    }
    __syncthreads();

    {
        int d = t >> 1, lh = (t & 1) * 32;
        for (int i0 = 0; i0 < 32; i0 += 4) {
            float4 o = { yl[lh + i0 + 0][d], yl[lh + i0 + 1][d],
                         yl[lh + i0 + 2][d], yl[lh + i0 + 3][d] };
            *(float4*)&y[(size_t)b * DD * LL + (size_t)d * LL + l0 + lh + i0] = o;
        }
    }
}

extern "C" void kernel_launch(void* const* d_in, const int* in_sizes, int n_in,
                              void* d_out, int out_size, void* d_ws, size_t ws_size,
                              hipStream_t stream)
{
    const float* x   = (const float*)d_in[0];
    const float* c1w = (const float*)d_in[1];
    const float* c1b = (const float*)d_in[2];
    const float* g1  = (const float*)d_in[3];
    const float* bb1 = (const float*)d_in[4];
    const float* c2w = (const float*)d_in[5];
    const float* c2b = (const float*)d_in[6];
    const float* g2  = (const float*)d_in[7];
    const float* bb2 = (const float*)d_in[8];
    const float* wq  = (const float*)d_in[9];
    const float* wk  = (const float*)d_in[10];
    const float* wv  = (const float*)d_in[11];
    const float* rel = (const float*)d_in[12];
    const float* lag = (const float*)d_in[13];
    const float* lab = (const float*)d_in[14];
    const float* l1g = (const float*)d_in[15];
    const float* l1b = (const float*)d_in[16];
    const float* l2g = (const float*)d_in[17];
    const float* l2b = (const float*)d_in[18];
    const float* w1f = (const float*)d_in[19];
    const float* b1f = (const float*)d_in[20];
    const float* w2f = (const float*)d_in[21];
    const float* b2f = (const float*)d_in[22];

    float* ws = (float*)d_ws;
    const size_t NE = (size_t)BB * LL * DD;      // 2M floats
    float* xsrc = ws;                  // [0, NE)
    float* qbuf = ws + NE;             // [NE, 2NE)
    float* kbuf = ws + 2 * NE;
    float* vbuf = ws + 3 * NE;
    float* abuf = ws + 4 * NE;
    float* attb = ws + 5 * NE;
    float* part = ws + 6 * NE;         // [6NE, 8NE)
    float* ff1b = qbuf;                // reuse q/k/v/abuf region: 4*NE = B*L*DFF

    k_conv<<<dim3(8, 16, 2), dim3(256), 0, stream>>>(x, c1w, c1b, g1, bb1, c2w, part);
    k_convfin<<<dim3(2048), dim3(256), 0, stream>>>(part, c2b, g2, bb2, xsrc);
    k_qkv<<<dim3(16, 16, 3), dim3(256), 0, stream>>>(xsrc, wq, wk, wv, qbuf, kbuf, vbuf);
    k_attn<<<dim3(16, 128), dim3(256), 0, stream>>>(qbuf, kbuf, vbuf, rel, abuf);
    k_ln<<<dim3(16, 16), dim3(256), 0, stream>>>(abuf, xsrc, lag, lab, l1g, l1b, attb);
    k_ff1<<<dim3(16, 16, 4), dim3(256), 0, stream>>>(attb, w1f, b1f, ff1b);
    k_ff2<<<dim3(16, 16), dim3(256), 0, stream>>>(ff1b, w2f, b2f, attb, l2g, l2b, (float*)d_out);
}

// Round 2
// 664.528 us; speedup vs baseline: 1.6683x; 1.6683x over previous
//
#include <hip/hip_runtime.h>
#include <math.h>

#define BB   16
#define CIN  16
#define LL   1024
#define DD   128
#define NHH  8
#define DHH  16
#define DF   512

#define INVS 0.9999950000374998f   // 1/sqrt(1+1e-5)

typedef __attribute__((ext_vector_type(4))) float f32x4;
typedef __attribute__((ext_vector_type(8))) __bf16 bf16x8;

__device__ __forceinline__ float geluf(float v) {
    return 0.5f * v * (1.0f + erff(v * 0.70710678118654752440f));
}

// Abramowitz-Stegun 7.1.26 erf, |err|<=1.5e-7: ~17 VALU ops (1 rcp + 1 exp)
__device__ __forceinline__ float gelu_as(float v) {
    float x  = v * 0.70710678118654752440f;
    float ax = fabsf(x);
    float tt = __builtin_amdgcn_rcpf(fmaf(0.3275911f, ax, 1.0f));
    float p  = fmaf(1.061405429f, tt, -1.453152027f);
    p = fmaf(p, tt, 1.421413741f);
    p = fmaf(p, tt, -0.284496736f);
    p = fmaf(p, tt, 0.254829592f);
    p = p * tt;
    float e  = __expf(-ax * ax);
    float pe = p * e;
    float ope = (x >= 0.0f) ? (2.0f - pe) : pe;   // 1 + erf(x)
    return 0.5f * v * ope;
}

// ---------- prep: w2 -> bf16 [d][k]  (k = o*16+c, already contiguous) ----------
__global__ __launch_bounds__(256) void k_prep_w2(
    const float* __restrict__ w2, __bf16* __restrict__ w2bf)
{
    int i = (blockIdx.x * 256 + threadIdx.x) * 4;
    float4 v = *(const float4*)&w2[i];
    union { __bf16 h[4]; float2 f2; } u;
    u.h[0] = (__bf16)v.x; u.h[1] = (__bf16)v.y;
    u.h[2] = (__bf16)v.z; u.h[3] = (__bf16)v.w;
    *(float2*)&w2bf[i] = u.f2;
}

// ---------- prep: fold BN1 scale into conv1 weights ----------
__global__ __launch_bounds__(256) void k_prep_w1(
    const float* __restrict__ w1, const float* __restrict__ c1b,
    const float* __restrict__ g1, const float* __restrict__ bb1,
    float* __restrict__ w1A, float* __restrict__ b1A)
{
    int o = blockIdx.x * 256 + threadIdx.x;
    if (o < DF) {
        float A = g1[o] * INVS;
        #pragma unroll
        for (int tp = 0; tp < 7; tp++) w1A[o * 8 + tp] = w1[o * 7 + tp] * A;
        w1A[o * 8 + 7] = 0.0f;
        b1A[o] = fmaf(c1b[o], A, bb1[o]);
    }
}

// ---------- fused conv1+BN1+GELU -> bf16 MFMA conv2 GEMM -> BN2+GELU -> xsrc ----------
__global__ __launch_bounds__(256) void k_conv(
    const float* __restrict__ x,
    const float* __restrict__ w1A, const float* __restrict__ b1A,
    const __bf16* __restrict__ w2bf,
    const float* __restrict__ c2b, const float* __restrict__ g2,
    const float* __restrict__ bb2,
    float* __restrict__ xsrc)
{
    const int lt = blockIdx.x;      // 16 tiles of 64 l
    const int b  = blockIdx.y;      // 16
    const int t  = threadIdx.x;
    const int l0 = lt * 64;

    __shared__ float xs[CIN][72];
    __shared__ __align__(16) __bf16 Ab[2][64 * 128];    // h1g tile, XOR-swizzled
    __shared__ __align__(16) __bf16 Bb[2][128 * 128];   // w2 tile, XOR-swizzled

    // stage x window (with halo)
    for (int idx = t; idx < CIN * 70; idx += 256) {
        int c = idx / 70, i = idx % 70;
        int l = l0 - 3 + i;
        xs[c][i] = (l >= 0 && l < LL) ? x[(b * CIN + c) * LL + l] : 0.0f;
    }
    __syncthreads();

    // conv thread mapping: c = t&15, lq = (t>>4)*4 ; x window held in regs
    const int cc = t & 15;
    const int lq = (t >> 4) * 4;
    float xw[10];
    #pragma unroll
    for (int j = 0; j < 10; j++) xw[j] = xs[cc][lq + j];

    const int lane = t & 63;
    const int l15  = lane & 15;
    const int kg   = lane >> 4;
    const int wv   = t >> 6;

    f32x4 acc[4][2];
    #pragma unroll
    for (int m = 0; m < 4; m++)
        #pragma unroll
        for (int n = 0; n < 2; n++) acc[m][n] = (f32x4){0.f, 0.f, 0.f, 0.f};

    f32x4 stg[8];

#define STAGE_LOAD(K0) do { \
    _Pragma("unroll") \
    for (int it = 0; it < 8; it++) { \
        int s = it * 256 + t; \
        int r = s >> 4, g = s & 15; \
        stg[it] = *(const f32x4*)&w2bf[(size_t)r * 8192 + (K0) + g * 8]; \
    } \
} while (0)

#define STAGE_WRITE(BUF) do { \
    _Pragma("unroll") \
    for (int it = 0; it < 8; it++) { \
        int s = it * 256 + t; \
        int r = s >> 4, g = s & 15; \
        *(f32x4*)&Bb[BUF][r * 128 + ((g * 8) ^ ((r & 7) << 3))] = stg[it]; \
    } \
} while (0)

#define CONV_CHUNK(BUF, O0) do { \
    _Pragma("unroll") \
    for (int oo = 0; oo < 8; oo++) { \
        const float* wp = &w1A[(size_t)((O0) + oo) * 8]; \
        float c0 = wp[0], c1 = wp[1], c2 = wp[2], c3 = wp[3]; \
        float c4 = wp[4], c5 = wp[5], c6 = wp[6]; \
        float bb_ = b1A[(O0) + oo]; \
        int kcol = oo * 16 + cc; \
        _Pragma("unroll") \
        for (int dl = 0; dl < 4; dl++) { \
            float s = fmaf(xw[dl], c0, bb_); \
            s = fmaf(xw[dl + 1], c1, s); \
            s = fmaf(xw[dl + 2], c2, s); \
            s = fmaf(xw[dl + 3], c3, s); \
            s = fmaf(xw[dl + 4], c4, s); \
            s = fmaf(xw[dl + 5], c5, s); \
            s = fmaf(xw[dl + 6], c6, s); \
            float h = gelu_as(s); \
            int l = lq + dl; \
            Ab[BUF][l * 128 + (kcol ^ ((l & 7) << 3))] = (__bf16)h; \
        } \
    } \
} while (0)

#define MFMA_CHUNK(BUF) do { \
    _Pragma("unroll") \
    for (int kk = 0; kk < 4; kk++) { \
        int kb = kk * 32 + kg * 8; \
        bf16x8 af[4], bfr[2]; \
        _Pragma("unroll") \
        for (int m = 0; m < 4; m++) { \
            int r = m * 16 + l15; \
            af[m] = *(const bf16x8*)&Ab[BUF][r * 128 + (kb ^ ((l15 & 7) << 3))]; \
        } \
        _Pragma("unroll") \
        for (int n = 0; n < 2; n++) { \
            int r = wv * 32 + n * 16 + l15; \
            bfr[n] = *(const bf16x8*)&Bb[BUF][r * 128 + (kb ^ ((l15 & 7) << 3))]; \
        } \
        _Pragma("unroll") \
        for (int m = 0; m < 4; m++) \
            _Pragma("unroll") \
            for (int n = 0; n < 2; n++) \
                acc[m][n] = __builtin_amdgcn_mfma_f32_16x16x32_bf16( \
                    af[m], bfr[n], acc[m][n], 0, 0, 0); \
    } \
} while (0)

    // prologue: chunk 0 into buf 0
    STAGE_LOAD(0);
    CONV_CHUNK(0, 0);
    STAGE_WRITE(0);
    __syncthreads();

    // windows 0..61 (unrolled x2 so buffer indices are compile-time)
    for (int ic = 0; ic < 62; ic += 2) {
        STAGE_LOAD((ic + 1) * 128);
        MFMA_CHUNK(0);
        CONV_CHUNK(1, (ic + 1) * 8);
        STAGE_WRITE(1);
        __syncthreads();

        STAGE_LOAD((ic + 2) * 128);
        MFMA_CHUNK(1);
        CONV_CHUNK(0, (ic + 2) * 8);
        STAGE_WRITE(0);
        __syncthreads();
    }
    // window 62 (cur=0, prep chunk 63 -> buf 1)
    STAGE_LOAD(63 * 128);
    MFMA_CHUNK(0);
    CONV_CHUNK(1, 63 * 8);
    STAGE_WRITE(1);
    __syncthreads();
    // window 63
    MFMA_CHUNK(1);

    // epilogue: BN2 + GELU, direct store (C/D: col=lane&15, row=(lane>>4)*4+reg)
    #pragma unroll
    for (int m = 0; m < 4; m++) {
        #pragma unroll
        for (int n = 0; n < 2; n++) {
            int d = wv * 32 + n * 16 + l15;
            float A2 = g2[d] * INVS;
            float B2 = fmaf(c2b[d], A2, bb2[d]);
            #pragma unroll
            for (int r = 0; r < 4; r++) {
                int l = l0 + m * 16 + kg * 4 + r;
                float val = gelu_as(fmaf(acc[m][n][r], A2, B2));
                xsrc[((size_t)b * LL + l) * DD + d] = val;
            }
        }
    }
#undef STAGE_LOAD
#undef STAGE_WRITE
#undef CONV_CHUNK
#undef MFMA_CHUNK
}

// ---------- x_pos = x_src + PE ; q/k/v = x_pos @ W^T  -> (B,H,L,16) ----------
__global__ __launch_bounds__(256) void k_qkv(
    const float* __restrict__ xsrc, const float* __restrict__ wq,
    const float* __restrict__ wk,   const float* __restrict__ wv,
    float* __restrict__ qo, float* __restrict__ ko, float* __restrict__ vo)
{
    const int lt = blockIdx.x, b = blockIdx.y, wsel = blockIdx.z;
    const int t = threadIdx.x;
    const int l0 = lt * 64;
    const float* w = (wsel == 0) ? wq : ((wsel == 1) ? wk : wv);
    float* out = (wsel == 0) ? qo : ((wsel == 1) ? ko : vo);

    __shared__ float xp[64][132];
    __shared__ float wt[16][132];

    #pragma unroll
    for (int u = 0; u < 8; u++) {
        int e = t * 8 + u;                 // f4 index, 2048 total
        int l = e >> 5, d0 = (e & 31) * 4;
        float4 xv = *(const float4*)&xsrc[((size_t)b * LL + l0 + l) * DD + d0];
        int j0 = d0 >> 1;
        float posf = (float)(l0 + l);
        float a0 = posf * expf(-0.14391156831212787f * (float)j0) * 0.125f;
        float a1 = posf * expf(-0.14391156831212787f * (float)(j0 + 1)) * 0.125f;
        xv.x += sinf(a0); xv.y += cosf(a0);
        xv.z += sinf(a1); xv.w += cosf(a1);
        *(float4*)&xp[l][d0] = xv;
    }
    __syncthreads();

    const int lg = t >> 4, dg = t & 15;
    const int lth = lg * 4, dth = dg * 8;
    float acc[4][8];
    #pragma unroll
    for (int i = 0; i < 4; i++)
        #pragma unroll
        for (int j = 0; j < 8; j++) acc[i][j] = 0.0f;

    for (int kc = 0; kc < 8; kc++) {
        {
            int d = t >> 1, kk0 = (t & 1) * 8;
            const float* src = &w[(size_t)d * DD + kc * 16 + kk0];
            float4 v0 = *(const float4*)src;
            float4 v1 = *(const float4*)(src + 4);
            wt[kk0 + 0][d] = v0.x; wt[kk0 + 1][d] = v0.y;
            wt[kk0 + 2][d] = v0.z; wt[kk0 + 3][d] = v0.w;
            wt[kk0 + 4][d] = v1.x; wt[kk0 + 5][d] = v1.y;
            wt[kk0 + 6][d] = v1.z; wt[kk0 + 7][d] = v1.w;
        }
        __syncthreads();
        #pragma unroll
        for (int kk = 0; kk < 16; kk++) {
            int k = kc * 16 + kk;
            float a0 = xp[lth + 0][k], a1 = xp[lth + 1][k];
            float a2 = xp[lth + 2][k], a3 = xp[lth + 3][k];
            float wvv[8];
            *(float4*)&wvv[0] = *(const float4*)&wt[kk][dth];
            *(float4*)&wvv[4] = *(const float4*)&wt[kk][dth + 4];
            #pragma unroll
            for (int j = 0; j < 8; j++) {
                acc[0][j] += a0 * wvv[j];
                acc[1][j] += a1 * wvv[j];
                acc[2][j] += a2 * wvv[j];
                acc[3][j] += a3 * wvv[j];
            }
        }
        __syncthreads();
    }
    int h = dth >> 4, dh0 = dth & 15;
    #pragma unroll
    for (int i = 0; i < 4; i++) {
        float* dst = &out[(((size_t)b * NHH + h) * LL + l0 + lth + i) * DHH + dh0];
        float4 o0 = {acc[i][0], acc[i][1], acc[i][2], acc[i][3]};
        float4 o1 = {acc[i][4], acc[i][5], acc[i][6], acc[i][7]};
        *(float4*)dst = o0;
        *(float4*)(dst + 4) = o1;
    }
}

// ---------- attention: softmax(QK^T*s)@V + relbias@V  (flash, 2 accumulators) ----------
__global__ __launch_bounds__(256) void k_attn(
    const float* __restrict__ q, const float* __restrict__ k,
    const float* __restrict__ v, const float* __restrict__ rel,
    float* __restrict__ out)
{
    const int qt = blockIdx.x;           // 16
    const int bh = blockIdx.y;           // 128
    const int h  = bh & 7;
    const int t  = threadIdx.x;
    const int q0 = qt * 64;

    __shared__ float qs[64][20];
    __shared__ float kst[16 * 160];      // (i, k): i*160 + (k>>4)*20 + (k&15)
    __shared__ float vst[8 * 324];       // (k, i): (k>>4)*324 + (k&15)*20 + i
    __shared__ float tbl[2048];

    const float scale = 0.08838834764831845f;  // 1/sqrt(128)

    for (int i = t; i < 2047; i += 256) tbl[i] = rel[(size_t)i * 8 + h];
    {
        int e = t * 4; int r = e >> 4, i0 = e & 15;
        float4 qv = *(const float4*)&q[((size_t)bh * LL + q0 + r) * DHH + i0];
        qv.x *= scale; qv.y *= scale; qv.z *= scale; qv.w *= scale;
        *(float4*)&qs[r][i0] = qv;
    }
    __syncthreads();

    const int rg = t >> 3, kg = t & 7;
    const int r0 = rg * 2;
    float qr[2][16];
    #pragma unroll
    for (int rr = 0; rr < 2; rr++)
        #pragma unroll
        for (int i = 0; i < 16; i += 4)
            *(float4*)&qr[rr][i] = *(const float4*)&qs[r0 + rr][i];

    float accp[2][16], accb[2][16];
    #pragma unroll
    for (int rr = 0; rr < 2; rr++)
        #pragma unroll
        for (int i = 0; i < 16; i++) { accp[rr][i] = 0.f; accb[rr][i] = 0.f; }
    float mrow[2] = {-INFINITY, -INFINITY};
    float lrow[2] = {0.f, 0.f};

    for (int kt = 0; kt < 8; kt++) {
        const int k0 = kt * 128;
        {
            int e = t * 8;
            int row = e >> 4, i0 = e & 15;       // i0 in {0,8}
            const float* kp = &k[((size_t)bh * LL + k0 + row) * DHH + i0];
            float4 a0 = *(const float4*)kp;
            float4 a1 = *(const float4*)(kp + 4);
            int blk = row >> 4, rr_ = row & 15;
            kst[(i0 + 0) * 160 + blk * 20 + rr_] = a0.x;
            kst[(i0 + 1) * 160 + blk * 20 + rr_] = a0.y;
            kst[(i0 + 2) * 160 + blk * 20 + rr_] = a0.z;
            kst[(i0 + 3) * 160 + blk * 20 + rr_] = a0.w;
            kst[(i0 + 4) * 160 + blk * 20 + rr_] = a1.x;
            kst[(i0 + 5) * 160 + blk * 20 + rr_] = a1.y;
            kst[(i0 + 6) * 160 + blk * 20 + rr_] = a1.z;
            kst[(i0 + 7) * 160 + blk * 20 + rr_] = a1.w;
            const float* vp = &v[((size_t)bh * LL + k0 + row) * DHH + i0];
            float4 b0 = *(const float4*)vp;
            float4 b1 = *(const float4*)(vp + 4);
            *(float4*)&vst[blk * 324 + rr_ * 20 + i0]     = b0;
            *(float4*)&vst[blk * 324 + rr_ * 20 + i0 + 4] = b1;
        }
        __syncthreads();

        float s[2][16];
        #pragma unroll
        for (int rr = 0; rr < 2; rr++)
            #pragma unroll
            for (int kk = 0; kk < 16; kk++) s[rr][kk] = 0.f;
        #pragma unroll
        for (int i = 0; i < 16; i++) {
            float kv[16];
            const float* base = &kst[i * 160 + kg * 20];
            *(float4*)&kv[0]  = *(const float4*)(base);
            *(float4*)&kv[4]  = *(const float4*)(base + 4);
            *(float4*)&kv[8]  = *(const float4*)(base + 8);
            *(float4*)&kv[12] = *(const float4*)(base + 12);
            #pragma unroll
            for (int kk = 0; kk < 16; kk++) {
                s[0][kk] += qr[0][i] * kv[kk];
                s[1][kk] += qr[1][i] * kv[kk];
            }
        }
        #pragma unroll
        for (int rr = 0; rr < 2; rr++) {
            float mt = s[rr][0];
            #pragma unroll
            for (int kk = 1; kk < 16; kk++) mt = fmaxf(mt, s[rr][kk]);
            mt = fmaxf(mt, __shfl_xor(mt, 1, 8));
            mt = fmaxf(mt, __shfl_xor(mt, 2, 8));
            mt = fmaxf(mt, __shfl_xor(mt, 4, 8));
            float mnew = fmaxf(mrow[rr], mt);
            float sf = __expf(mrow[rr] - mnew);
            mrow[rr] = mnew;
            lrow[rr] *= sf;
            #pragma unroll
            for (int i = 0; i < 16; i++) accp[rr][i] *= sf;
            float ls = 0.f;
            #pragma unroll
            for (int kk = 0; kk < 16; kk++) {
                float p = __expf(s[rr][kk] - mnew);
                s[rr][kk] = p;
                ls += p;
            }
            ls += __shfl_xor(ls, 1, 8);
            ls += __shfl_xor(ls, 2, 8);
            ls += __shfl_xor(ls, 4, 8);
            lrow[rr] += ls;
        }
        #pragma unroll
        for (int kk = 0; kk < 16; kk++) {
            int kidx = k0 + kg * 16 + kk;
            float vv[16];
            const float* vb = &vst[kg * 324 + kk * 20];
            *(float4*)&vv[0]  = *(const float4*)(vb);
            *(float4*)&vv[4]  = *(const float4*)(vb + 4);
            *(float4*)&vv[8]  = *(const float4*)(vb + 8);
            *(float4*)&vv[12] = *(const float4*)(vb + 12);
            float bc0 = tbl[q0 + r0     - kidx + 1023];
            float bc1 = tbl[q0 + r0 + 1 - kidx + 1023];
            float p0 = s[0][kk], p1 = s[1][kk];
            #pragma unroll
            for (int i = 0; i < 16; i++) {
                accp[0][i] += p0 * vv[i];
                accp[1][i] += p1 * vv[i];
                accb[0][i] += bc0 * vv[i];
                accb[1][i] += bc1 * vv[i];
            }
        }
        __syncthreads();
    }

    #pragma unroll
    for (int rr = 0; rr < 2; rr++) {
        float inv = 1.0f / lrow[rr];
        #pragma unroll
        for (int i = 0; i < 16; i++) {
            float a = accp[rr][i];
            a += __shfl_xor(a, 1, 8);
            a += __shfl_xor(a, 2, 8);
            a += __shfl_xor(a, 4, 8);
            float bs = accb[rr][i];
            bs += __shfl_xor(bs, 1, 8);
            bs += __shfl_xor(bs, 2, 8);
            bs += __shfl_xor(bs, 4, 8);
            accp[rr][i] = a * inv + bs;
        }
        float2 o = {accp[rr][kg * 2], accp[rr][kg * 2 + 1]};
        *(float2*)&out[((size_t)bh * LL + q0 + r0 + rr) * DHH + kg * 2] = o;
    }
}

// ---------- LN(attn_out) ; att = LN(x_src + .) ----------
__global__ __launch_bounds__(256) void k_ln(
    const float* __restrict__ ao,  const float* __restrict__ xsrc,
    const float* __restrict__ lag, const float* __restrict__ lab,
    const float* __restrict__ l1g, const float* __restrict__ l1b,
    float* __restrict__ att)
{
    const int lt = blockIdx.x, b = blockIdx.y;
    const int t = threadIdx.x;
    const int l0 = lt * 64;
    __shared__ float tile[64][132];

    #pragma unroll
    for (int u = 0; u < 4; u++) {
        int cid = u * 256 + t;               // 1024 chunks of 8
        int hh = cid >> 7, rem = cid & 127;
        int l = rem >> 1, dh0 = (rem & 1) * 8;
        const float* src = &ao[(((size_t)b * NHH + hh) * LL + l0 + l) * DHH + dh0];
        float4 a0 = *(const float4*)src;
        float4 a1 = *(const float4*)(src + 4);
        *(float4*)&tile[l][hh * 16 + dh0]     = a0;
        *(float4*)&tile[l][hh * 16 + dh0 + 4] = a1;
    }
    __syncthreads();

    const int wid = t >> 6, lane = t & 63;
    float2 ga  = *(const float2*)&lag[lane * 2];
    float2 ba  = *(const float2*)&lab[lane * 2];
    float2 g1v = *(const float2*)&l1g[lane * 2];
    float2 b1v = *(const float2*)&l1b[lane * 2];

    for (int rr = 0; rr < 16; rr++) {
        int r = wid * 16 + rr;
        float2 vv = *(const float2*)&tile[r][lane * 2];
        float s = vv.x + vv.y, s2 = vv.x * vv.x + vv.y * vv.y;
        #pragma unroll
        for (int m = 1; m < 64; m <<= 1) { s += __shfl_xor(s, m, 64); s2 += __shfl_xor(s2, m, 64); }
        float mu = s * (1.f / 128.f);
        float var = s2 * (1.f / 128.f) - mu * mu;
        float rs = rsqrtf(var + 1e-5f);
        float o0 = (vv.x - mu) * rs * ga.x + ba.x;
        float o1 = (vv.y - mu) * rs * ga.y + ba.y;
        float2 xv = *(const float2*)&xsrc[((size_t)b * LL + l0 + r) * DD + lane * 2];
        float t0 = xv.x + o0, t1 = xv.y + o1;
        s = t0 + t1; s2 = t0 * t0 + t1 * t1;
        #pragma unroll
        for (int m = 1; m < 64; m <<= 1) { s += __shfl_xor(s, m, 64); s2 += __shfl_xor(s2, m, 64); }
        mu = s * (1.f / 128.f);
        var = s2 * (1.f / 128.f) - mu * mu;
        rs = rsqrtf(var + 1e-5f);
        float a0 = (t0 - mu) * rs * g1v.x + b1v.x;
        float a1 = (t1 - mu) * rs * g1v.y + b1v.y;
        float2 o = {a0, a1};
        *(float2*)&att[((size_t)b * LL + l0 + r) * DD + lane * 2] = o;
    }
}

// ---------- ff1 = relu(att @ w1^T + b1) ----------
__global__ __launch_bounds__(256) void k_ff1(
    const float* __restrict__ att, const float* __restrict__ w1f,
    const float* __restrict__ b1f, float* __restrict__ ff1)
{
    const int lt = blockIdx.x, b = blockIdx.y, ng = blockIdx.z;
    const int l0 = lt * 64, n0 = ng * 128;
    const int t = threadIdx.x;
    __shared__ float xt[64][132];
    __shared__ float wt[16][132];

    #pragma unroll
    for (int u = 0; u < 8; u++) {
        int e = u * 256 + t;                  // 2048 f4
        int l = e >> 5, d0 = (e & 31) * 4;
        *(float4*)&xt[l][d0] = *(const float4*)&att[((size_t)b * LL + l0 + l) * DD + d0];
    }
    __syncthreads();

    const int lg = t >> 4, dg = t & 15;
    const int lth = lg * 4, nth = dg * 8;
    float acc[4][8];
    #pragma unroll
    for (int i = 0; i < 4; i++)
        #pragma unroll
        for (int j = 0; j < 8; j++) acc[i][j] = 0.0f;

    for (int kc = 0; kc < 8; kc++) {
        {
            int d = t >> 1, kk0 = (t & 1) * 8;
            const float* src = &w1f[(size_t)(n0 + d) * DD + kc * 16 + kk0];
            float4 v0 = *(const float4*)src;
            float4 v1 = *(const float4*)(src + 4);
            wt[kk0 + 0][d] = v0.x; wt[kk0 + 1][d] = v0.y;
            wt[kk0 + 2][d] = v0.z; wt[kk0 + 3][d] = v0.w;
            wt[kk0 + 4][d] = v1.x; wt[kk0 + 5][d] = v1.y;
            wt[kk0 + 6][d] = v1.z; wt[kk0 + 7][d] = v1.w;
        }
        __syncthreads();
        #pragma unroll
        for (int kk = 0; kk < 16; kk++) {
            int kx = kc * 16 + kk;
            float a0 = xt[lth + 0][kx], a1 = xt[lth + 1][kx];
            float a2 = xt[lth + 2][kx], a3 = xt[lth + 3][kx];
            float wvv[8];
            *(float4*)&wvv[0] = *(const float4*)&wt[kk][nth];
            *(float4*)&wvv[4] = *(const float4*)&wt[kk][nth + 4];
            #pragma unroll
            for (int j = 0; j < 8; j++) {
                acc[0][j] += a0 * wvv[j];
                acc[1][j] += a1 * wvv[j];
                acc[2][j] += a2 * wvv[j];
                acc[3][j] += a3 * wvv[j];
            }
        }
        __syncthreads();
    }
    float bvv[8];
    *(float4*)&bvv[0] = *(const float4*)&b1f[n0 + nth];
    *(float4*)&bvv[4] = *(const float4*)&b1f[n0 + nth + 4];
    #pragma unroll
    for (int i = 0; i < 4; i++) {
        float r[8];
        #pragma unroll
        for (int j = 0; j < 8; j++) r[j] = fmaxf(acc[i][j] + bvv[j], 0.0f);
        float* dst = &ff1[((size_t)b * LL + l0 + lth + i) * DF + n0 + nth];
        float4 o0 = {r[0], r[1], r[2], r[3]};
        float4 o1 = {r[4], r[5], r[6], r[7]};
        *(float4*)dst = o0;
        *(float4*)(dst + 4) = o1;
    }
}

// ---------- ff2 + residual + LN2 + transpose-store ----------
__global__ __launch_bounds__(256) void k_ff2(
    const float* __restrict__ ff1, const float* __restrict__ w2f,
    const float* __restrict__ b2f, const float* __restrict__ att,
    const float* __restrict__ l2g, const float* __restrict__ l2b,
    float* __restrict__ y)
{
    const int lt = blockIdx.x, b = blockIdx.y;
    const int l0 = lt * 64;
    const int t = threadIdx.x;
    __shared__ float fc[64][36];
    __shared__ float wt[32][132];
    __shared__ float yl[64][132];

    const int lg = t >> 4, dg = t & 15;
    const int lth = lg * 4, dth = dg * 8;
    float acc[4][8];
    #pragma unroll
    for (int i = 0; i < 4; i++)
        #pragma unroll
        for (int j = 0; j < 8; j++) acc[i][j] = 0.0f;

    for (int kc = 0; kc < 16; kc++) {
        {
            int l = t >> 2, k0 = (t & 3) * 8;
            const float* src = &ff1[((size_t)b * LL + l0 + l) * DF + kc * 32 + k0];
            float4 a0 = *(const float4*)src;
            float4 a1 = *(const float4*)(src + 4);
            *(float4*)&fc[l][k0]     = a0;
            *(float4*)&fc[l][k0 + 4] = a1;
        }
        {
            int d = t >> 1, kk0 = (t & 1) * 16;
            const float* src = &w2f[(size_t)d * DF + kc * 32 + kk0];
            float4 v0 = *(const float4*)src;
            float4 v1 = *(const float4*)(src + 4);
            float4 v2 = *(const float4*)(src + 8);
            float4 v3 = *(const float4*)(src + 12);
            wt[kk0 +  0][d] = v0.x; wt[kk0 +  1][d] = v0.y;
            wt[kk0 +  2][d] = v0.z; wt[kk0 +  3][d] = v0.w;
            wt[kk0 +  4][d] = v1.x; wt[kk0 +  5][d] = v1.y;
            wt[kk0 +  6][d] = v1.z; wt[kk0 +  7][d] = v1.w;
            wt[kk0 +  8][d] = v2.x; wt[kk0 +  9][d] = v2.y;
            wt[kk0 + 10][d] = v2.z; wt[kk0 + 11][d] = v2.w;
            wt[kk0 + 12][d] = v3.x; wt[kk0 + 13][d] = v3.y;
            wt[kk0 + 14][d] = v3.z; wt[kk0 + 15][d] = v3.w;
        }
        __syncthreads();
        #pragma unroll
        for (int kk = 0; kk < 32; kk++) {
            float a0 = fc[lth + 0][kk], a1 = fc[lth + 1][kk];
            float a2 = fc[lth + 2][kk], a3 = fc[lth + 3][kk];
            float wvv[8];
            *(float4*)&wvv[0] = *(const float4*)&wt[kk][dth];
            *(float4*)&wvv[4] = *(const float4*)&wt[kk][dth + 4];
            #pragma unroll
            for (int j = 0; j < 8; j++) {
                acc[0][j] += a0 * wvv[j];
                acc[1][j] += a1 * wvv[j];
                acc[2][j] += a2 * wvv[j];
                acc[3][j] += a3 * wvv[j];
            }
        }
        __syncthreads();
    }

    float bvv[8];
    *(float4*)&bvv[0] = *(const float4*)&b2f[dth];
    *(float4*)&bvv[4] = *(const float4*)&b2f[dth + 4];
    #pragma unroll
    for (int i = 0; i < 4; i++) {
        const float* ar = &att[((size_t)b * LL + l0 + lth + i) * DD + dth];
        float4 r0 = *(const float4*)ar;
        float4 r1 = *(const float4*)(ar + 4);
        float rv[8] = {r0.x, r0.y, r0.z, r0.w, r1.x, r1.y, r1.z, r1.w};
        #pragma unroll
        for (int j = 0; j < 8; j++)
            yl[lth + i][dth + j] = acc[i][j] + bvv[j] + rv[j];
    }
    __syncthreads();

    const int wid = t >> 6, lane = t & 63;
    float2 gv = *(const float2*)&l2g[lane * 2];
    float2 bv = *(const float2*)&l2b[lane * 2];
    for (int rr = 0; rr < 16; rr++) {
        int r = wid * 16 + rr;
        float2 vv = *(const float2*)&yl[r][lane * 2];
        float s = vv.x + vv.y, s2 = vv.x * vv.x + vv.y * vv.y;
        #pragma unroll
        for (int m = 1; m < 64; m <<= 1) { s += __shfl_xor(s, m, 64); s2 += __shfl_xor(s2, m, 64); }
        float mu = s * (1.f / 128.f);
        float var = s2 * (1.f / 128.f) - mu * mu;
        float rs = rsqrtf(var + 1e-5f);
        float o0 = (vv.x - mu) * rs * gv.x + bv.x;
        float o1 = (vv.y - mu) * rs * gv.y + bv.y;
        yl[r][lane * 2]     = o0;
        yl[r][lane * 2 + 1] = o1;
    }
    __syncthreads();

    {
        int d = t >> 1, lh = (t & 1) * 32;
        for (int i0 = 0; i0 < 32; i0 += 4) {
            float4 o = { yl[lh + i0 + 0][d], yl[lh + i0 + 1][d],
                         yl[lh + i0 + 2][d], yl[lh + i0 + 3][d] };
            *(float4*)&y[(size_t)b * DD * LL + (size_t)d * LL + l0 + lh + i0] = o;
        }
    }
}

extern "C" void kernel_launch(void* const* d_in, const int* in_sizes, int n_in,
                              void* d_out, int out_size, void* d_ws, size_t ws_size,
                              hipStream_t stream)
{
    const float* x   = (const float*)d_in[0];
    const float* c1w = (const float*)d_in[1];
    const float* c1b = (const float*)d_in[2];
    const float* g1  = (const float*)d_in[3];
    const float* bb1 = (const float*)d_in[4];
    const float* c2w = (const float*)d_in[5];
    const float* c2b = (const float*)d_in[6];
    const float* g2  = (const float*)d_in[7];
    const float* bb2 = (const float*)d_in[8];
    const float* wq  = (const float*)d_in[9];
    const float* wk  = (const float*)d_in[10];
    const float* wv  = (const float*)d_in[11];
    const float* rel = (const float*)d_in[12];
    const float* lag = (const float*)d_in[13];
    const float* lab = (const float*)d_in[14];
    const float* l1g = (const float*)d_in[15];
    const float* l1b = (const float*)d_in[16];
    const float* l2g = (const float*)d_in[17];
    const float* l2b = (const float*)d_in[18];
    const float* w1f = (const float*)d_in[19];
    const float* b1f = (const float*)d_in[20];
    const float* w2f = (const float*)d_in[21];
    const float* b2f = (const float*)d_in[22];

    float* ws = (float*)d_ws;
    const size_t NE = (size_t)BB * LL * DD;      // 2M floats
    float* xsrc = ws;                  // [0, NE)
    float* qbuf = ws + NE;             // [NE, 2NE)
    float* kbuf = ws + 2 * NE;
    float* vbuf = ws + 3 * NE;
    float* abuf = ws + 4 * NE;
    float* attb = ws + 5 * NE;
    float* base6 = ws + 6 * NE;        // prep region
    __bf16* w2bf = (__bf16*)base6;     // 1M bf16 = 2 MB
    float* w1A  = base6 + 524288;      // 512*8 f32
    float* b1A  = w1A + 4096;          // 512 f32
    float* ff1b = qbuf;                // reuse q/k/v/abuf region: 4*NE = B*L*DFF

    k_prep_w2<<<dim3(1024), dim3(256), 0, stream>>>(c2w, w2bf);
    k_prep_w1<<<dim3(2), dim3(256), 0, stream>>>(c1w, c1b, g1, bb1, w1A, b1A);
    k_conv<<<dim3(16, 16), dim3(256), 0, stream>>>(x, w1A, b1A, w2bf, c2b, g2, bb2, xsrc);
    k_qkv<<<dim3(16, 16, 3), dim3(256), 0, stream>>>(xsrc, wq, wk, wv, qbuf, kbuf, vbuf);
    k_attn<<<dim3(16, 128), dim3(256), 0, stream>>>(qbuf, kbuf, vbuf, rel, abuf);
    k_ln<<<dim3(16, 16), dim3(256), 0, stream>>>(abuf, xsrc, lag, lab, l1g, l1b, attb);
    k_ff1<<<dim3(16, 16, 4), dim3(256), 0, stream>>>(attb, w1f, b1f, ff1b);
    k_ff2<<<dim3(16, 16), dim3(256), 0, stream>>>(ff1b, w2f, b2f, attb, l2g, l2b, (float*)d_out);
}

// Round 3
// 495.006 us; speedup vs baseline: 2.2397x; 1.3425x over previous
//
#include <hip/hip_runtime.h>
#include <math.h>

#define BB   16
#define CIN  16
#define LL   1024
#define DD   128
#define NHH  8
#define DHH  16
#define DF   512

#define INVS 0.9999950000374998f   // 1/sqrt(1+1e-5)

typedef __attribute__((ext_vector_type(4))) float f32x4;
typedef __attribute__((ext_vector_type(8))) __bf16 bf16x8;

__device__ __forceinline__ float geluf(float v) {
    return 0.5f * v * (1.0f + erff(v * 0.70710678118654752440f));
}

// Abramowitz-Stegun 7.1.26 erf, |err|<=1.5e-7: ~17 VALU ops (1 rcp + 1 exp)
__device__ __forceinline__ float gelu_as(float v) {
    float x  = v * 0.70710678118654752440f;
    float ax = fabsf(x);
    float tt = __builtin_amdgcn_rcpf(fmaf(0.3275911f, ax, 1.0f));
    float p  = fmaf(1.061405429f, tt, -1.453152027f);
    p = fmaf(p, tt, 1.421413741f);
    p = fmaf(p, tt, -0.284496736f);
    p = fmaf(p, tt, 0.254829592f);
    p = p * tt;
    float e  = __expf(-ax * ax);
    float pe = p * e;
    float ope = (x >= 0.0f) ? (2.0f - pe) : pe;   // 1 + erf(x)
    return 0.5f * v * ope;
}

__device__ __forceinline__ unsigned pkbf(float a, float b) {
    union { __bf16 h[2]; unsigned u; } z;
    z.h[0] = (__bf16)a; z.h[1] = (__bf16)b;
    return z.u;
}

__device__ __forceinline__ bf16x8 pack8(float4 a, float4 b) {
    union { __bf16 h[8]; bf16x8 v8; } u;
    u.h[0] = (__bf16)a.x; u.h[1] = (__bf16)a.y;
    u.h[2] = (__bf16)a.z; u.h[3] = (__bf16)a.w;
    u.h[4] = (__bf16)b.x; u.h[5] = (__bf16)b.y;
    u.h[6] = (__bf16)b.z; u.h[7] = (__bf16)b.w;
    return u.v8;
}

// ---------- prep: w2 -> bf16 [d][k]  (k = o*16+c, already contiguous) ----------
__global__ __launch_bounds__(256) void k_prep_w2(
    const float* __restrict__ w2, __bf16* __restrict__ w2bf)
{
    int i = (blockIdx.x * 256 + threadIdx.x) * 4;
    float4 v = *(const float4*)&w2[i];
    union { __bf16 h[4]; float2 f2; } u;
    u.h[0] = (__bf16)v.x; u.h[1] = (__bf16)v.y;
    u.h[2] = (__bf16)v.z; u.h[3] = (__bf16)v.w;
    *(float2*)&w2bf[i] = u.f2;
}

// ---------- prep: fold BN1 scale into conv1 weights ----------
__global__ __launch_bounds__(256) void k_prep_w1(
    const float* __restrict__ w1, const float* __restrict__ c1b,
    const float* __restrict__ g1, const float* __restrict__ bb1,
    float* __restrict__ w1A, float* __restrict__ b1A)
{
    int o = blockIdx.x * 256 + threadIdx.x;
    if (o < DF) {
        float A = g1[o] * INVS;
        #pragma unroll
        for (int tp = 0; tp < 7; tp++) w1A[o * 8 + tp] = w1[o * 7 + tp] * A;
        w1A[o * 8 + 7] = 0.0f;
        b1A[o] = fmaf(c1b[o], A, bb1[o]);
    }
}

// ---------- fused conv1+BN1+GELU -> bf16 MFMA conv2 GEMM -> BN2+GELU -> xsrc ----------
__global__ __launch_bounds__(256) void k_conv(
    const float* __restrict__ x,
    const float* __restrict__ w1A, const float* __restrict__ b1A,
    const __bf16* __restrict__ w2bf,
    const float* __restrict__ c2b, const float* __restrict__ g2,
    const float* __restrict__ bb2,
    float* __restrict__ xsrc)
{
    const int lt = blockIdx.x;      // 16 tiles of 64 l
    const int b  = blockIdx.y;      // 16
    const int t  = threadIdx.x;
    const int l0 = lt * 64;

    __shared__ float xs[CIN][72];
    __shared__ __align__(16) __bf16 Ab[2][64 * 128];    // h1g tile, XOR-swizzled
    __shared__ __align__(16) __bf16 Bb[2][128 * 128];   // w2 tile, XOR-swizzled

    // stage x window (with halo)
    for (int idx = t; idx < CIN * 70; idx += 256) {
        int c = idx / 70, i = idx % 70;
        int l = l0 - 3 + i;
        xs[c][i] = (l >= 0 && l < LL) ? x[(b * CIN + c) * LL + l] : 0.0f;
    }
    __syncthreads();

    // conv thread mapping: c = t&15, lq = (t>>4)*4 ; x window held in regs
    const int cc = t & 15;
    const int lq = (t >> 4) * 4;
    float xw[10];
    #pragma unroll
    for (int j = 0; j < 10; j++) xw[j] = xs[cc][lq + j];

    const int lane = t & 63;
    const int l15  = lane & 15;
    const int kg   = lane >> 4;
    const int wv   = t >> 6;

    f32x4 acc[4][2];
    #pragma unroll
    for (int m = 0; m < 4; m++)
        #pragma unroll
        for (int n = 0; n < 2; n++) acc[m][n] = (f32x4){0.f, 0.f, 0.f, 0.f};

    f32x4 stg[8];

#define STAGE_LOAD(K0) do { \
    _Pragma("unroll") \
    for (int it = 0; it < 8; it++) { \
        int s = it * 256 + t; \
        int r = s >> 4, g = s & 15; \
        stg[it] = *(const f32x4*)&w2bf[(size_t)r * 8192 + (K0) + g * 8]; \
    } \
} while (0)

#define STAGE_WRITE(BUF) do { \
    _Pragma("unroll") \
    for (int it = 0; it < 8; it++) { \
        int s = it * 256 + t; \
        int r = s >> 4, g = s & 15; \
        *(f32x4*)&Bb[BUF][r * 128 + ((g * 8) ^ ((r & 7) << 3))] = stg[it]; \
    } \
} while (0)

#define CONV_CHUNK(BUF, O0) do { \
    _Pragma("unroll") \
    for (int oo = 0; oo < 8; oo++) { \
        const float* wp = &w1A[(size_t)((O0) + oo) * 8]; \
        float c0 = wp[0], c1 = wp[1], c2 = wp[2], c3 = wp[3]; \
        float c4 = wp[4], c5 = wp[5], c6 = wp[6]; \
        float bb_ = b1A[(O0) + oo]; \
        int kcol = oo * 16 + cc; \
        _Pragma("unroll") \
        for (int dl = 0; dl < 4; dl++) { \
            float s = fmaf(xw[dl], c0, bb_); \
            s = fmaf(xw[dl + 1], c1, s); \
            s = fmaf(xw[dl + 2], c2, s); \
            s = fmaf(xw[dl + 3], c3, s); \
            s = fmaf(xw[dl + 4], c4, s); \
            s = fmaf(xw[dl + 5], c5, s); \
            s = fmaf(xw[dl + 6], c6, s); \
            float h = gelu_as(s); \
            int l = lq + dl; \
            Ab[BUF][l * 128 + (kcol ^ ((l & 7) << 3))] = (__bf16)h; \
        } \
    } \
} while (0)

#define MFMA_CHUNK(BUF) do { \
    _Pragma("unroll") \
    for (int kk = 0; kk < 4; kk++) { \
        int kb = kk * 32 + kg * 8; \
        bf16x8 af[4], bfr[2]; \
        _Pragma("unroll") \
        for (int m = 0; m < 4; m++) { \
            int r = m * 16 + l15; \
            af[m] = *(const bf16x8*)&Ab[BUF][r * 128 + (kb ^ ((l15 & 7) << 3))]; \
        } \
        _Pragma("unroll") \
        for (int n = 0; n < 2; n++) { \
            int r = wv * 32 + n * 16 + l15; \
            bfr[n] = *(const bf16x8*)&Bb[BUF][r * 128 + (kb ^ ((l15 & 7) << 3))]; \
        } \
        _Pragma("unroll") \
        for (int m = 0; m < 4; m++) \
            _Pragma("unroll") \
            for (int n = 0; n < 2; n++) \
                acc[m][n] = __builtin_amdgcn_mfma_f32_16x16x32_bf16( \
                    af[m], bfr[n], acc[m][n], 0, 0, 0); \
    } \
} while (0)

    // prologue: chunk 0 into buf 0
    STAGE_LOAD(0);
    CONV_CHUNK(0, 0);
    STAGE_WRITE(0);
    __syncthreads();

    // windows 0..61 (unrolled x2 so buffer indices are compile-time)
    for (int ic = 0; ic < 62; ic += 2) {
        STAGE_LOAD((ic + 1) * 128);
        MFMA_CHUNK(0);
        CONV_CHUNK(1, (ic + 1) * 8);
        STAGE_WRITE(1);
        __syncthreads();

        STAGE_LOAD((ic + 2) * 128);
        MFMA_CHUNK(1);
        CONV_CHUNK(0, (ic + 2) * 8);
        STAGE_WRITE(0);
        __syncthreads();
    }
    // window 62 (cur=0, prep chunk 63 -> buf 1)
    STAGE_LOAD(63 * 128);
    MFMA_CHUNK(0);
    CONV_CHUNK(1, 63 * 8);
    STAGE_WRITE(1);
    __syncthreads();
    // window 63
    MFMA_CHUNK(1);

    // epilogue: BN2 + GELU, direct store (C/D: col=lane&15, row=(lane>>4)*4+reg)
    #pragma unroll
    for (int m = 0; m < 4; m++) {
        #pragma unroll
        for (int n = 0; n < 2; n++) {
            int d = wv * 32 + n * 16 + l15;
            float A2 = g2[d] * INVS;
            float B2 = fmaf(c2b[d], A2, bb2[d]);
            #pragma unroll
            for (int r = 0; r < 4; r++) {
                int l = l0 + m * 16 + kg * 4 + r;
                float val = gelu_as(fmaf(acc[m][n][r], A2, B2));
                xsrc[((size_t)b * LL + l) * DD + d] = val;
            }
        }
    }
#undef STAGE_LOAD
#undef STAGE_WRITE
#undef CONV_CHUNK
#undef MFMA_CHUNK
}

// ---------- x_pos = x_src + PE ; q/k/v = x_pos @ W^T  -> (B,H,L,16) ----------
__global__ __launch_bounds__(256) void k_qkv(
    const float* __restrict__ xsrc, const float* __restrict__ wq,
    const float* __restrict__ wk,   const float* __restrict__ wv,
    float* __restrict__ qo, float* __restrict__ ko, float* __restrict__ vo)
{
    const int lt = blockIdx.x, b = blockIdx.y, wsel = blockIdx.z;
    const int t = threadIdx.x;
    const int l0 = lt * 64;
    const float* w = (wsel == 0) ? wq : ((wsel == 1) ? wk : wv);
    float* out = (wsel == 0) ? qo : ((wsel == 1) ? ko : vo);

    __shared__ float xp[64][132];
    __shared__ float wt[16][132];

    #pragma unroll
    for (int u = 0; u < 8; u++) {
        int e = t * 8 + u;                 // f4 index, 2048 total
        int l = e >> 5, d0 = (e & 31) * 4;
        float4 xv = *(const float4*)&xsrc[((size_t)b * LL + l0 + l) * DD + d0];
        int j0 = d0 >> 1;
        float posf = (float)(l0 + l);
        float a0 = posf * expf(-0.14391156831212787f * (float)j0) * 0.125f;
        float a1 = posf * expf(-0.14391156831212787f * (float)(j0 + 1)) * 0.125f;
        xv.x += sinf(a0); xv.y += cosf(a0);
        xv.z += sinf(a1); xv.w += cosf(a1);
        *(float4*)&xp[l][d0] = xv;
    }
    __syncthreads();

    const int lg = t >> 4, dg = t & 15;
    const int lth = lg * 4, dth = dg * 8;
    float acc[4][8];
    #pragma unroll
    for (int i = 0; i < 4; i++)
        #pragma unroll
        for (int j = 0; j < 8; j++) acc[i][j] = 0.0f;

    for (int kc = 0; kc < 8; kc++) {
        {
            int d = t >> 1, kk0 = (t & 1) * 8;
            const float* src = &w[(size_t)d * DD + kc * 16 + kk0];
            float4 v0 = *(const float4*)src;
            float4 v1 = *(const float4*)(src + 4);
            wt[kk0 + 0][d] = v0.x; wt[kk0 + 1][d] = v0.y;
            wt[kk0 + 2][d] = v0.z; wt[kk0 + 3][d] = v0.w;
            wt[kk0 + 4][d] = v1.x; wt[kk0 + 5][d] = v1.y;
            wt[kk0 + 6][d] = v1.z; wt[kk0 + 7][d] = v1.w;
        }
        __syncthreads();
        #pragma unroll
        for (int kk = 0; kk < 16; kk++) {
            int k = kc * 16 + kk;
            float a0 = xp[lth + 0][k], a1 = xp[lth + 1][k];
            float a2 = xp[lth + 2][k], a3 = xp[lth + 3][k];
            float wvv[8];
            *(float4*)&wvv[0] = *(const float4*)&wt[kk][dth];
            *(float4*)&wvv[4] = *(const float4*)&wt[kk][dth + 4];
            #pragma unroll
            for (int j = 0; j < 8; j++) {
                acc[0][j] += a0 * wvv[j];
                acc[1][j] += a1 * wvv[j];
                acc[2][j] += a2 * wvv[j];
                acc[3][j] += a3 * wvv[j];
            }
        }
        __syncthreads();
    }
    int h = dth >> 4, dh0 = dth & 15;
    #pragma unroll
    for (int i = 0; i < 4; i++) {
        float* dst = &out[(((size_t)b * NHH + h) * LL + l0 + lth + i) * DHH + dh0];
        float4 o0 = {acc[i][0], acc[i][1], acc[i][2], acc[i][3]};
        float4 o1 = {acc[i][4], acc[i][5], acc[i][6], acc[i][7]};
        *(float4*)dst = o0;
        *(float4*)(dst + 4) = o1;
    }
}

// ---------- attention via MFMA: softmax(QK^T*s)@V + relbias@V  (flash) ----------
// grid (bh=128, qt=8): all q-tiles of one bh on same XCD (L2 reuse of K/V)
__global__ __launch_bounds__(256) void k_attn(
    const float* __restrict__ q, const float* __restrict__ k,
    const float* __restrict__ v, const float* __restrict__ rel,
    float* __restrict__ out)
{
    const int bh = blockIdx.x;           // 128
    const int qt = blockIdx.y;           // 8 tiles of 128 q
    const int h  = bh & 7;
    const int t  = threadIdx.x;
    const int w  = t >> 6, lane = t & 63;
    const int g  = lane >> 4, qi = lane & 15;
    const int xq = (qi & 7) << 3;
    const int qbase = qt * 128 + w * 32;
    const float scale = 0.08838834764831845f;  // 1/sqrt(128)

    // LDS: V^T dbuf [2][16d][128k] | P per wave [16q][128k] | rev rel tables
    __shared__ __align__(16) __bf16 lds[16384];
    __bf16* Vl = lds;                    // 4096
    __bf16* Pw = lds + 4096 + w * 2048;  // per-wave 2048
    __bf16* R0 = lds + 12288;            // 2048
    __bf16* R1 = lds + 14336;            // 2048

    // reversed bias tables: R0[x] = tbl[2046-x], R1[x] = R0[x+1]
    for (int i = t; i < 2048; i += 256) {
        R0[i] = (__bf16)((i <= 2046) ? rel[(size_t)(2046 - i) * NHH + h] : 0.0f);
        R1[i] = (__bf16)((i <= 2045) ? rel[(size_t)(2045 - i) * NHH + h] : 0.0f);
    }

    // Q B-fragments (col=q, kelems=dh; dh>=16 zeroed)
    bf16x8 qf[2];
    #pragma unroll
    for (int n = 0; n < 2; n++) {
        union { __bf16 hh[8]; bf16x8 v8; } u;
        #pragma unroll
        for (int j = 0; j < 8; j++) u.hh[j] = (__bf16)0.0f;
        if (g < 2) {
            const float* qp = &q[((size_t)bh * LL + qbase + n * 16 + qi) * DHH + g * 8];
            float4 a = *(const float4*)qp, b4 = *(const float4*)(qp + 4);
            float sv[8] = {a.x, a.y, a.z, a.w, b4.x, b4.y, b4.z, b4.w};
            #pragma unroll
            for (int j = 0; j < 8; j++) u.hh[j] = (__bf16)(sv[j] * scale);
        }
        qf[n] = u.v8;
    }

    f32x4 accp[2], accb[2];
    #pragma unroll
    for (int n = 0; n < 2; n++) {
        accp[n] = (f32x4){0.f, 0.f, 0.f, 0.f};
        accb[n] = (f32x4){0.f, 0.f, 0.f, 0.f};
    }
    float mrun[2] = {-INFINITY, -INFINITY};
    float lrun[2] = {0.f, 0.f};

    const f32x4 zero4 = (f32x4){0.f, 0.f, 0.f, 0.f};

#define PROC_N(Sn, n) do { \
    float mx = Sn[0][0]; \
    _Pragma("unroll") \
    for (int f = 0; f < 8; f++) { \
        _Pragma("unroll") \
        for (int r = 0; r < 4; r++) if (f || r) mx = fmaxf(mx, Sn[f][r]); } \
    mx = fmaxf(mx, __shfl_xor(mx, 16, 64)); \
    mx = fmaxf(mx, __shfl_xor(mx, 32, 64)); \
    float mnew = fmaxf(mrun[n], mx); \
    float sf = __expf(mrun[n] - mnew); \
    mrun[n] = mnew; \
    lrun[n] *= sf; \
    accp[n][0] *= sf; accp[n][1] *= sf; accp[n][2] *= sf; accp[n][3] *= sf; \
    float ls = 0.f; \
    _Pragma("unroll") \
    for (int f = 0; f < 8; f++) { \
        float p0 = __expf(Sn[f][0] - mnew), p1 = __expf(Sn[f][1] - mnew); \
        float p2 = __expf(Sn[f][2] - mnew), p3 = __expf(Sn[f][3] - mnew); \
        ls += (p0 + p1) + (p2 + p3); \
        unsigned* pp = (unsigned*)(Pw + (qi * 128 + ((f * 16 + g * 4) ^ xq))); \
        pp[0] = pkbf(p0, p1); pp[1] = pkbf(p2, p3); \
    } \
    ls += __shfl_xor(ls, 16, 64); ls += __shfl_xor(ls, 32, 64); \
    lrun[n] += ls; \
    int qoff = 1023 - (qbase + (n) * 16 + qi) + k0; \
    _Pragma("unroll") \
    for (int c = 0; c < 4; c++) { \
        bf16x8 vf = *(const bf16x8*)&Vbuf[qi * 128 + ((c * 32 + g * 8) ^ xq)]; \
        bf16x8 pf = *(const bf16x8*)&Pw[qi * 128 + ((c * 32 + g * 8) ^ xq)]; \
        int idx = qoff + c * 32 + 8 * g; \
        const unsigned* tb = (const unsigned*)((idx & 1) ? R1 : R0); \
        unsigned s_ = (unsigned)idx >> 1; \
        union { unsigned u[4]; bf16x8 v8; } bu; \
        bu.u[0] = tb[s_]; bu.u[1] = tb[s_ + 1]; \
        bu.u[2] = tb[s_ + 2]; bu.u[3] = tb[s_ + 3]; \
        accp[n] = __builtin_amdgcn_mfma_f32_16x16x32_bf16(vf, pf, accp[n], 0, 0, 0); \
        accb[n] = __builtin_amdgcn_mfma_f32_16x16x32_bf16(vf, bu.v8, accb[n], 0, 0, 0); \
    } \
} while (0)

    for (int kt = 0; kt < 8; kt++) {
        const int k0 = kt * 128;
        // stage V^T (cooperative, swizzled, double-buffered)
        {
            int kr = t >> 1, d0 = (t & 1) * 8;
            const float* vp = &v[((size_t)bh * LL + k0 + kr) * DHH + d0];
            float4 a = *(const float4*)vp, b4 = *(const float4*)(vp + 4);
            __bf16* dst = Vl + (kt & 1) * 2048;
            float vv[8] = {a.x, a.y, a.z, a.w, b4.x, b4.y, b4.z, b4.w};
            #pragma unroll
            for (int i = 0; i < 8; i++) {
                int d = d0 + i;
                dst[d * 128 + (kr ^ ((d & 7) << 3))] = (__bf16)vv[i];
            }
        }
        __syncthreads();
        const __bf16* Vbuf = Vl + (kt & 1) * 2048;

        // S^T = K·Q^T  (A=K frag: row=k, kelems=dh; garbage dh>=16 ok, Q zeroed)
        f32x4 S0[8], S1[8];
        #pragma unroll
        for (int f = 0; f < 8; f++) {
            const float* kp = &k[((size_t)bh * LL + k0 + f * 16 + qi) * DHH + (g & 1) * 8];
            float4 ka = *(const float4*)kp, kb = *(const float4*)(kp + 4);
            bf16x8 kf = pack8(ka, kb);
            S0[f] = __builtin_amdgcn_mfma_f32_16x16x32_bf16(kf, qf[0], zero4, 0, 0, 0);
            S1[f] = __builtin_amdgcn_mfma_f32_16x16x32_bf16(kf, qf[1], zero4, 0, 0, 0);
        }

        PROC_N(S0, 0);
        PROC_N(S1, 1);
    }
#undef PROC_N

    // epilogue: out = accp/l + accb ; C layout: col=q=lane&15, row=d=4g+r
    #pragma unroll
    for (int n = 0; n < 2; n++) {
        float inv = 1.0f / lrun[n];
        float4 o;
        o.x = accp[n][0] * inv + accb[n][0];
        o.y = accp[n][1] * inv + accb[n][1];
        o.z = accp[n][2] * inv + accb[n][2];
        o.w = accp[n][3] * inv + accb[n][3];
        *(float4*)&out[((size_t)bh * LL + qbase + n * 16 + qi) * DHH + g * 4] = o;
    }
}

// ---------- LN(attn_out) ; att = LN(x_src + .) ----------
__global__ __launch_bounds__(256) void k_ln(
    const float* __restrict__ ao,  const float* __restrict__ xsrc,
    const float* __restrict__ lag, const float* __restrict__ lab,
    const float* __restrict__ l1g, const float* __restrict__ l1b,
    float* __restrict__ att)
{
    const int lt = blockIdx.x, b = blockIdx.y;
    const int t = threadIdx.x;
    const int l0 = lt * 64;
    __shared__ float tile[64][132];

    #pragma unroll
    for (int u = 0; u < 4; u++) {
        int cid = u * 256 + t;               // 1024 chunks of 8
        int hh = cid >> 7, rem = cid & 127;
        int l = rem >> 1, dh0 = (rem & 1) * 8;
        const float* src = &ao[(((size_t)b * NHH + hh) * LL + l0 + l) * DHH + dh0];
        float4 a0 = *(const float4*)src;
        float4 a1 = *(const float4*)(src + 4);
        *(float4*)&tile[l][hh * 16 + dh0]     = a0;
        *(float4*)&tile[l][hh * 16 + dh0 + 4] = a1;
    }
    __syncthreads();

    const int wid = t >> 6, lane = t & 63;
    float2 ga  = *(const float2*)&lag[lane * 2];
    float2 ba  = *(const float2*)&lab[lane * 2];
    float2 g1v = *(const float2*)&l1g[lane * 2];
    float2 b1v = *(const float2*)&l1b[lane * 2];

    for (int rr = 0; rr < 16; rr++) {
        int r = wid * 16 + rr;
        float2 vv = *(const float2*)&tile[r][lane * 2];
        float s = vv.x + vv.y, s2 = vv.x * vv.x + vv.y * vv.y;
        #pragma unroll
        for (int m = 1; m < 64; m <<= 1) { s += __shfl_xor(s, m, 64); s2 += __shfl_xor(s2, m, 64); }
        float mu = s * (1.f / 128.f);
        float var = s2 * (1.f / 128.f) - mu * mu;
        float rs = rsqrtf(var + 1e-5f);
        float o0 = (vv.x - mu) * rs * ga.x + ba.x;
        float o1 = (vv.y - mu) * rs * ga.y + ba.y;
        float2 xv = *(const float2*)&xsrc[((size_t)b * LL + l0 + r) * DD + lane * 2];
        float t0 = xv.x + o0, t1 = xv.y + o1;
        s = t0 + t1; s2 = t0 * t0 + t1 * t1;
        #pragma unroll
        for (int m = 1; m < 64; m <<= 1) { s += __shfl_xor(s, m, 64); s2 += __shfl_xor(s2, m, 64); }
        mu = s * (1.f / 128.f);
        var = s2 * (1.f / 128.f) - mu * mu;
        rs = rsqrtf(var + 1e-5f);
        float a0 = (t0 - mu) * rs * g1v.x + b1v.x;
        float a1 = (t1 - mu) * rs * g1v.y + b1v.y;
        float2 o = {a0, a1};
        *(float2*)&att[((size_t)b * LL + l0 + r) * DD + lane * 2] = o;
    }
}

// ---------- ff1 = relu(att @ w1^T + b1) ----------
__global__ __launch_bounds__(256) void k_ff1(
    const float* __restrict__ att, const float* __restrict__ w1f,
    const float* __restrict__ b1f, float* __restrict__ ff1)
{
    const int lt = blockIdx.x, b = blockIdx.y, ng = blockIdx.z;
    const int l0 = lt * 64, n0 = ng * 128;
    const int t = threadIdx.x;
    __shared__ float xt[64][132];
    __shared__ float wt[16][132];

    #pragma unroll
    for (int u = 0; u < 8; u++) {
        int e = u * 256 + t;                  // 2048 f4
        int l = e >> 5, d0 = (e & 31) * 4;
        *(float4*)&xt[l][d0] = *(const float4*)&att[((size_t)b * LL + l0 + l) * DD + d0];
    }
    __syncthreads();

    const int lg = t >> 4, dg = t & 15;
    const int lth = lg * 4, nth = dg * 8;
    float acc[4][8];
    #pragma unroll
    for (int i = 0; i < 4; i++)
        #pragma unroll
        for (int j = 0; j < 8; j++) acc[i][j] = 0.0f;

    for (int kc = 0; kc < 8; kc++) {
        {
            int d = t >> 1, kk0 = (t & 1) * 8;
            const float* src = &w1f[(size_t)(n0 + d) * DD + kc * 16 + kk0];
            float4 v0 = *(const float4*)src;
            float4 v1 = *(const float4*)(src + 4);
            wt[kk0 + 0][d] = v0.x; wt[kk0 + 1][d] = v0.y;
            wt[kk0 + 2][d] = v0.z; wt[kk0 + 3][d] = v0.w;
            wt[kk0 + 4][d] = v1.x; wt[kk0 + 5][d] = v1.y;
            wt[kk0 + 6][d] = v1.z; wt[kk0 + 7][d] = v1.w;
        }
        __syncthreads();
        #pragma unroll
        for (int kk = 0; kk < 16; kk++) {
            int kx = kc * 16 + kk;
            float a0 = xt[lth + 0][kx], a1 = xt[lth + 1][kx];
            float a2 = xt[lth + 2][kx], a3 = xt[lth + 3][kx];
            float wvv[8];
            *(float4*)&wvv[0] = *(const float4*)&wt[kk][nth];
            *(float4*)&wvv[4] = *(const float4*)&wt[kk][nth + 4];
            #pragma unroll
            for (int j = 0; j < 8; j++) {
                acc[0][j] += a0 * wvv[j];
                acc[1][j] += a1 * wvv[j];
                acc[2][j] += a2 * wvv[j];
                acc[3][j] += a3 * wvv[j];
            }
        }
        __syncthreads();
    }
    float bvv[8];
    *(float4*)&bvv[0] = *(const float4*)&b1f[n0 + nth];
    *(float4*)&bvv[4] = *(const float4*)&b1f[n0 + nth + 4];
    #pragma unroll
    for (int i = 0; i < 4; i++) {
        float r[8];
        #pragma unroll
        for (int j = 0; j < 8; j++) r[j] = fmaxf(acc[i][j] + bvv[j], 0.0f);
        float* dst = &ff1[((size_t)b * LL + l0 + lth + i) * DF + n0 + nth];
        float4 o0 = {r[0], r[1], r[2], r[3]};
        float4 o1 = {r[4], r[5], r[6], r[7]};
        *(float4*)dst = o0;
        *(float4*)(dst + 4) = o1;
    }
}

// ---------- ff2 + residual + LN2 + transpose-store ----------
__global__ __launch_bounds__(256) void k_ff2(
    const float* __restrict__ ff1, const float* __restrict__ w2f,
    const float* __restrict__ b2f, const float* __restrict__ att,
    const float* __restrict__ l2g, const float* __restrict__ l2b,
    float* __restrict__ y)
{
    const int lt = blockIdx.x, b = blockIdx.y;
    const int l0 = lt * 64;
    const int t = threadIdx.x;
    __shared__ float fc[64][36];
    __shared__ float wt[32][132];
    __shared__ float yl[64][132];

    const int lg = t >> 4, dg = t & 15;
    const int lth = lg * 4, dth = dg * 8;
    float acc[4][8];
    #pragma unroll
    for (int i = 0; i < 4; i++)
        #pragma unroll
        for (int j = 0; j < 8; j++) acc[i][j] = 0.0f;

    for (int kc = 0; kc < 16; kc++) {
        {
            int l = t >> 2, k0 = (t & 3) * 8;
            const float* src = &ff1[((size_t)b * LL + l0 + l) * DF + kc * 32 + k0];
            float4 a0 = *(const float4*)src;
            float4 a1 = *(const float4*)(src + 4);
            *(float4*)&fc[l][k0]     = a0;
            *(float4*)&fc[l][k0 + 4] = a1;
        }
        {
            int d = t >> 1, kk0 = (t & 1) * 16;
            const float* src = &w2f[(size_t)d * DF + kc * 32 + kk0];
            float4 v0 = *(const float4*)src;
            float4 v1 = *(const float4*)(src + 4);
            float4 v2 = *(const float4*)(src + 8);
            float4 v3 = *(const float4*)(src + 12);
            wt[kk0 +  0][d] = v0.x; wt[kk0 +  1][d] = v0.y;
            wt[kk0 +  2][d] = v0.z; wt[kk0 +  3][d] = v0.w;
            wt[kk0 +  4][d] = v1.x; wt[kk0 +  5][d] = v1.y;
            wt[kk0 +  6][d] = v1.z; wt[kk0 +  7][d] = v1.w;
            wt[kk0 +  8][d] = v2.x; wt[kk0 +  9][d] = v2.y;
            wt[kk0 + 10][d] = v2.z; wt[kk0 + 11][d] = v2.w;
            wt[kk0 + 12][d] = v3.x; wt[kk0 + 13][d] = v3.y;
            wt[kk0 + 14][d] = v3.z; wt[kk0 + 15][d] = v3.w;
        }
        __syncthreads();
        #pragma unroll
        for (int kk = 0; kk < 32; kk++) {
            float a0 = fc[lth + 0][kk], a1 = fc[lth + 1][kk];
            float a2 = fc[lth + 2][kk], a3 = fc[lth + 3][kk];
            float wvv[8];
            *(float4*)&wvv[0] = *(const float4*)&wt[kk][dth];
            *(float4*)&wvv[4] = *(const float4*)&wt[kk][dth + 4];
            #pragma unroll
            for (int j = 0; j < 8; j++) {
                acc[0][j] += a0 * wvv[j];
                acc[1][j] += a1 * wvv[j];
                acc[2][j] += a2 * wvv[j];
                acc[3][j] += a3 * wvv[j];
            }
        }
        __syncthreads();
    }

    float bvv[8];
    *(float4*)&bvv[0] = *(const float4*)&b2f[dth];
    *(float4*)&bvv[4] = *(const float4*)&b2f[dth + 4];
    #pragma unroll
    for (int i = 0; i < 4; i++) {
        const float* ar = &att[((size_t)b * LL + l0 + lth + i) * DD + dth];
        float4 r0 = *(const float4*)ar;
        float4 r1 = *(const float4*)(ar + 4);
        float rv[8] = {r0.x, r0.y, r0.z, r0.w, r1.x, r1.y, r1.z, r1.w};
        #pragma unroll
        for (int j = 0; j < 8; j++)
            yl[lth + i][dth + j] = acc[i][j] + bvv[j] + rv[j];
    }
    __syncthreads();

    const int wid = t >> 6, lane = t & 63;
    float2 gv = *(const float2*)&l2g[lane * 2];
    float2 bv = *(const float2*)&l2b[lane * 2];
    for (int rr = 0; rr < 16; rr++) {
        int r = wid * 16 + rr;
        float2 vv = *(const float2*)&yl[r][lane * 2];
        float s = vv.x + vv.y, s2 = vv.x * vv.x + vv.y * vv.y;
        #pragma unroll
        for (int m = 1; m < 64; m <<= 1) { s += __shfl_xor(s, m, 64); s2 += __shfl_xor(s2, m, 64); }
        float mu = s * (1.f / 128.f);
        float var = s2 * (1.f / 128.f) - mu * mu;
        float rs = rsqrtf(var + 1e-5f);
        float o0 = (vv.x - mu) * rs * gv.x + bv.x;
        float o1 = (vv.y - mu) * rs * gv.y + bv.y;
        yl[r][lane * 2]     = o0;
        yl[r][lane * 2 + 1] = o1;
    }
    __syncthreads();

    {
        int d = t >> 1, lh = (t & 1) * 32;
        for (int i0 = 0; i0 < 32; i0 += 4) {
            float4 o = { yl[lh + i0 + 0][d], yl[lh + i0 + 1][d],
                         yl[lh + i0 + 2][d], yl[lh + i0 + 3][d] };
            *(float4*)&y[(size_t)b * DD * LL + (size_t)d * LL + l0 + lh + i0] = o;
        }
    }
}

extern "C" void kernel_launch(void* const* d_in, const int* in_sizes, int n_in,
                              void* d_out, int out_size, void* d_ws, size_t ws_size,
                              hipStream_t stream)
{
    const float* x   = (const float*)d_in[0];
    const float* c1w = (const float*)d_in[1];
    const float* c1b = (const float*)d_in[2];
    const float* g1  = (const float*)d_in[3];
    const float* bb1 = (const float*)d_in[4];
    const float* c2w = (const float*)d_in[5];
    const float* c2b = (const float*)d_in[6];
    const float* g2  = (const float*)d_in[7];
    const float* bb2 = (const float*)d_in[8];
    const float* wq  = (const float*)d_in[9];
    const float* wk  = (const float*)d_in[10];
    const float* wv  = (const float*)d_in[11];
    const float* rel = (const float*)d_in[12];
    const float* lag = (const float*)d_in[13];
    const float* lab = (const float*)d_in[14];
    const float* l1g = (const float*)d_in[15];
    const float* l1b = (const float*)d_in[16];
    const float* l2g = (const float*)d_in[17];
    const float* l2b = (const float*)d_in[18];
    const float* w1f = (const float*)d_in[19];
    const float* b1f = (const float*)d_in[20];
    const float* w2f = (const float*)d_in[21];
    const float* b2f = (const float*)d_in[22];

    float* ws = (float*)d_ws;
    const size_t NE = (size_t)BB * LL * DD;      // 2M floats
    float* xsrc = ws;                  // [0, NE)
    float* qbuf = ws + NE;             // [NE, 2NE)
    float* kbuf = ws + 2 * NE;
    float* vbuf = ws + 3 * NE;
    float* abuf = ws + 4 * NE;
    float* attb = ws + 5 * NE;
    float* base6 = ws + 6 * NE;        // prep region
    __bf16* w2bf = (__bf16*)base6;     // 1M bf16 = 2 MB
    float* w1A  = base6 + 524288;      // 512*8 f32
    float* b1A  = w1A + 4096;          // 512 f32
    float* ff1b = qbuf;                // reuse q/k/v/abuf region: 4*NE = B*L*DFF

    k_prep_w2<<<dim3(1024), dim3(256), 0, stream>>>(c2w, w2bf);
    k_prep_w1<<<dim3(2), dim3(256), 0, stream>>>(c1w, c1b, g1, bb1, w1A, b1A);
    k_conv<<<dim3(16, 16), dim3(256), 0, stream>>>(x, w1A, b1A, w2bf, c2b, g2, bb2, xsrc);
    k_qkv<<<dim3(16, 16, 3), dim3(256), 0, stream>>>(xsrc, wq, wk, wv, qbuf, kbuf, vbuf);
    k_attn<<<dim3(128, 8), dim3(256), 0, stream>>>(qbuf, kbuf, vbuf, rel, abuf);
    k_ln<<<dim3(16, 16), dim3(256), 0, stream>>>(abuf, xsrc, lag, lab, l1g, l1b, attb);
    k_ff1<<<dim3(16, 16, 4), dim3(256), 0, stream>>>(attb, w1f, b1f, ff1b);
    k_ff2<<<dim3(16, 16), dim3(256), 0, stream>>>(ff1b, w2f, b2f, attb, l2g, l2b, (float*)d_out);
}

// Round 4
// 333.735 us; speedup vs baseline: 3.3220x; 1.4832x over previous
//
#include <hip/hip_runtime.h>
#include <math.h>

#define BB   16
#define CIN  16
#define LL   1024
#define DD   128
#define NHH  8
#define DHH  16
#define DF   512

#define INVS 0.9999950000374998f   // 1/sqrt(1+1e-5)

typedef __attribute__((ext_vector_type(4))) float f32x4;
typedef __attribute__((ext_vector_type(8))) __bf16 bf16x8;

// tanh-form GELU: v*sigmoid(1.59577*(v+0.044715 v^3)), |err vs erf| <= ~4e-4
__device__ __forceinline__ float gelu_t(float v) {
    float u = v * v;
    float a = v * fmaf(-0.07135481627f, u, -1.5957691216f);
    float e = __expf(a);
    return v * __builtin_amdgcn_rcpf(1.0f + e);
}

__device__ __forceinline__ unsigned pkbf(float a, float b) {
    union { __bf16 h[2]; unsigned u; } z;
    z.h[0] = (__bf16)a; z.h[1] = (__bf16)b;
    return z.u;
}

// ---------- prep: w2 -> bf16 [d][k]  (k = o*16+c, already contiguous) ----------
__global__ __launch_bounds__(256) void k_prep_w2(
    const float* __restrict__ w2, __bf16* __restrict__ w2bf)
{
    int i = (blockIdx.x * 256 + threadIdx.x) * 4;
    float4 v = *(const float4*)&w2[i];
    union { __bf16 h[4]; float2 f2; } u;
    u.h[0] = (__bf16)v.x; u.h[1] = (__bf16)v.y;
    u.h[2] = (__bf16)v.z; u.h[3] = (__bf16)v.w;
    *(float2*)&w2bf[i] = u.f2;
}

// ---------- prep: fold BN1 scale into conv1 weights ----------
__global__ __launch_bounds__(256) void k_prep_w1(
    const float* __restrict__ w1, const float* __restrict__ c1b,
    const float* __restrict__ g1, const float* __restrict__ bb1,
    float* __restrict__ w1A, float* __restrict__ b1A)
{
    int o = blockIdx.x * 256 + threadIdx.x;
    if (o < DF) {
        float A = g1[o] * INVS;
        #pragma unroll
        for (int tp = 0; tp < 7; tp++) w1A[o * 8 + tp] = w1[o * 7 + tp] * A;
        w1A[o * 8 + 7] = 0.0f;
        b1A[o] = fmaf(c1b[o], A, bb1[o]);
    }
}

#define SWZ(l) ((((l) & 7) ^ (((l) >> 2) & 6)))

// ---------- fused conv1+BN1+GELU -> bf16 MFMA conv2 GEMM -> BN2+GELU -> xsrc ----------
// 512 threads, 8 waves (2mw x 4nw); A (h1) via LDS dbuf, B (w2) global->reg dbuf
__global__ __launch_bounds__(512) void k_conv(
    const float* __restrict__ x,
    const float* __restrict__ w1A, const float* __restrict__ b1A,
    const __bf16* __restrict__ w2bf,
    const float* __restrict__ c2b, const float* __restrict__ g2,
    const float* __restrict__ bb2,
    float* __restrict__ xsrc)
{
    const int lt = blockIdx.x;      // 16 tiles of 64 l
    const int b  = blockIdx.y;      // 16
    const int t  = threadIdx.x;
    const int l0 = lt * 64;

    __shared__ float xs[CIN][72];
    __shared__ float w1s[DF * 8];
    __shared__ float b1s[DF];
    __shared__ __align__(16) __bf16 Ab[2][64 * 128];

    for (int idx = t; idx < CIN * 70; idx += 512) {
        int c = idx / 70, i = idx % 70;
        int l = l0 - 3 + i;
        xs[c][i] = (l >= 0 && l < LL) ? x[(b * CIN + c) * LL + l] : 0.0f;
    }
    for (int i = t; i < DF * 8; i += 512) w1s[i] = w1A[i];
    for (int i = t; i < DF; i += 512) b1s[i] = b1A[i];
    __syncthreads();

    // conv mapping: c-pair, l-quad, o-group
    const int cp  = t & 7;
    const int lqi = (t >> 3) & 15;
    const int og  = t >> 7;          // 0..3 (wave-pair uniform)
    const int c0  = cp * 2;
    const int lq  = lqi * 4;

    float xw[2][10];
    #pragma unroll
    for (int j = 0; j < 10; j++) {
        xw[0][j] = xs[c0][lq + j];
        xw[1][j] = xs[c0 + 1][lq + j];
    }

    // mfma mapping
    const int w = t >> 6, lane = t & 63;
    const int l15 = lane & 15, kg = lane >> 4;
    const int mw = w >> 2, nw = w & 3;

    f32x4 acc[2][2];
    #pragma unroll
    for (int mf = 0; mf < 2; mf++)
        #pragma unroll
        for (int nf = 0; nf < 2; nf++) acc[mf][nf] = (f32x4){0.f, 0.f, 0.f, 0.f};

    bf16x8 breg[2][8];

#define BLOAD(CH, BUF) do { \
    _Pragma("unroll") \
    for (int nf = 0; nf < 2; nf++) \
        _Pragma("unroll") \
        for (int kk = 0; kk < 4; kk++) \
            breg[BUF][nf * 4 + kk] = *(const bf16x8*)&w2bf[ \
                (size_t)(nw * 32 + nf * 16 + l15) * 8192 + (size_t)(CH) * 128 + kk * 32 + kg * 8]; \
} while (0)

#define CONV_CHUNK(BUF, CH) do { \
    _Pragma("unroll") \
    for (int j = 0; j < 2; j++) { \
        int o = (CH) * 8 + og * 2 + j; \
        f32x4 wA = *(const f32x4*)&w1s[o * 8]; \
        f32x4 wB = *(const f32x4*)&w1s[o * 8 + 4]; \
        float bias = b1s[o]; \
        int kcol = (og * 2 + j) * 16 + c0; \
        _Pragma("unroll") \
        for (int dl = 0; dl < 4; dl++) { \
            float h2[2]; \
            _Pragma("unroll") \
            for (int ci = 0; ci < 2; ci++) { \
                float s = fmaf(xw[ci][dl], wA[0], bias); \
                s = fmaf(xw[ci][dl + 1], wA[1], s); \
                s = fmaf(xw[ci][dl + 2], wA[2], s); \
                s = fmaf(xw[ci][dl + 3], wA[3], s); \
                s = fmaf(xw[ci][dl + 4], wB[0], s); \
                s = fmaf(xw[ci][dl + 5], wB[1], s); \
                s = fmaf(xw[ci][dl + 6], wB[2], s); \
                h2[ci] = gelu_t(s); \
            } \
            int l = lq + dl; \
            *(unsigned*)&Ab[BUF][l * 128 + (kcol ^ (SWZ(l) << 3))] = pkbf(h2[0], h2[1]); \
        } \
    } \
} while (0)

#define MFMA_CHUNK(BUF, BREGI) do { \
    _Pragma("unroll") \
    for (int kk = 0; kk < 4; kk++) { \
        int kb = kk * 32 + kg * 8; \
        bf16x8 af[2]; \
        _Pragma("unroll") \
        for (int mf = 0; mf < 2; mf++) { \
            int r = mw * 32 + mf * 16 + l15; \
            af[mf] = *(const bf16x8*)&Ab[BUF][r * 128 + (kb ^ (SWZ(r) << 3))]; \
        } \
        _Pragma("unroll") \
        for (int mf = 0; mf < 2; mf++) \
            _Pragma("unroll") \
            for (int nf = 0; nf < 2; nf++) \
                acc[mf][nf] = __builtin_amdgcn_mfma_f32_16x16x32_bf16( \
                    af[mf], breg[BREGI][nf * 4 + kk], acc[mf][nf], 0, 0, 0); \
    } \
} while (0)

    BLOAD(0, 0);
    CONV_CHUNK(0, 0);
    __syncthreads();

    for (int ic = 0; ic < 62; ic += 2) {
        BLOAD(ic + 1, 1);
        MFMA_CHUNK(0, 0);
        CONV_CHUNK(1, ic + 1);
        __syncthreads();

        BLOAD(ic + 2, 0);
        MFMA_CHUNK(1, 1);
        CONV_CHUNK(0, ic + 2);
        __syncthreads();
    }
    BLOAD(63, 1);
    MFMA_CHUNK(0, 0);
    CONV_CHUNK(1, 63);
    __syncthreads();
    MFMA_CHUNK(1, 1);

    // epilogue: BN2 + GELU  (C/D: col(lane&15)=B rows=d, row((lane>>4)*4+r)=A rows=l)
    #pragma unroll
    for (int mf = 0; mf < 2; mf++) {
        #pragma unroll
        for (int nf = 0; nf < 2; nf++) {
            int d = nw * 32 + nf * 16 + l15;
            float A2 = g2[d] * INVS;
            float B2 = fmaf(c2b[d], A2, bb2[d]);
            #pragma unroll
            for (int r = 0; r < 4; r++) {
                int l = l0 + mw * 32 + mf * 16 + kg * 4 + r;
                xsrc[((size_t)b * LL + l) * DD + d] = gelu_t(fmaf(acc[mf][nf][r], A2, B2));
            }
        }
    }
#undef BLOAD
#undef CONV_CHUNK
#undef MFMA_CHUNK
}

// ---------- x_pos = x_src + PE ; q/k/v = x_pos @ W^T -> bf16 (B,H,L,16); q prescaled ----------
__global__ __launch_bounds__(256) void k_qkv(
    const float* __restrict__ xsrc, const float* __restrict__ wq,
    const float* __restrict__ wk,   const float* __restrict__ wv,
    __bf16* __restrict__ qo, __bf16* __restrict__ ko, __bf16* __restrict__ vo)
{
    const int lt = blockIdx.x, b = blockIdx.y, wsel = blockIdx.z;
    const int t = threadIdx.x;
    const int l0 = lt * 64;
    const float* w = (wsel == 0) ? wq : ((wsel == 1) ? wk : wv);
    __bf16* out = (wsel == 0) ? qo : ((wsel == 1) ? ko : vo);
    const float osc = (wsel == 0) ? 0.08838834764831845f : 1.0f;

    __shared__ float xp[64][132];
    __shared__ float wt[16][132];

    #pragma unroll
    for (int u = 0; u < 8; u++) {
        int e = t * 8 + u;                 // f4 index, 2048 total
        int l = e >> 5, d0 = (e & 31) * 4;
        float4 xv = *(const float4*)&xsrc[((size_t)b * LL + l0 + l) * DD + d0];
        int j0 = d0 >> 1;
        float posf = (float)(l0 + l);
        float a0 = posf * expf(-0.14391156831212787f * (float)j0) * 0.125f;
        float a1 = posf * expf(-0.14391156831212787f * (float)(j0 + 1)) * 0.125f;
        xv.x += sinf(a0); xv.y += cosf(a0);
        xv.z += sinf(a1); xv.w += cosf(a1);
        *(float4*)&xp[l][d0] = xv;
    }
    __syncthreads();

    const int lg = t >> 4, dg = t & 15;
    const int lth = lg * 4, dth = dg * 8;
    float acc[4][8];
    #pragma unroll
    for (int i = 0; i < 4; i++)
        #pragma unroll
        for (int j = 0; j < 8; j++) acc[i][j] = 0.0f;

    for (int kc = 0; kc < 8; kc++) {
        {
            int d = t >> 1, kk0 = (t & 1) * 8;
            const float* src = &w[(size_t)d * DD + kc * 16 + kk0];
            float4 v0 = *(const float4*)src;
            float4 v1 = *(const float4*)(src + 4);
            wt[kk0 + 0][d] = v0.x; wt[kk0 + 1][d] = v0.y;
            wt[kk0 + 2][d] = v0.z; wt[kk0 + 3][d] = v0.w;
            wt[kk0 + 4][d] = v1.x; wt[kk0 + 5][d] = v1.y;
            wt[kk0 + 6][d] = v1.z; wt[kk0 + 7][d] = v1.w;
        }
        __syncthreads();
        #pragma unroll
        for (int kk = 0; kk < 16; kk++) {
            int k = kc * 16 + kk;
            float a0 = xp[lth + 0][k], a1 = xp[lth + 1][k];
            float a2 = xp[lth + 2][k], a3 = xp[lth + 3][k];
            float wvv[8];
            *(float4*)&wvv[0] = *(const float4*)&wt[kk][dth];
            *(float4*)&wvv[4] = *(const float4*)&wt[kk][dth + 4];
            #pragma unroll
            for (int j = 0; j < 8; j++) {
                acc[0][j] += a0 * wvv[j];
                acc[1][j] += a1 * wvv[j];
                acc[2][j] += a2 * wvv[j];
                acc[3][j] += a3 * wvv[j];
            }
        }
        __syncthreads();
    }
    int h = dth >> 4, dh0 = dth & 15;
    #pragma unroll
    for (int i = 0; i < 4; i++) {
        union { __bf16 hh[8]; bf16x8 v8; } u;
        #pragma unroll
        for (int j = 0; j < 8; j++) u.hh[j] = (__bf16)(acc[i][j] * osc);
        *(bf16x8*)&out[(((size_t)b * NHH + h) * LL + l0 + lth + i) * DHH + dh0] = u.v8;
    }
}

// ---------- attention via MFMA: softmax(QK^T*s)@V + relbias@V  (flash) ----------
__global__ __launch_bounds__(256) void k_attn(
    const __bf16* __restrict__ q, const __bf16* __restrict__ k,
    const __bf16* __restrict__ v, const float* __restrict__ rel,
    float* __restrict__ out)
{
    const int bh = blockIdx.x;           // 128
    const int qt = blockIdx.y;           // 8 tiles of 128 q
    const int h  = bh & 7;
    const int t  = threadIdx.x;
    const int w  = t >> 6, lane = t & 63;
    const int g  = lane >> 4, qi = lane & 15;
    const int xq = (qi & 7) << 3;
    const int qbase = qt * 128 + w * 32;

    // LDS: V^T dbuf [2][16d][128k] | P per wave [16q][128k] | rev rel tables
    __shared__ __align__(16) __bf16 lds[16384];
    __bf16* Vl = lds;                    // 4096
    __bf16* Pw = lds + 4096 + w * 2048;  // per-wave 2048
    __bf16* R0 = lds + 12288;            // 2048
    __bf16* R1 = lds + 14336;            // 2048

    for (int i = t; i < 2048; i += 256) {
        R0[i] = (__bf16)((i <= 2046) ? rel[(size_t)(2046 - i) * NHH + h] : 0.0f);
        R1[i] = (__bf16)((i <= 2045) ? rel[(size_t)(2045 - i) * NHH + h] : 0.0f);
    }

    // Q B-fragments (col=q, kelems=dh; dh>=16 zeroed); q prescaled by 1/sqrt(128)
    bf16x8 qf[2];
    {
        union { unsigned u[4]; bf16x8 v8; } uz;
        uz.u[0] = uz.u[1] = uz.u[2] = uz.u[3] = 0u;
        #pragma unroll
        for (int n = 0; n < 2; n++) {
            qf[n] = uz.v8;
            if (g < 2)
                qf[n] = *(const bf16x8*)&q[((size_t)bh * LL + qbase + n * 16 + qi) * DHH + g * 8];
        }
    }

    f32x4 accp[2], accb[2];
    #pragma unroll
    for (int n = 0; n < 2; n++) {
        accp[n] = (f32x4){0.f, 0.f, 0.f, 0.f};
        accb[n] = (f32x4){0.f, 0.f, 0.f, 0.f};
    }
    float mrun[2] = {-INFINITY, -INFINITY};
    float lrun[2] = {0.f, 0.f};

    const f32x4 zero4 = (f32x4){0.f, 0.f, 0.f, 0.f};

#define PROC_N(Sn, n) do { \
    float mx = Sn[0][0]; \
    _Pragma("unroll") \
    for (int f = 0; f < 8; f++) { \
        _Pragma("unroll") \
        for (int r = 0; r < 4; r++) if (f || r) mx = fmaxf(mx, Sn[f][r]); } \
    mx = fmaxf(mx, __shfl_xor(mx, 16, 64)); \
    mx = fmaxf(mx, __shfl_xor(mx, 32, 64)); \
    float mnew = fmaxf(mrun[n], mx); \
    float sf = __expf(mrun[n] - mnew); \
    mrun[n] = mnew; \
    lrun[n] *= sf; \
    accp[n][0] *= sf; accp[n][1] *= sf; accp[n][2] *= sf; accp[n][3] *= sf; \
    float ls = 0.f; \
    _Pragma("unroll") \
    for (int f = 0; f < 8; f++) { \
        float p0 = __expf(Sn[f][0] - mnew), p1 = __expf(Sn[f][1] - mnew); \
        float p2 = __expf(Sn[f][2] - mnew), p3 = __expf(Sn[f][3] - mnew); \
        ls += (p0 + p1) + (p2 + p3); \
        unsigned* pp = (unsigned*)(Pw + (qi * 128 + ((f * 16 + g * 4) ^ xq))); \
        pp[0] = pkbf(p0, p1); pp[1] = pkbf(p2, p3); \
    } \
    ls += __shfl_xor(ls, 16, 64); ls += __shfl_xor(ls, 32, 64); \
    lrun[n] += ls; \
    int qoff = 1023 - (qbase + (n) * 16 + qi) + k0; \
    _Pragma("unroll") \
    for (int c = 0; c < 4; c++) { \
        bf16x8 vf = *(const bf16x8*)&Vbuf[qi * 128 + ((c * 32 + g * 8) ^ xq)]; \
        bf16x8 pf = *(const bf16x8*)&Pw[qi * 128 + ((c * 32 + g * 8) ^ xq)]; \
        int idx = qoff + c * 32 + 8 * g; \
        const unsigned* tb = (const unsigned*)((idx & 1) ? R1 : R0); \
        unsigned s_ = (unsigned)idx >> 1; \
        union { unsigned u[4]; bf16x8 v8; } bu; \
        bu.u[0] = tb[s_]; bu.u[1] = tb[s_ + 1]; \
        bu.u[2] = tb[s_ + 2]; bu.u[3] = tb[s_ + 3]; \
        accp[n] = __builtin_amdgcn_mfma_f32_16x16x32_bf16(vf, pf, accp[n], 0, 0, 0); \
        accb[n] = __builtin_amdgcn_mfma_f32_16x16x32_bf16(vf, bu.v8, accb[n], 0, 0, 0); \
    } \
} while (0)

    for (int kt = 0; kt < 8; kt++) {
        const int k0 = kt * 128;
        // stage V^T (cooperative, swizzled, double-buffered)
        {
            int kr = t >> 1, d0 = (t & 1) * 8;
            bf16x8 b8 = *(const bf16x8*)&v[((size_t)bh * LL + k0 + kr) * DHH + d0];
            __bf16* dst = Vl + (kt & 1) * 2048;
            #pragma unroll
            for (int i = 0; i < 8; i++) {
                int d = d0 + i;
                dst[d * 128 + (kr ^ ((d & 7) << 3))] = b8[i];
            }
        }
        __syncthreads();
        const __bf16* Vbuf = Vl + (kt & 1) * 2048;

        // S^T = K·Q^T  (A=K frag: row=k, kelems=dh; garbage dh>=16 ok, Q zeroed)
        f32x4 S0[8], S1[8];
        #pragma unroll
        for (int f = 0; f < 8; f++) {
            bf16x8 kf = *(const bf16x8*)&k[((size_t)bh * LL + k0 + f * 16 + qi) * DHH + (g & 1) * 8];
            S0[f] = __builtin_amdgcn_mfma_f32_16x16x32_bf16(kf, qf[0], zero4, 0, 0, 0);
            S1[f] = __builtin_amdgcn_mfma_f32_16x16x32_bf16(kf, qf[1], zero4, 0, 0, 0);
        }

        PROC_N(S0, 0);
        PROC_N(S1, 1);
    }
#undef PROC_N

    // epilogue: out = accp/l + accb ; C layout: col=q=lane&15, row=d=4g+r
    #pragma unroll
    for (int n = 0; n < 2; n++) {
        float inv = 1.0f / lrun[n];
        float4 o;
        o.x = accp[n][0] * inv + accb[n][0];
        o.y = accp[n][1] * inv + accb[n][1];
        o.z = accp[n][2] * inv + accb[n][2];
        o.w = accp[n][3] * inv + accb[n][3];
        *(float4*)&out[((size_t)bh * LL + qbase + n * 16 + qi) * DHH + g * 4] = o;
    }
}

// ---------- LN(attn_out) ; att = LN(x_src + .) ----------
__global__ __launch_bounds__(256) void k_ln(
    const float* __restrict__ ao,  const float* __restrict__ xsrc,
    const float* __restrict__ lag, const float* __restrict__ lab,
    const float* __restrict__ l1g, const float* __restrict__ l1b,
    float* __restrict__ att)
{
    const int lt = blockIdx.x, b = blockIdx.y;
    const int t = threadIdx.x;
    const int l0 = lt * 64;
    __shared__ float tile[64][132];

    #pragma unroll
    for (int u = 0; u < 4; u++) {
        int cid = u * 256 + t;               // 1024 chunks of 8
        int hh = cid >> 7, rem = cid & 127;
        int l = rem >> 1, dh0 = (rem & 1) * 8;
        const float* src = &ao[(((size_t)b * NHH + hh) * LL + l0 + l) * DHH + dh0];
        float4 a0 = *(const float4*)src;
        float4 a1 = *(const float4*)(src + 4);
        *(float4*)&tile[l][hh * 16 + dh0]     = a0;
        *(float4*)&tile[l][hh * 16 + dh0 + 4] = a1;
    }
    __syncthreads();

    const int wid = t >> 6, lane = t & 63;
    float2 ga  = *(const float2*)&lag[lane * 2];
    float2 ba  = *(const float2*)&lab[lane * 2];
    float2 g1v = *(const float2*)&l1g[lane * 2];
    float2 b1v = *(const float2*)&l1b[lane * 2];

    for (int rr = 0; rr < 16; rr++) {
        int r = wid * 16 + rr;
        float2 vv = *(const float2*)&tile[r][lane * 2];
        float s = vv.x + vv.y, s2 = vv.x * vv.x + vv.y * vv.y;
        #pragma unroll
        for (int m = 1; m < 64; m <<= 1) { s += __shfl_xor(s, m, 64); s2 += __shfl_xor(s2, m, 64); }
        float mu = s * (1.f / 128.f);
        float var = s2 * (1.f / 128.f) - mu * mu;
        float rs = rsqrtf(var + 1e-5f);
        float o0 = (vv.x - mu) * rs * ga.x + ba.x;
        float o1 = (vv.y - mu) * rs * ga.y + ba.y;
        float2 xv = *(const float2*)&xsrc[((size_t)b * LL + l0 + r) * DD + lane * 2];
        float t0 = xv.x + o0, t1 = xv.y + o1;
        s = t0 + t1; s2 = t0 * t0 + t1 * t1;
        #pragma unroll
        for (int m = 1; m < 64; m <<= 1) { s += __shfl_xor(s, m, 64); s2 += __shfl_xor(s2, m, 64); }
        mu = s * (1.f / 128.f);
        var = s2 * (1.f / 128.f) - mu * mu;
        rs = rsqrtf(var + 1e-5f);
        float a0 = (t0 - mu) * rs * g1v.x + b1v.x;
        float a1 = (t1 - mu) * rs * g1v.y + b1v.y;
        float2 o = {a0, a1};
        *(float2*)&att[((size_t)b * LL + l0 + r) * DD + lane * 2] = o;
    }
}

// ---------- ff1 = relu(att @ w1^T + b1) ----------
__global__ __launch_bounds__(256) void k_ff1(
    const float* __restrict__ att, const float* __restrict__ w1f,
    const float* __restrict__ b1f, float* __restrict__ ff1)
{
    const int lt = blockIdx.x, b = blockIdx.y, ng = blockIdx.z;
    const int l0 = lt * 64, n0 = ng * 128;
    const int t = threadIdx.x;
    __shared__ float xt[64][132];
    __shared__ float wt[16][132];

    #pragma unroll
    for (int u = 0; u < 8; u++) {
        int e = u * 256 + t;                  // 2048 f4
        int l = e >> 5, d0 = (e & 31) * 4;
        *(float4*)&xt[l][d0] = *(const float4*)&att[((size_t)b * LL + l0 + l) * DD + d0];
    }
    __syncthreads();

    const int lg = t >> 4, dg = t & 15;
    const int lth = lg * 4, nth = dg * 8;
    float acc[4][8];
    #pragma unroll
    for (int i = 0; i < 4; i++)
        #pragma unroll
        for (int j = 0; j < 8; j++) acc[i][j] = 0.0f;

    for (int kc = 0; kc < 8; kc++) {
        {
            int d = t >> 1, kk0 = (t & 1) * 8;
            const float* src = &w1f[(size_t)(n0 + d) * DD + kc * 16 + kk0];
            float4 v0 = *(const float4*)src;
            float4 v1 = *(const float4*)(src + 4);
            wt[kk0 + 0][d] = v0.x; wt[kk0 + 1][d] = v0.y;
            wt[kk0 + 2][d] = v0.z; wt[kk0 + 3][d] = v0.w;
            wt[kk0 + 4][d] = v1.x; wt[kk0 + 5][d] = v1.y;
            wt[kk0 + 6][d] = v1.z; wt[kk0 + 7][d] = v1.w;
        }
        __syncthreads();
        #pragma unroll
        for (int kk = 0; kk < 16; kk++) {
            int kx = kc * 16 + kk;
            float a0 = xt[lth + 0][kx], a1 = xt[lth + 1][kx];
            float a2 = xt[lth + 2][kx], a3 = xt[lth + 3][kx];
            float wvv[8];
            *(float4*)&wvv[0] = *(const float4*)&wt[kk][nth];
            *(float4*)&wvv[4] = *(const float4*)&wt[kk][nth + 4];
            #pragma unroll
            for (int j = 0; j < 8; j++) {
                acc[0][j] += a0 * wvv[j];
                acc[1][j] += a1 * wvv[j];
                acc[2][j] += a2 * wvv[j];
                acc[3][j] += a3 * wvv[j];
            }
        }
        __syncthreads();
    }
    float bvv[8];
    *(float4*)&bvv[0] = *(const float4*)&b1f[n0 + nth];
    *(float4*)&bvv[4] = *(const float4*)&b1f[n0 + nth + 4];
    #pragma unroll
    for (int i = 0; i < 4; i++) {
        float r[8];
        #pragma unroll
        for (int j = 0; j < 8; j++) r[j] = fmaxf(acc[i][j] + bvv[j], 0.0f);
        float* dst = &ff1[((size_t)b * LL + l0 + lth + i) * DF + n0 + nth];
        float4 o0 = {r[0], r[1], r[2], r[3]};
        float4 o1 = {r[4], r[5], r[6], r[7]};
        *(float4*)dst = o0;
        *(float4*)(dst + 4) = o1;
    }
}

// ---------- ff2 + residual + LN2 + transpose-store ----------
__global__ __launch_bounds__(256) void k_ff2(
    const float* __restrict__ ff1, const float* __restrict__ w2f,
    const float* __restrict__ b2f, const float* __restrict__ att,
    const float* __restrict__ l2g, const float* __restrict__ l2b,
    float* __restrict__ y)
{
    const int lt = blockIdx.x, b = blockIdx.y;
    const int l0 = lt * 64;
    const int t = threadIdx.x;
    __shared__ float fc[64][36];
    __shared__ float wt[32][132];
    __shared__ float yl[64][132];

    const int lg = t >> 4, dg = t & 15;
    const int lth = lg * 4, dth = dg * 8;
    float acc[4][8];
    #pragma unroll
    for (int i = 0; i < 4; i++)
        #pragma unroll
        for (int j = 0; j < 8; j++) acc[i][j] = 0.0f;

    for (int kc = 0; kc < 16; kc++) {
        {
            int l = t >> 2, k0 = (t & 3) * 8;
            const float* src = &ff1[((size_t)b * LL + l0 + l) * DF + kc * 32 + k0];
            float4 a0 = *(const float4*)src;
            float4 a1 = *(const float4*)(src + 4);
            *(float4*)&fc[l][k0]     = a0;
            *(float4*)&fc[l][k0 + 4] = a1;
        }
        {
            int d = t >> 1, kk0 = (t & 1) * 16;
            const float* src = &w2f[(size_t)d * DF + kc * 32 + kk0];
            float4 v0 = *(const float4*)src;
            float4 v1 = *(const float4*)(src + 4);
            float4 v2 = *(const float4*)(src + 8);
            float4 v3 = *(const float4*)(src + 12);
            wt[kk0 +  0][d] = v0.x; wt[kk0 +  1][d] = v0.y;
            wt[kk0 +  2][d] = v0.z; wt[kk0 +  3][d] = v0.w;
            wt[kk0 +  4][d] = v1.x; wt[kk0 +  5][d] = v1.y;
            wt[kk0 +  6][d] = v1.z; wt[kk0 +  7][d] = v1.w;
            wt[kk0 +  8][d] = v2.x; wt[kk0 +  9][d] = v2.y;
            wt[kk0 + 10][d] = v2.z; wt[kk0 + 11][d] = v2.w;
            wt[kk0 + 12][d] = v3.x; wt[kk0 + 13][d] = v3.y;
            wt[kk0 + 14][d] = v3.z; wt[kk0 + 15][d] = v3.w;
        }
        __syncthreads();
        #pragma unroll
        for (int kk = 0; kk < 32; kk++) {
            float a0 = fc[lth + 0][kk], a1 = fc[lth + 1][kk];
            float a2 = fc[lth + 2][kk], a3 = fc[lth + 3][kk];
            float wvv[8];
            *(float4*)&wvv[0] = *(const float4*)&wt[kk][dth];
            *(float4*)&wvv[4] = *(const float4*)&wt[kk][dth + 4];
            #pragma unroll
            for (int j = 0; j < 8; j++) {
                acc[0][j] += a0 * wvv[j];
                acc[1][j] += a1 * wvv[j];
                acc[2][j] += a2 * wvv[j];
                acc[3][j] += a3 * wvv[j];
            }
        }
        __syncthreads();
    }

    float bvv[8];
    *(float4*)&bvv[0] = *(const float4*)&b2f[dth];
    *(float4*)&bvv[4] = *(const float4*)&b2f[dth + 4];
    #pragma unroll
    for (int i = 0; i < 4; i++) {
        const float* ar = &att[((size_t)b * LL + l0 + lth + i) * DD + dth];
        float4 r0 = *(const float4*)ar;
        float4 r1 = *(const float4*)(ar + 4);
        float rv[8] = {r0.x, r0.y, r0.z, r0.w, r1.x, r1.y, r1.z, r1.w};
        #pragma unroll
        for (int j = 0; j < 8; j++)
            yl[lth + i][dth + j] = acc[i][j] + bvv[j] + rv[j];
    }
    __syncthreads();

    const int wid = t >> 6, lane = t & 63;
    float2 gv = *(const float2*)&l2g[lane * 2];
    float2 bv = *(const float2*)&l2b[lane * 2];
    for (int rr = 0; rr < 16; rr++) {
        int r = wid * 16 + rr;
        float2 vv = *(const float2*)&yl[r][lane * 2];
        float s = vv.x + vv.y, s2 = vv.x * vv.x + vv.y * vv.y;
        #pragma unroll
        for (int m = 1; m < 64; m <<= 1) { s += __shfl_xor(s, m, 64); s2 += __shfl_xor(s2, m, 64); }
        float mu = s * (1.f / 128.f);
        float var = s2 * (1.f / 128.f) - mu * mu;
        float rs = rsqrtf(var + 1e-5f);
        float o0 = (vv.x - mu) * rs * gv.x + bv.x;
        float o1 = (vv.y - mu) * rs * gv.y + bv.y;
        yl[r][lane * 2]     = o0;
        yl[r][lane * 2 + 1] = o1;
    }
    __syncthreads();

    {
        int d = t >> 1, lh = (t & 1) * 32;
        for (int i0 = 0; i0 < 32; i0 += 4) {
            float4 o = { yl[lh + i0 + 0][d], yl[lh + i0 + 1][d],
                         yl[lh + i0 + 2][d], yl[lh + i0 + 3][d] };
            *(float4*)&y[(size_t)b * DD * LL + (size_t)d * LL + l0 + lh + i0] = o;
        }
    }
}

extern "C" void kernel_launch(void* const* d_in, const int* in_sizes, int n_in,
                              void* d_out, int out_size, void* d_ws, size_t ws_size,
                              hipStream_t stream)
{
    const float* x   = (const float*)d_in[0];
    const float* c1w = (const float*)d_in[1];
    const float* c1b = (const float*)d_in[2];
    const float* g1  = (const float*)d_in[3];
    const float* bb1 = (const float*)d_in[4];
    const float* c2w = (const float*)d_in[5];
    const float* c2b = (const float*)d_in[6];
    const float* g2  = (const float*)d_in[7];
    const float* bb2 = (const float*)d_in[8];
    const float* wq  = (const float*)d_in[9];
    const float* wk  = (const float*)d_in[10];
    const float* wv  = (const float*)d_in[11];
    const float* rel = (const float*)d_in[12];
    const float* lag = (const float*)d_in[13];
    const float* lab = (const float*)d_in[14];
    const float* l1g = (const float*)d_in[15];
    const float* l1b = (const float*)d_in[16];
    const float* l2g = (const float*)d_in[17];
    const float* l2b = (const float*)d_in[18];
    const float* w1f = (const float*)d_in[19];
    const float* b1f = (const float*)d_in[20];
    const float* w2f = (const float*)d_in[21];
    const float* b2f = (const float*)d_in[22];

    float* ws = (float*)d_ws;
    const size_t NE = (size_t)BB * LL * DD;      // 2M floats
    float* xsrc = ws;                  // [0, NE)
    __bf16* qbuf = (__bf16*)(ws + NE);
    __bf16* kbuf = (__bf16*)(ws + 2 * NE);
    __bf16* vbuf = (__bf16*)(ws + 3 * NE);
    float* abuf = ws + 4 * NE;
    float* attb = ws + 5 * NE;
    float* base6 = ws + 6 * NE;        // prep region
    __bf16* w2bf = (__bf16*)base6;     // 1M bf16 = 2 MB
    float* w1A  = base6 + 524288;      // 512*8 f32
    float* b1A  = w1A + 4096;          // 512 f32
    float* ff1b = ws + NE;             // reuse q/k/v/abuf region: 4*NE = B*L*DFF

    k_prep_w2<<<dim3(1024), dim3(256), 0, stream>>>(c2w, w2bf);
    k_prep_w1<<<dim3(2), dim3(256), 0, stream>>>(c1w, c1b, g1, bb1, w1A, b1A);
    k_conv<<<dim3(16, 16), dim3(512), 0, stream>>>(x, w1A, b1A, w2bf, c2b, g2, bb2, xsrc);
    k_qkv<<<dim3(16, 16, 3), dim3(256), 0, stream>>>(xsrc, wq, wk, wv, qbuf, kbuf, vbuf);
    k_attn<<<dim3(128, 8), dim3(256), 0, stream>>>(qbuf, kbuf, vbuf, rel, abuf);
    k_ln<<<dim3(16, 16), dim3(256), 0, stream>>>(abuf, xsrc, lag, lab, l1g, l1b, attb);
    k_ff1<<<dim3(16, 16, 4), dim3(256), 0, stream>>>(attb, w1f, b1f, ff1b);
    k_ff2<<<dim3(16, 16), dim3(256), 0, stream>>>(ff1b, w2f, b2f, attb, l2g, l2b, (float*)d_out);
}

// Round 5
// 246.447 us; speedup vs baseline: 4.4986x; 1.3542x over previous
//
#include <hip/hip_runtime.h>
#include <math.h>

#define BB   16
#define CIN  16
#define LL   1024
#define DD   128
#define NHH  8
#define DHH  16
#define DF   512

#define INVS 0.9999950000374998f   // 1/sqrt(1+1e-5)
#define QSCALE 0.08838834764831845f

typedef __attribute__((ext_vector_type(4))) float f32x4;
typedef __attribute__((ext_vector_type(8))) __bf16 bf16x8;

// tanh-form GELU: v*sigmoid(1.59577*(v+0.044715 v^3)), |err vs erf| <= ~4e-4
__device__ __forceinline__ float gelu_t(float v) {
    float u = v * v;
    float a = v * fmaf(-0.07135481627f, u, -1.5957691216f);
    float e = __expf(a);
    return v * __builtin_amdgcn_rcpf(1.0f + e);
}

__device__ __forceinline__ unsigned pkbf(float a, float b) {
    union { __bf16 h[2]; unsigned u; } z;
    z.h[0] = (__bf16)a; z.h[1] = (__bf16)b;
    return z.u;
}

#define SWZ(l) ((((l) & 7) ^ (((l) >> 2) & 6)))

// ---------- one prep kernel: all weight conversions + PE table ----------
__global__ __launch_bounds__(256) void k_prep(
    const float* __restrict__ c2w,
    const float* __restrict__ wq, const float* __restrict__ wk,
    const float* __restrict__ wv,
    const float* __restrict__ w1f, const float* __restrict__ w2f,
    const float* __restrict__ c1w, const float* __restrict__ c1b,
    const float* __restrict__ g1,  const float* __restrict__ bb1,
    __bf16* __restrict__ w2bf,  __bf16* __restrict__ wallbf,
    __bf16* __restrict__ w1fbf, __bf16* __restrict__ w2fbf,
    float* __restrict__ peb, float* __restrict__ w1A, float* __restrict__ b1A)
{
    const int bid = blockIdx.x;
    const int t = threadIdx.x;
    if (bid < 1024) {                       // w2: 1M elems
        int i = (bid * 256 + t) * 4;
        float4 v = *(const float4*)&c2w[i];
        union { __bf16 h[4]; float2 f2; } u;
        u.h[0] = (__bf16)v.x; u.h[1] = (__bf16)v.y;
        u.h[2] = (__bf16)v.z; u.h[3] = (__bf16)v.w;
        *(float2*)&w2bf[i] = u.f2;
    } else if (bid < 1072) {                // wq|wk|wv: 3*16384, wq pre-scaled
        int e = ((bid - 1024) * 256 + t) * 4;
        int sel = e >> 14, r = e & 16383;
        const float* src = (sel == 0) ? wq : ((sel == 1) ? wk : wv);
        float sc = (sel == 0) ? QSCALE : 1.0f;
        float4 v = *(const float4*)&src[r];
        union { __bf16 h[4]; float2 f2; } u;
        u.h[0] = (__bf16)(v.x * sc); u.h[1] = (__bf16)(v.y * sc);
        u.h[2] = (__bf16)(v.z * sc); u.h[3] = (__bf16)(v.w * sc);
        *(float2*)&wallbf[e] = u.f2;
    } else if (bid < 1136) {                // w1f: 65536
        int e = ((bid - 1072) * 256 + t) * 4;
        float4 v = *(const float4*)&w1f[e];
        union { __bf16 h[4]; float2 f2; } u;
        u.h[0] = (__bf16)v.x; u.h[1] = (__bf16)v.y;
        u.h[2] = (__bf16)v.z; u.h[3] = (__bf16)v.w;
        *(float2*)&w1fbf[e] = u.f2;
    } else if (bid < 1200) {                // w2f: 65536
        int e = ((bid - 1136) * 256 + t) * 4;
        float4 v = *(const float4*)&w2f[e];
        union { __bf16 h[4]; float2 f2; } u;
        u.h[0] = (__bf16)v.x; u.h[1] = (__bf16)v.y;
        u.h[2] = (__bf16)v.z; u.h[3] = (__bf16)v.w;
        *(float2*)&w2fbf[e] = u.f2;
    } else if (bid < 1456) {                // PE table: 65536 (l, j) pairs
        int p = (bid - 1200) * 256 + t;
        int l = p >> 6, jj = p & 63;
        float ang = (float)l * expf(-0.14391156831212787f * (float)jj) * 0.125f;
        peb[l * 128 + jj * 2]     = sinf(ang);
        peb[l * 128 + jj * 2 + 1] = cosf(ang);
    } else {                                // fold BN1 into conv1 weights
        for (int o = t; o < DF; o += 256) {
            float A = g1[o] * INVS;
            #pragma unroll
            for (int tp = 0; tp < 7; tp++) w1A[o * 8 + tp] = c1w[o * 7 + tp] * A;
            w1A[o * 8 + 7] = 0.0f;
            b1A[o] = fmaf(c1b[o], A, bb1[o]);
        }
    }
}

// ---------- fused conv1+BN1+GELU -> bf16 MFMA conv2 GEMM -> BN2+GELU -> xsrc ----------
// 256 threads (4 waves), 32l x 128d tile, grid (32,16): ~2 blocks/CU
__global__ __launch_bounds__(256) void k_conv(
    const float* __restrict__ x,
    const float* __restrict__ w1A, const float* __restrict__ b1A,
    const __bf16* __restrict__ w2bf,
    const float* __restrict__ c2b, const float* __restrict__ g2,
    const float* __restrict__ bb2,
    float* __restrict__ xsrc)
{
    const int lt = blockIdx.x;      // 32 tiles of 32 l
    const int b  = blockIdx.y;      // 16
    const int t  = threadIdx.x;
    const int l0 = lt * 32;

    __shared__ float xs[CIN][40];
    __shared__ __align__(16) __bf16 Ab[2][32 * 128];

    for (int idx = t; idx < CIN * 38; idx += 256) {
        int c = idx / 38, i = idx % 38;
        int l = l0 - 3 + i;
        xs[c][i] = (l >= 0 && l < LL) ? x[(b * CIN + c) * LL + l] : 0.0f;
    }
    __syncthreads();

    // conv mapping: c-pair(8) x l-quad(8) x o-group(4, wave-uniform)
    const int cp  = t & 7;
    const int lqi = (t >> 3) & 7;
    const int ogu = __builtin_amdgcn_readfirstlane(t >> 6);
    const int c0  = cp * 2;
    const int lq  = lqi * 4;

    float xw[2][10];
    #pragma unroll
    for (int j = 0; j < 10; j++) {
        xw[0][j] = xs[c0][lq + j];
        xw[1][j] = xs[c0 + 1][lq + j];
    }

    const int lane = t & 63;
    const int l15 = lane & 15, kg = lane >> 4;
    const int nw = t >> 6;

    f32x4 acc[2][2];
    #pragma unroll
    for (int mf = 0; mf < 2; mf++)
        #pragma unroll
        for (int nf = 0; nf < 2; nf++) acc[mf][nf] = (f32x4){0.f, 0.f, 0.f, 0.f};

    bf16x8 breg[2][8];

#define BLOAD(CH, BUF) do { \
    _Pragma("unroll") \
    for (int nf = 0; nf < 2; nf++) \
        _Pragma("unroll") \
        for (int kk = 0; kk < 4; kk++) \
            breg[BUF][nf * 4 + kk] = *(const bf16x8*)&w2bf[ \
                (size_t)(nw * 32 + nf * 16 + l15) * 8192 + (size_t)(CH) * 128 + kk * 32 + kg * 8]; \
} while (0)

#define CONV_CHUNK(BUF, CH) do { \
    _Pragma("unroll") \
    for (int j = 0; j < 2; j++) { \
        int o = (CH) * 8 + ogu * 2 + j; \
        f32x4 wA = *(const f32x4*)&w1A[o * 8]; \
        f32x4 wB = *(const f32x4*)&w1A[o * 8 + 4]; \
        float bias = b1A[o]; \
        int kcol = (ogu * 2 + j) * 16 + c0; \
        _Pragma("unroll") \
        for (int dl = 0; dl < 4; dl++) { \
            float h2[2]; \
            _Pragma("unroll") \
            for (int ci = 0; ci < 2; ci++) { \
                float s = fmaf(xw[ci][dl], wA[0], bias); \
                s = fmaf(xw[ci][dl + 1], wA[1], s); \
                s = fmaf(xw[ci][dl + 2], wA[2], s); \
                s = fmaf(xw[ci][dl + 3], wA[3], s); \
                s = fmaf(xw[ci][dl + 4], wB[0], s); \
                s = fmaf(xw[ci][dl + 5], wB[1], s); \
                s = fmaf(xw[ci][dl + 6], wB[2], s); \
                h2[ci] = gelu_t(s); \
            } \
            int l = lq + dl; \
            *(unsigned*)&Ab[BUF][l * 128 + (kcol ^ (SWZ(l) << 3))] = pkbf(h2[0], h2[1]); \
        } \
    } \
} while (0)

#define MFMA_CHUNK(BUF, BI) do { \
    _Pragma("unroll") \
    for (int kk = 0; kk < 4; kk++) { \
        int kb = kk * 32 + kg * 8; \
        bf16x8 af[2]; \
        _Pragma("unroll") \
        for (int mf = 0; mf < 2; mf++) { \
            int r = mf * 16 + l15; \
            af[mf] = *(const bf16x8*)&Ab[BUF][r * 128 + (kb ^ (SWZ(r) << 3))]; \
        } \
        _Pragma("unroll") \
        for (int mf = 0; mf < 2; mf++) \
            _Pragma("unroll") \
            for (int nf = 0; nf < 2; nf++) \
                acc[mf][nf] = __builtin_amdgcn_mfma_f32_16x16x32_bf16( \
                    af[mf], breg[BI][nf * 4 + kk], acc[mf][nf], 0, 0, 0); \
    } \
} while (0)

    BLOAD(0, 0);
    CONV_CHUNK(0, 0);
    __syncthreads();

    for (int ic = 0; ic < 62; ic += 2) {
        BLOAD(ic + 1, 1);
        MFMA_CHUNK(0, 0);
        CONV_CHUNK(1, ic + 1);
        __syncthreads();

        BLOAD(ic + 2, 0);
        MFMA_CHUNK(1, 1);
        CONV_CHUNK(0, ic + 2);
        __syncthreads();
    }
    BLOAD(63, 1);
    MFMA_CHUNK(0, 0);
    CONV_CHUNK(1, 63);
    __syncthreads();
    MFMA_CHUNK(1, 1);

    // epilogue: BN2 + GELU
    #pragma unroll
    for (int mf = 0; mf < 2; mf++) {
        #pragma unroll
        for (int nf = 0; nf < 2; nf++) {
            int d = nw * 32 + nf * 16 + l15;
            float A2 = g2[d] * INVS;
            float B2 = fmaf(c2b[d], A2, bb2[d]);
            #pragma unroll
            for (int r = 0; r < 4; r++) {
                int l = l0 + mf * 16 + kg * 4 + r;
                xsrc[((size_t)b * LL + l) * DD + d] = gelu_t(fmaf(acc[mf][nf][r], A2, B2));
            }
        }
    }
#undef BLOAD
#undef CONV_CHUNK
#undef MFMA_CHUNK
}

// ---------- qkv via MFMA: x_pos = xsrc + PE (bf16), out = x_pos @ W^T ----------
// 384 threads (6 waves): wave w covers 64 outputs of [q|k|v] (wq pre-scaled)
__global__ __launch_bounds__(384) void k_qkv(
    const float* __restrict__ xsrc, const float* __restrict__ peb,
    const __bf16* __restrict__ wallbf,
    __bf16* __restrict__ qo, __bf16* __restrict__ ko, __bf16* __restrict__ vo)
{
    const int lt = blockIdx.x, b = blockIdx.y;
    const int t = threadIdx.x;
    const int l0 = lt * 64;

    __shared__ __align__(16) __bf16 Xp[64 * 128];

    for (int e = t; e < 2048; e += 384) {
        int l = e >> 5, d0 = (e & 31) * 4;
        float4 xv = *(const float4*)&xsrc[((size_t)b * LL + l0 + l) * DD + d0];
        float4 pv = *(const float4*)&peb[(size_t)(l0 + l) * DD + d0];
        union { __bf16 h[4]; float2 f2; } u;
        u.h[0] = (__bf16)(xv.x + pv.x); u.h[1] = (__bf16)(xv.y + pv.y);
        u.h[2] = (__bf16)(xv.z + pv.z); u.h[3] = (__bf16)(xv.w + pv.w);
        *(float2*)&Xp[l * 128 + (d0 ^ (SWZ(l) << 3))] = u.f2;
    }
    __syncthreads();

    const int w = t >> 6, lane = t & 63;
    const int l15 = lane & 15, kg = lane >> 4;
    const int wsel = w >> 1, hb = w & 1;

    bf16x8 breg[16];
    #pragma unroll
    for (int nf = 0; nf < 4; nf++)
        #pragma unroll
        for (int kk = 0; kk < 4; kk++)
            breg[nf * 4 + kk] = *(const bf16x8*)&wallbf[
                (size_t)wsel * 16384 + (size_t)(hb * 64 + nf * 16 + l15) * 128 + kk * 32 + kg * 8];

    f32x4 acc[4][4];
    #pragma unroll
    for (int mf = 0; mf < 4; mf++)
        #pragma unroll
        for (int nf = 0; nf < 4; nf++) acc[mf][nf] = (f32x4){0.f, 0.f, 0.f, 0.f};

    #pragma unroll
    for (int kk = 0; kk < 4; kk++) {
        int kb = kk * 32 + kg * 8;
        bf16x8 af[4];
        #pragma unroll
        for (int mf = 0; mf < 4; mf++) {
            int r = mf * 16 + l15;
            af[mf] = *(const bf16x8*)&Xp[r * 128 + (kb ^ (SWZ(r) << 3))];
        }
        #pragma unroll
        for (int mf = 0; mf < 4; mf++)
            #pragma unroll
            for (int nf = 0; nf < 4; nf++)
                acc[mf][nf] = __builtin_amdgcn_mfma_f32_16x16x32_bf16(
                    af[mf], breg[nf * 4 + kk], acc[mf][nf], 0, 0, 0);
    }

    __bf16* op = (wsel == 0) ? qo : ((wsel == 1) ? ko : vo);
    #pragma unroll
    for (int mf = 0; mf < 4; mf++) {
        #pragma unroll
        for (int nf = 0; nf < 4; nf++) {
            int h = hb * 4 + nf;
            #pragma unroll
            for (int r = 0; r < 4; r++) {
                int l = l0 + mf * 16 + kg * 4 + r;
                op[(((size_t)b * NHH + h) * LL + l) * DHH + l15] = (__bf16)acc[mf][nf][r];
            }
        }
    }
}

// ---------- attention via MFMA: softmax(QK^T*s)@V + relbias@V  (flash) ----------
__global__ __launch_bounds__(256) void k_attn(
    const __bf16* __restrict__ q, const __bf16* __restrict__ k,
    const __bf16* __restrict__ v, const float* __restrict__ rel,
    float* __restrict__ out)
{
    const int bh = blockIdx.x;           // 128
    const int qt = blockIdx.y;           // 8 tiles of 128 q
    const int h  = bh & 7;
    const int t  = threadIdx.x;
    const int w  = t >> 6, lane = t & 63;
    const int g  = lane >> 4, qi = lane & 15;
    const int xq = (qi & 7) << 3;
    const int qbase = qt * 128 + w * 32;

    __shared__ __align__(16) __bf16 lds[16384];
    __bf16* Vl = lds;                    // 4096
    __bf16* Pw = lds + 4096 + w * 2048;  // per-wave 2048
    __bf16* R0 = lds + 12288;            // 2048
    __bf16* R1 = lds + 14336;            // 2048

    for (int i = t; i < 2048; i += 256) {
        R0[i] = (__bf16)((i <= 2046) ? rel[(size_t)(2046 - i) * NHH + h] : 0.0f);
        R1[i] = (__bf16)((i <= 2045) ? rel[(size_t)(2045 - i) * NHH + h] : 0.0f);
    }

    bf16x8 qf[2];
    {
        union { unsigned u[4]; bf16x8 v8; } uz;
        uz.u[0] = uz.u[1] = uz.u[2] = uz.u[3] = 0u;
        #pragma unroll
        for (int n = 0; n < 2; n++) {
            qf[n] = uz.v8;
            if (g < 2)
                qf[n] = *(const bf16x8*)&q[((size_t)bh * LL + qbase + n * 16 + qi) * DHH + g * 8];
        }
    }

    f32x4 accp[2], accb[2];
    #pragma unroll
    for (int n = 0; n < 2; n++) {
        accp[n] = (f32x4){0.f, 0.f, 0.f, 0.f};
        accb[n] = (f32x4){0.f, 0.f, 0.f, 0.f};
    }
    float mrun[2] = {-INFINITY, -INFINITY};
    float lrun[2] = {0.f, 0.f};

    const f32x4 zero4 = (f32x4){0.f, 0.f, 0.f, 0.f};

#define PROC_N(Sn, n) do { \
    float mx = Sn[0][0]; \
    _Pragma("unroll") \
    for (int f = 0; f < 8; f++) { \
        _Pragma("unroll") \
        for (int r = 0; r < 4; r++) if (f || r) mx = fmaxf(mx, Sn[f][r]); } \
    mx = fmaxf(mx, __shfl_xor(mx, 16, 64)); \
    mx = fmaxf(mx, __shfl_xor(mx, 32, 64)); \
    float mnew = fmaxf(mrun[n], mx); \
    float sf = __expf(mrun[n] - mnew); \
    mrun[n] = mnew; \
    lrun[n] *= sf; \
    accp[n][0] *= sf; accp[n][1] *= sf; accp[n][2] *= sf; accp[n][3] *= sf; \
    float ls = 0.f; \
    _Pragma("unroll") \
    for (int f = 0; f < 8; f++) { \
        float p0 = __expf(Sn[f][0] - mnew), p1 = __expf(Sn[f][1] - mnew); \
        float p2 = __expf(Sn[f][2] - mnew), p3 = __expf(Sn[f][3] - mnew); \
        ls += (p0 + p1) + (p2 + p3); \
        unsigned* pp = (unsigned*)(Pw + (qi * 128 + ((f * 16 + g * 4) ^ xq))); \
        pp[0] = pkbf(p0, p1); pp[1] = pkbf(p2, p3); \
    } \
    ls += __shfl_xor(ls, 16, 64); ls += __shfl_xor(ls, 32, 64); \
    lrun[n] += ls; \
    int qoff = 1023 - (qbase + (n) * 16 + qi) + k0; \
    _Pragma("unroll") \
    for (int c = 0; c < 4; c++) { \
        bf16x8 vf = *(const bf16x8*)&Vbuf[qi * 128 + ((c * 32 + g * 8) ^ xq)]; \
        bf16x8 pf = *(const bf16x8*)&Pw[qi * 128 + ((c * 32 + g * 8) ^ xq)]; \
        int idx = qoff + c * 32 + 8 * g; \
        const unsigned* tb = (const unsigned*)((idx & 1) ? R1 : R0); \
        unsigned s_ = (unsigned)idx >> 1; \
        union { unsigned u[4]; bf16x8 v8; } bu; \
        bu.u[0] = tb[s_]; bu.u[1] = tb[s_ + 1]; \
        bu.u[2] = tb[s_ + 2]; bu.u[3] = tb[s_ + 3]; \
        accp[n] = __builtin_amdgcn_mfma_f32_16x16x32_bf16(vf, pf, accp[n], 0, 0, 0); \
        accb[n] = __builtin_amdgcn_mfma_f32_16x16x32_bf16(vf, bu.v8, accb[n], 0, 0, 0); \
    } \
} while (0)

    for (int kt = 0; kt < 8; kt++) {
        const int k0 = kt * 128;
        {
            int kr = t >> 1, d0 = (t & 1) * 8;
            bf16x8 b8 = *(const bf16x8*)&v[((size_t)bh * LL + k0 + kr) * DHH + d0];
            __bf16* dst = Vl + (kt & 1) * 2048;
            #pragma unroll
            for (int i = 0; i < 8; i++) {
                int d = d0 + i;
                dst[d * 128 + (kr ^ ((d & 7) << 3))] = b8[i];
            }
        }
        __syncthreads();
        const __bf16* Vbuf = Vl + (kt & 1) * 2048;

        f32x4 S0[8], S1[8];
        #pragma unroll
        for (int f = 0; f < 8; f++) {
            bf16x8 kf = *(const bf16x8*)&k[((size_t)bh * LL + k0 + f * 16 + qi) * DHH + (g & 1) * 8];
            S0[f] = __builtin_amdgcn_mfma_f32_16x16x32_bf16(kf, qf[0], zero4, 0, 0, 0);
            S1[f] = __builtin_amdgcn_mfma_f32_16x16x32_bf16(kf, qf[1], zero4, 0, 0, 0);
        }

        PROC_N(S0, 0);
        PROC_N(S1, 1);
    }
#undef PROC_N

    #pragma unroll
    for (int n = 0; n < 2; n++) {
        float inv = 1.0f / lrun[n];
        float4 o;
        o.x = accp[n][0] * inv + accb[n][0];
        o.y = accp[n][1] * inv + accb[n][1];
        o.z = accp[n][2] * inv + accb[n][2];
        o.w = accp[n][3] * inv + accb[n][3];
        *(float4*)&out[((size_t)bh * LL + qbase + n * 16 + qi) * DHH + g * 4] = o;
    }
}

// ---------- LN(attn_out) ; att = LN(x_src + .) ----------
__global__ __launch_bounds__(256) void k_ln(
    const float* __restrict__ ao,  const float* __restrict__ xsrc,
    const float* __restrict__ lag, const float* __restrict__ lab,
    const float* __restrict__ l1g, const float* __restrict__ l1b,
    float* __restrict__ att)
{
    const int lt = blockIdx.x, b = blockIdx.y;
    const int t = threadIdx.x;
    const int l0 = lt * 64;
    __shared__ float tile[64][132];

    #pragma unroll
    for (int u = 0; u < 4; u++) {
        int cid = u * 256 + t;
        int hh = cid >> 7, rem = cid & 127;
        int l = rem >> 1, dh0 = (rem & 1) * 8;
        const float* src = &ao[(((size_t)b * NHH + hh) * LL + l0 + l) * DHH + dh0];
        float4 a0 = *(const float4*)src;
        float4 a1 = *(const float4*)(src + 4);
        *(float4*)&tile[l][hh * 16 + dh0]     = a0;
        *(float4*)&tile[l][hh * 16 + dh0 + 4] = a1;
    }
    __syncthreads();

    const int wid = t >> 6, lane = t & 63;
    float2 ga  = *(const float2*)&lag[lane * 2];
    float2 ba  = *(const float2*)&lab[lane * 2];
    float2 g1v = *(const float2*)&l1g[lane * 2];
    float2 b1v = *(const float2*)&l1b[lane * 2];

    for (int rr = 0; rr < 16; rr++) {
        int r = wid * 16 + rr;
        float2 vv = *(const float2*)&tile[r][lane * 2];
        float s = vv.x + vv.y, s2 = vv.x * vv.x + vv.y * vv.y;
        #pragma unroll
        for (int m = 1; m < 64; m <<= 1) { s += __shfl_xor(s, m, 64); s2 += __shfl_xor(s2, m, 64); }
        float mu = s * (1.f / 128.f);
        float var = s2 * (1.f / 128.f) - mu * mu;
        float rs = rsqrtf(var + 1e-5f);
        float o0 = (vv.x - mu) * rs * ga.x + ba.x;
        float o1 = (vv.y - mu) * rs * ga.y + ba.y;
        float2 xv = *(const float2*)&xsrc[((size_t)b * LL + l0 + r) * DD + lane * 2];
        float t0 = xv.x + o0, t1 = xv.y + o1;
        s = t0 + t1; s2 = t0 * t0 + t1 * t1;
        #pragma unroll
        for (int m = 1; m < 64; m <<= 1) { s += __shfl_xor(s, m, 64); s2 += __shfl_xor(s2, m, 64); }
        mu = s * (1.f / 128.f);
        var = s2 * (1.f / 128.f) - mu * mu;
        rs = rsqrtf(var + 1e-5f);
        float a0 = (t0 - mu) * rs * g1v.x + b1v.x;
        float a1 = (t1 - mu) * rs * g1v.y + b1v.y;
        float2 o = {a0, a1};
        *(float2*)&att[((size_t)b * LL + l0 + r) * DD + lane * 2] = o;
    }
}

// ---------- ff1 = relu(att @ w1^T + b1) -> bf16, MFMA ----------
__global__ __launch_bounds__(512) void k_ff1(
    const float* __restrict__ att, const __bf16* __restrict__ w1fbf,
    const float* __restrict__ b1f, __bf16* __restrict__ ff1b)
{
    const int lt = blockIdx.x, b = blockIdx.y;
    const int t = threadIdx.x;
    const int l0 = lt * 64;

    __shared__ __align__(16) __bf16 Ax[64 * 128];

    #pragma unroll
    for (int it = 0; it < 4; it++) {
        int e = it * 512 + t;
        int l = e >> 5, d0 = (e & 31) * 4;
        float4 xv = *(const float4*)&att[((size_t)b * LL + l0 + l) * DD + d0];
        union { __bf16 h[4]; float2 f2; } u;
        u.h[0] = (__bf16)xv.x; u.h[1] = (__bf16)xv.y;
        u.h[2] = (__bf16)xv.z; u.h[3] = (__bf16)xv.w;
        *(float2*)&Ax[l * 128 + (d0 ^ (SWZ(l) << 3))] = u.f2;
    }
    __syncthreads();

    const int w = t >> 6, lane = t & 63;
    const int l15 = lane & 15, kg = lane >> 4;

    bf16x8 breg[16];
    #pragma unroll
    for (int nf = 0; nf < 4; nf++)
        #pragma unroll
        for (int kk = 0; kk < 4; kk++)
            breg[nf * 4 + kk] = *(const bf16x8*)&w1fbf[
                (size_t)(w * 64 + nf * 16 + l15) * 128 + kk * 32 + kg * 8];

    f32x4 acc[4][4];
    #pragma unroll
    for (int mf = 0; mf < 4; mf++)
        #pragma unroll
        for (int nf = 0; nf < 4; nf++) acc[mf][nf] = (f32x4){0.f, 0.f, 0.f, 0.f};

    #pragma unroll
    for (int kk = 0; kk < 4; kk++) {
        int kb = kk * 32 + kg * 8;
        bf16x8 af[4];
        #pragma unroll
        for (int mf = 0; mf < 4; mf++) {
            int r = mf * 16 + l15;
            af[mf] = *(const bf16x8*)&Ax[r * 128 + (kb ^ (SWZ(r) << 3))];
        }
        #pragma unroll
        for (int mf = 0; mf < 4; mf++)
            #pragma unroll
            for (int nf = 0; nf < 4; nf++)
                acc[mf][nf] = __builtin_amdgcn_mfma_f32_16x16x32_bf16(
                    af[mf], breg[nf * 4 + kk], acc[mf][nf], 0, 0, 0);
    }

    #pragma unroll
    for (int nf = 0; nf < 4; nf++) {
        int n = w * 64 + nf * 16 + l15;
        float bias = b1f[n];
        #pragma unroll
        for (int mf = 0; mf < 4; mf++) {
            #pragma unroll
            for (int r = 0; r < 4; r++) {
                int l = l0 + mf * 16 + kg * 4 + r;
                float vv = fmaxf(acc[mf][nf][r] + bias, 0.0f);
                ff1b[((size_t)b * LL + l) * DF + n] = (__bf16)vv;
            }
        }
    }
}

// ---------- ff2 (MFMA, K=512) + bias + residual + LN2 + transpose-store ----------
__global__ __launch_bounds__(512) void k_ff2(
    const __bf16* __restrict__ ff1b, const __bf16* __restrict__ w2fbf,
    const float* __restrict__ b2f, const float* __restrict__ att,
    const float* __restrict__ l2g, const float* __restrict__ l2b,
    float* __restrict__ y)
{
    const int lt = blockIdx.x, b = blockIdx.y;
    const int t = threadIdx.x;
    const int l0 = lt * 64;

    __shared__ __align__(16) __bf16 Ax[64 * 512];   // 64KB; reused as yl after GEMM
    float* yl = (float*)Ax;                          // [64][132] overlay

    #pragma unroll
    for (int it = 0; it < 8; it++) {
        int g8 = it * 512 + t;                       // 4096 granules of 8
        int l = g8 >> 6, c8 = g8 & 63;
        bf16x8 v8 = *(const bf16x8*)&ff1b[((size_t)b * LL + l0 + l) * DF + c8 * 8];
        *(bf16x8*)&Ax[l * 512 + ((c8 * 8) ^ (SWZ(l) << 3))] = v8;
    }
    __syncthreads();

    const int w = t >> 6, lane = t & 63;
    const int l15 = lane & 15, kg = lane >> 4;
    const int d = w * 16 + l15;

    bf16x8 breg[16];
    #pragma unroll
    for (int kk = 0; kk < 16; kk++)
        breg[kk] = *(const bf16x8*)&w2fbf[(size_t)d * DF + kk * 32 + kg * 8];

    f32x4 acc[4];
    #pragma unroll
    for (int mf = 0; mf < 4; mf++) acc[mf] = (f32x4){0.f, 0.f, 0.f, 0.f};

    #pragma unroll
    for (int kk = 0; kk < 16; kk++) {
        int kb = kk * 32 + kg * 8;
        #pragma unroll
        for (int mf = 0; mf < 4; mf++) {
            int r = mf * 16 + l15;
            bf16x8 af = *(const bf16x8*)&Ax[r * 512 + (kb ^ (SWZ(r) << 3))];
            acc[mf] = __builtin_amdgcn_mfma_f32_16x16x32_bf16(af, breg[kk], acc[mf], 0, 0, 0);
        }
    }
    __syncthreads();   // Ax reads done; overlay as yl

    {
        float bias = b2f[d];
        #pragma unroll
        for (int mf = 0; mf < 4; mf++) {
            #pragma unroll
            for (int r = 0; r < 4; r++) {
                int l = mf * 16 + kg * 4 + r;
                float res = att[((size_t)b * LL + l0 + l) * DD + d];
                yl[l * 132 + d] = acc[mf][r] + bias + res;
            }
        }
    }
    __syncthreads();

    const int wid = t >> 6;
    float2 gv = *(const float2*)&l2g[lane * 2];
    float2 bv = *(const float2*)&l2b[lane * 2];
    for (int rr = 0; rr < 8; rr++) {
        int r = wid * 8 + rr;
        float2 vv = *(const float2*)&yl[r * 132 + lane * 2];
        float s = vv.x + vv.y, s2 = vv.x * vv.x + vv.y * vv.y;
        #pragma unroll
        for (int m = 1; m < 64; m <<= 1) { s += __shfl_xor(s, m, 64); s2 += __shfl_xor(s2, m, 64); }
        float mu = s * (1.f / 128.f);
        float var = s2 * (1.f / 128.f) - mu * mu;
        float rs = rsqrtf(var + 1e-5f);
        float o0 = (vv.x - mu) * rs * gv.x + bv.x;
        float o1 = (vv.y - mu) * rs * gv.y + bv.y;
        yl[r * 132 + lane * 2]     = o0;
        yl[r * 132 + lane * 2 + 1] = o1;
    }
    __syncthreads();

    {
        int dd = t >> 2, lh = (t & 3) * 16;
        #pragma unroll
        for (int i0 = 0; i0 < 16; i0 += 4) {
            float4 o = { yl[(lh + i0 + 0) * 132 + dd], yl[(lh + i0 + 1) * 132 + dd],
                         yl[(lh + i0 + 2) * 132 + dd], yl[(lh + i0 + 3) * 132 + dd] };
            *(float4*)&y[(size_t)b * DD * LL + (size_t)dd * LL + l0 + lh + i0] = o;
        }
    }
}

extern "C" void kernel_launch(void* const* d_in, const int* in_sizes, int n_in,
                              void* d_out, int out_size, void* d_ws, size_t ws_size,
                              hipStream_t stream)
{
    const float* x   = (const float*)d_in[0];
    const float* c1w = (const float*)d_in[1];
    const float* c1b = (const float*)d_in[2];
    const float* g1  = (const float*)d_in[3];
    const float* bb1 = (const float*)d_in[4];
    const float* c2w = (const float*)d_in[5];
    const float* c2b = (const float*)d_in[6];
    const float* g2  = (const float*)d_in[7];
    const float* bb2 = (const float*)d_in[8];
    const float* wq  = (const float*)d_in[9];
    const float* wk  = (const float*)d_in[10];
    const float* wv  = (const float*)d_in[11];
    const float* rel = (const float*)d_in[12];
    const float* lag = (const float*)d_in[13];
    const float* lab = (const float*)d_in[14];
    const float* l1g = (const float*)d_in[15];
    const float* l1b = (const float*)d_in[16];
    const float* l2g = (const float*)d_in[17];
    const float* l2b = (const float*)d_in[18];
    const float* w1f = (const float*)d_in[19];
    const float* b1f = (const float*)d_in[20];
    const float* w2f = (const float*)d_in[21];
    const float* b2f = (const float*)d_in[22];

    char* W = (char*)d_ws;
    const size_t MB = 1ull << 20;
    float*  xsrc   = (float*)(W);
    float*  abuf   = (float*)(W + 8 * MB);
    float*  attb   = (float*)(W + 16 * MB);
    __bf16* qbuf   = (__bf16*)(W + 24 * MB);
    __bf16* kbuf   = (__bf16*)(W + 28 * MB);
    __bf16* vbuf   = (__bf16*)(W + 32 * MB);
    __bf16* ff1b   = (__bf16*)(W + 36 * MB);
    __bf16* w2bf   = (__bf16*)(W + 52 * MB);
    __bf16* wallbf = (__bf16*)(W + 54 * MB);
    __bf16* w1fbf  = (__bf16*)(W + 54 * MB + 128 * 1024);
    __bf16* w2fbf  = (__bf16*)(W + 54 * MB + 256 * 1024);
    float*  peb    = (float*)(W + 54 * MB + 384 * 1024);
    float*  w1A    = (float*)(W + 54 * MB + 896 * 1024);
    float*  b1A    = (float*)(W + 54 * MB + 912 * 1024);

    k_prep<<<dim3(1457), dim3(256), 0, stream>>>(
        c2w, wq, wk, wv, w1f, w2f, c1w, c1b, g1, bb1,
        w2bf, wallbf, w1fbf, w2fbf, peb, w1A, b1A);
    k_conv<<<dim3(32, 16), dim3(256), 0, stream>>>(x, w1A, b1A, w2bf, c2b, g2, bb2, xsrc);
    k_qkv<<<dim3(16, 16), dim3(384), 0, stream>>>(xsrc, peb, wallbf, qbuf, kbuf, vbuf);
    k_attn<<<dim3(128, 8), dim3(256), 0, stream>>>(qbuf, kbuf, vbuf, rel, abuf);
    k_ln<<<dim3(16, 16), dim3(256), 0, stream>>>(abuf, xsrc, lag, lab, l1g, l1b, attb);
    k_ff1<<<dim3(16, 16), dim3(512), 0, stream>>>(attb, w1fbf, b1f, ff1b);
    k_ff2<<<dim3(16, 16), dim3(512), 0, stream>>>(ff1b, w2fbf, b2f, attb, l2g, l2b, (float*)d_out);
}

// Round 6
// 240.695 us; speedup vs baseline: 4.6061x; 1.0239x over previous
//
#include <hip/hip_runtime.h>
#include <math.h>

#define BB   16
#define CIN  16
#define LL   1024
#define DD   128
#define NHH  8
#define DHH  16
#define DF   512

#define INVS 0.9999950000374998f   // 1/sqrt(1+1e-5)
#define QSCALE 0.08838834764831845f

typedef __attribute__((ext_vector_type(4))) float f32x4;
typedef __attribute__((ext_vector_type(8))) __bf16 bf16x8;

// tanh-form GELU: v*sigmoid(1.59577*(v+0.044715 v^3)), |err vs erf| <= ~4e-4
__device__ __forceinline__ float gelu_t(float v) {
    float u = v * v;
    float a = v * fmaf(-0.07135481627f, u, -1.5957691216f);
    float e = __expf(a);
    return v * __builtin_amdgcn_rcpf(1.0f + e);
}

__device__ __forceinline__ unsigned pkbf(float a, float b) {
    union { __bf16 h[2]; unsigned u; } z;
    z.h[0] = (__bf16)a; z.h[1] = (__bf16)b;
    return z.u;
}

#define SWZ(l) ((((l) & 7) ^ (((l) >> 2) & 6)))

// ---------- one prep kernel: all weight conversions + PE table ----------
__global__ __launch_bounds__(256) void k_prep(
    const float* __restrict__ c2w,
    const float* __restrict__ wq, const float* __restrict__ wk,
    const float* __restrict__ wv,
    const float* __restrict__ w1f, const float* __restrict__ w2f,
    const float* __restrict__ c1w, const float* __restrict__ c1b,
    const float* __restrict__ g1,  const float* __restrict__ bb1,
    __bf16* __restrict__ w2bf,  __bf16* __restrict__ wallbf,
    __bf16* __restrict__ w1fbf, __bf16* __restrict__ w2fbf,
    float* __restrict__ peb, float* __restrict__ w1A, float* __restrict__ b1A)
{
    const int bid = blockIdx.x;
    const int t = threadIdx.x;
    if (bid < 1024) {                       // w2: 1M elems
        int i = (bid * 256 + t) * 4;
        float4 v = *(const float4*)&c2w[i];
        union { __bf16 h[4]; float2 f2; } u;
        u.h[0] = (__bf16)v.x; u.h[1] = (__bf16)v.y;
        u.h[2] = (__bf16)v.z; u.h[3] = (__bf16)v.w;
        *(float2*)&w2bf[i] = u.f2;
    } else if (bid < 1072) {                // wq|wk|wv: 3*16384, wq pre-scaled
        int e = ((bid - 1024) * 256 + t) * 4;
        int sel = e >> 14, r = e & 16383;
        const float* src = (sel == 0) ? wq : ((sel == 1) ? wk : wv);
        float sc = (sel == 0) ? QSCALE : 1.0f;
        float4 v = *(const float4*)&src[r];
        union { __bf16 h[4]; float2 f2; } u;
        u.h[0] = (__bf16)(v.x * sc); u.h[1] = (__bf16)(v.y * sc);
        u.h[2] = (__bf16)(v.z * sc); u.h[3] = (__bf16)(v.w * sc);
        *(float2*)&wallbf[e] = u.f2;
    } else if (bid < 1136) {                // w1f: 65536
        int e = ((bid - 1072) * 256 + t) * 4;
        float4 v = *(const float4*)&w1f[e];
        union { __bf16 h[4]; float2 f2; } u;
        u.h[0] = (__bf16)v.x; u.h[1] = (__bf16)v.y;
        u.h[2] = (__bf16)v.z; u.h[3] = (__bf16)v.w;
        *(float2*)&w1fbf[e] = u.f2;
    } else if (bid < 1200) {                // w2f: 65536
        int e = ((bid - 1136) * 256 + t) * 4;
        float4 v = *(const float4*)&w2f[e];
        union { __bf16 h[4]; float2 f2; } u;
        u.h[0] = (__bf16)v.x; u.h[1] = (__bf16)v.y;
        u.h[2] = (__bf16)v.z; u.h[3] = (__bf16)v.w;
        *(float2*)&w2fbf[e] = u.f2;
    } else if (bid < 1456) {                // PE table: 65536 (l, j) pairs
        int p = (bid - 1200) * 256 + t;
        int l = p >> 6, jj = p & 63;
        float ang = (float)l * expf(-0.14391156831212787f * (float)jj) * 0.125f;
        peb[l * 128 + jj * 2]     = sinf(ang);
        peb[l * 128 + jj * 2 + 1] = cosf(ang);
    } else {                                // fold BN1 into conv1 weights
        for (int o = t; o < DF; o += 256) {
            float A = g1[o] * INVS;
            #pragma unroll
            for (int tp = 0; tp < 7; tp++) w1A[o * 8 + tp] = c1w[o * 7 + tp] * A;
            w1A[o * 8 + 7] = 0.0f;
            b1A[o] = fmaf(c1b[o], A, bb1[o]);
        }
    }
}

// ---------- fused conv1+BN1+GELU -> bf16 MFMA conv2 GEMM -> BN2+GELU -> xsrc ----------
// 512 threads (8 waves), 32l x 128d tile, 32 chunks of 16 o, grid (32,16): 2 blocks/CU
__global__ __launch_bounds__(512, 4) void k_conv(
    const float* __restrict__ x,
    const float* __restrict__ w1A, const float* __restrict__ b1A,
    const __bf16* __restrict__ w2bf,
    const float* __restrict__ c2b, const float* __restrict__ g2,
    const float* __restrict__ bb2,
    float* __restrict__ xsrc)
{
    const int lt = blockIdx.x;      // 32 tiles of 32 l
    const int b  = blockIdx.y;      // 16
    const int t  = threadIdx.x;
    const int l0 = lt * 32;

    __shared__ float xs[CIN][40];
    __shared__ __align__(16) __bf16 Ab[2][32 * 256];

    for (int idx = t; idx < CIN * 38; idx += 512) {
        int c = idx / 38, i = idx % 38;
        int l = l0 - 3 + i;
        xs[c][i] = (l >= 0 && l < LL) ? x[(b * CIN + c) * LL + l] : 0.0f;
    }
    __syncthreads();

    const int lane = t & 63;
    const int wv   = t >> 6;                         // 0..7
    const int ogu  = __builtin_amdgcn_readfirstlane(wv); // wave-uniform o-subgroup
    const int cp   = lane & 7;
    const int lqi  = lane >> 3;                      // 0..7
    const int c0   = cp * 2;
    const int lq   = lqi * 4;

    float xw[2][10];
    #pragma unroll
    for (int j = 0; j < 10; j++) {
        xw[0][j] = xs[c0][lq + j];
        xw[1][j] = xs[c0 + 1][lq + j];
    }

    const int l15 = lane & 15, kg = lane >> 4;

    f32x4 acc[2];
    acc[0] = (f32x4){0.f, 0.f, 0.f, 0.f};
    acc[1] = (f32x4){0.f, 0.f, 0.f, 0.f};

    bf16x8 breg[8];

#define BLOAD(CH) do { \
    _Pragma("unroll") \
    for (int kk = 0; kk < 8; kk++) \
        breg[kk] = *(const bf16x8*)&w2bf[ \
            (size_t)(wv * 16 + l15) * 8192 + (size_t)(CH) * 256 + kk * 32 + kg * 8]; \
} while (0)

#define CONV_CHUNK(BUF, CH) do { \
    _Pragma("unroll") \
    for (int j = 0; j < 2; j++) { \
        int o = (CH) * 16 + ogu * 2 + j; \
        f32x4 wA = *(const f32x4*)&w1A[o * 8]; \
        f32x4 wB = *(const f32x4*)&w1A[o * 8 + 4]; \
        float bias = b1A[o]; \
        int kcol = (ogu * 2 + j) * 16 + c0; \
        _Pragma("unroll") \
        for (int dl = 0; dl < 4; dl++) { \
            float h2[2]; \
            _Pragma("unroll") \
            for (int ci = 0; ci < 2; ci++) { \
                float s = fmaf(xw[ci][dl], wA[0], bias); \
                s = fmaf(xw[ci][dl + 1], wA[1], s); \
                s = fmaf(xw[ci][dl + 2], wA[2], s); \
                s = fmaf(xw[ci][dl + 3], wA[3], s); \
                s = fmaf(xw[ci][dl + 4], wB[0], s); \
                s = fmaf(xw[ci][dl + 5], wB[1], s); \
                s = fmaf(xw[ci][dl + 6], wB[2], s); \
                h2[ci] = gelu_t(s); \
            } \
            int l = lq + dl; \
            *(unsigned*)&Ab[BUF][l * 256 + (kcol ^ (SWZ(l) << 3))] = pkbf(h2[0], h2[1]); \
        } \
    } \
} while (0)

#define MFMA_CHUNK(BUF) do { \
    _Pragma("unroll") \
    for (int kk = 0; kk < 8; kk++) { \
        int kb = kk * 32 + kg * 8; \
        _Pragma("unroll") \
        for (int mf = 0; mf < 2; mf++) { \
            int r = mf * 16 + l15; \
            bf16x8 af = *(const bf16x8*)&Ab[BUF][r * 256 + (kb ^ (SWZ(r) << 3))]; \
            acc[mf] = __builtin_amdgcn_mfma_f32_16x16x32_bf16(af, breg[kk], acc[mf], 0, 0, 0); \
        } \
    } \
} while (0)

    BLOAD(0);
    CONV_CHUNK(0, 0);
    __syncthreads();

    for (int ic = 0; ic < 30; ic += 2) {
        MFMA_CHUNK(0);
        BLOAD(ic + 1);
        CONV_CHUNK(1, ic + 1);
        __syncthreads();

        MFMA_CHUNK(1);
        BLOAD(ic + 2);
        CONV_CHUNK(0, ic + 2);
        __syncthreads();
    }
    MFMA_CHUNK(0);          // chunk 30
    BLOAD(31);
    CONV_CHUNK(1, 31);
    __syncthreads();
    MFMA_CHUNK(1);          // chunk 31

    // epilogue: BN2 + GELU  (C: col=lane&15 -> d-frag, row=(lane>>4)*4+r -> l)
    {
        int d = wv * 16 + l15;
        float A2 = g2[d] * INVS;
        float B2 = fmaf(c2b[d], A2, bb2[d]);
        #pragma unroll
        for (int mf = 0; mf < 2; mf++) {
            #pragma unroll
            for (int r = 0; r < 4; r++) {
                int l = l0 + mf * 16 + kg * 4 + r;
                xsrc[((size_t)b * LL + l) * DD + d] = gelu_t(fmaf(acc[mf][r], A2, B2));
            }
        }
    }
#undef BLOAD
#undef CONV_CHUNK
#undef MFMA_CHUNK
}

// ---------- qkv via MFMA: x_pos = xsrc + PE (bf16), out = x_pos @ W^T ----------
// 384 threads (6 waves): wave w covers 64 outputs of [q|k|v] (wq pre-scaled)
__global__ __launch_bounds__(384) void k_qkv(
    const float* __restrict__ xsrc, const float* __restrict__ peb,
    const __bf16* __restrict__ wallbf,
    __bf16* __restrict__ qo, __bf16* __restrict__ ko, __bf16* __restrict__ vo)
{
    const int lt = blockIdx.x, b = blockIdx.y;
    const int t = threadIdx.x;
    const int l0 = lt * 64;

    __shared__ __align__(16) __bf16 Xp[64 * 128];

    for (int e = t; e < 2048; e += 384) {
        int l = e >> 5, d0 = (e & 31) * 4;
        float4 xv = *(const float4*)&xsrc[((size_t)b * LL + l0 + l) * DD + d0];
        float4 pv = *(const float4*)&peb[(size_t)(l0 + l) * DD + d0];
        union { __bf16 h[4]; float2 f2; } u;
        u.h[0] = (__bf16)(xv.x + pv.x); u.h[1] = (__bf16)(xv.y + pv.y);
        u.h[2] = (__bf16)(xv.z + pv.z); u.h[3] = (__bf16)(xv.w + pv.w);
        *(float2*)&Xp[l * 128 + (d0 ^ (SWZ(l) << 3))] = u.f2;
    }
    __syncthreads();

    const int w = t >> 6, lane = t & 63;
    const int l15 = lane & 15, kg = lane >> 4;
    const int wsel = w >> 1, hb = w & 1;

    bf16x8 breg[16];
    #pragma unroll
    for (int nf = 0; nf < 4; nf++)
        #pragma unroll
        for (int kk = 0; kk < 4; kk++)
            breg[nf * 4 + kk] = *(const bf16x8*)&wallbf[
                (size_t)wsel * 16384 + (size_t)(hb * 64 + nf * 16 + l15) * 128 + kk * 32 + kg * 8];

    f32x4 acc[4][4];
    #pragma unroll
    for (int mf = 0; mf < 4; mf++)
        #pragma unroll
        for (int nf = 0; nf < 4; nf++) acc[mf][nf] = (f32x4){0.f, 0.f, 0.f, 0.f};

    #pragma unroll
    for (int kk = 0; kk < 4; kk++) {
        int kb = kk * 32 + kg * 8;
        bf16x8 af[4];
        #pragma unroll
        for (int mf = 0; mf < 4; mf++) {
            int r = mf * 16 + l15;
            af[mf] = *(const bf16x8*)&Xp[r * 128 + (kb ^ (SWZ(r) << 3))];
        }
        #pragma unroll
        for (int mf = 0; mf < 4; mf++)
            #pragma unroll
            for (int nf = 0; nf < 4; nf++)
                acc[mf][nf] = __builtin_amdgcn_mfma_f32_16x16x32_bf16(
                    af[mf], breg[nf * 4 + kk], acc[mf][nf], 0, 0, 0);
    }

    __bf16* op = (wsel == 0) ? qo : ((wsel == 1) ? ko : vo);
    #pragma unroll
    for (int mf = 0; mf < 4; mf++) {
        #pragma unroll
        for (int nf = 0; nf < 4; nf++) {
            int h = hb * 4 + nf;
            #pragma unroll
            for (int r = 0; r < 4; r++) {
                int l = l0 + mf * 16 + kg * 4 + r;
                op[(((size_t)b * NHH + h) * LL + l) * DHH + l15] = (__bf16)acc[mf][nf][r];
            }
        }
    }
}

// ---------- attention via MFMA: softmax(QK^T*s)@V + relbias@V  (flash) ----------
__global__ __launch_bounds__(256) void k_attn(
    const __bf16* __restrict__ q, const __bf16* __restrict__ k,
    const __bf16* __restrict__ v, const float* __restrict__ rel,
    float* __restrict__ out)
{
    const int bh = blockIdx.x;           // 128
    const int qt = blockIdx.y;           // 8 tiles of 128 q
    const int h  = bh & 7;
    const int t  = threadIdx.x;
    const int w  = t >> 6, lane = t & 63;
    const int g  = lane >> 4, qi = lane & 15;
    const int xq = (qi & 7) << 3;
    const int qbase = qt * 128 + w * 32;

    __shared__ __align__(16) __bf16 lds[16384];
    __bf16* Vl = lds;                    // 4096
    __bf16* Pw = lds + 4096 + w * 2048;  // per-wave 2048
    __bf16* R0 = lds + 12288;            // 2048
    __bf16* R1 = lds + 14336;            // 2048

    for (int i = t; i < 2048; i += 256) {
        R0[i] = (__bf16)((i <= 2046) ? rel[(size_t)(2046 - i) * NHH + h] : 0.0f);
        R1[i] = (__bf16)((i <= 2045) ? rel[(size_t)(2045 - i) * NHH + h] : 0.0f);
    }

    bf16x8 qf[2];
    {
        union { unsigned u[4]; bf16x8 v8; } uz;
        uz.u[0] = uz.u[1] = uz.u[2] = uz.u[3] = 0u;
        #pragma unroll
        for (int n = 0; n < 2; n++) {
            qf[n] = uz.v8;
            if (g < 2)
                qf[n] = *(const bf16x8*)&q[((size_t)bh * LL + qbase + n * 16 + qi) * DHH + g * 8];
        }
    }

    f32x4 accp[2], accb[2];
    #pragma unroll
    for (int n = 0; n < 2; n++) {
        accp[n] = (f32x4){0.f, 0.f, 0.f, 0.f};
        accb[n] = (f32x4){0.f, 0.f, 0.f, 0.f};
    }
    float mrun[2] = {-INFINITY, -INFINITY};
    float lrun[2] = {0.f, 0.f};

    const f32x4 zero4 = (f32x4){0.f, 0.f, 0.f, 0.f};

#define PROC_N(Sn, n) do { \
    float mx = Sn[0][0]; \
    _Pragma("unroll") \
    for (int f = 0; f < 8; f++) { \
        _Pragma("unroll") \
        for (int r = 0; r < 4; r++) if (f || r) mx = fmaxf(mx, Sn[f][r]); } \
    mx = fmaxf(mx, __shfl_xor(mx, 16, 64)); \
    mx = fmaxf(mx, __shfl_xor(mx, 32, 64)); \
    float mnew = fmaxf(mrun[n], mx); \
    float sf = __expf(mrun[n] - mnew); \
    mrun[n] = mnew; \
    lrun[n] *= sf; \
    accp[n][0] *= sf; accp[n][1] *= sf; accp[n][2] *= sf; accp[n][3] *= sf; \
    float ls = 0.f; \
    _Pragma("unroll") \
    for (int f = 0; f < 8; f++) { \
        float p0 = __expf(Sn[f][0] - mnew), p1 = __expf(Sn[f][1] - mnew); \
        float p2 = __expf(Sn[f][2] - mnew), p3 = __expf(Sn[f][3] - mnew); \
        ls += (p0 + p1) + (p2 + p3); \
        unsigned* pp = (unsigned*)(Pw + (qi * 128 + ((f * 16 + g * 4) ^ xq))); \
        pp[0] = pkbf(p0, p1); pp[1] = pkbf(p2, p3); \
    } \
    ls += __shfl_xor(ls, 16, 64); ls += __shfl_xor(ls, 32, 64); \
    lrun[n] += ls; \
    int qoff = 1023 - (qbase + (n) * 16 + qi) + k0; \
    _Pragma("unroll") \
    for (int c = 0; c < 4; c++) { \
        bf16x8 vf = *(const bf16x8*)&Vbuf[qi * 128 + ((c * 32 + g * 8) ^ xq)]; \
        bf16x8 pf = *(const bf16x8*)&Pw[qi * 128 + ((c * 32 + g * 8) ^ xq)]; \
        int idx = qoff + c * 32 + 8 * g; \
        const unsigned* tb = (const unsigned*)((idx & 1) ? R1 : R0); \
        unsigned s_ = (unsigned)idx >> 1; \
        union { unsigned u[4]; bf16x8 v8; } bu; \
        bu.u[0] = tb[s_]; bu.u[1] = tb[s_ + 1]; \
        bu.u[2] = tb[s_ + 2]; bu.u[3] = tb[s_ + 3]; \
        accp[n] = __builtin_amdgcn_mfma_f32_16x16x32_bf16(vf, pf, accp[n], 0, 0, 0); \
        accb[n] = __builtin_amdgcn_mfma_f32_16x16x32_bf16(vf, bu.v8, accb[n], 0, 0, 0); \
    } \
} while (0)

    for (int kt = 0; kt < 8; kt++) {
        const int k0 = kt * 128;
        {
            int kr = t >> 1, d0 = (t & 1) * 8;
            bf16x8 b8 = *(const bf16x8*)&v[((size_t)bh * LL + k0 + kr) * DHH + d0];
            __bf16* dst = Vl + (kt & 1) * 2048;
            #pragma unroll
            for (int i = 0; i < 8; i++) {
                int d = d0 + i;
                dst[d * 128 + (kr ^ ((d & 7) << 3))] = b8[i];
            }
        }
        __syncthreads();
        const __bf16* Vbuf = Vl + (kt & 1) * 2048;

        f32x4 S0[8], S1[8];
        #pragma unroll
        for (int f = 0; f < 8; f++) {
            bf16x8 kf = *(const bf16x8*)&k[((size_t)bh * LL + k0 + f * 16 + qi) * DHH + (g & 1) * 8];
            S0[f] = __builtin_amdgcn_mfma_f32_16x16x32_bf16(kf, qf[0], zero4, 0, 0, 0);
            S1[f] = __builtin_amdgcn_mfma_f32_16x16x32_bf16(kf, qf[1], zero4, 0, 0, 0);
        }

        PROC_N(S0, 0);
        PROC_N(S1, 1);
    }
#undef PROC_N

    #pragma unroll
    for (int n = 0; n < 2; n++) {
        float inv = 1.0f / lrun[n];
        float4 o;
        o.x = accp[n][0] * inv + accb[n][0];
        o.y = accp[n][1] * inv + accb[n][1];
        o.z = accp[n][2] * inv + accb[n][2];
        o.w = accp[n][3] * inv + accb[n][3];
        *(float4*)&out[((size_t)bh * LL + qbase + n * 16 + qi) * DHH + g * 4] = o;
    }
}

// ---------- LN(attn_out) ; att = LN(x_src + .) ----------
__global__ __launch_bounds__(256) void k_ln(
    const float* __restrict__ ao,  const float* __restrict__ xsrc,
    const float* __restrict__ lag, const float* __restrict__ lab,
    const float* __restrict__ l1g, const float* __restrict__ l1b,
    float* __restrict__ att)
{
    const int lt = blockIdx.x, b = blockIdx.y;
    const int t = threadIdx.x;
    const int l0 = lt * 64;
    __shared__ float tile[64][132];

    #pragma unroll
    for (int u = 0; u < 4; u++) {
        int cid = u * 256 + t;
        int hh = cid >> 7, rem = cid & 127;
        int l = rem >> 1, dh0 = (rem & 1) * 8;
        const float* src = &ao[(((size_t)b * NHH + hh) * LL + l0 + l) * DHH + dh0];
        float4 a0 = *(const float4*)src;
        float4 a1 = *(const float4*)(src + 4);
        *(float4*)&tile[l][hh * 16 + dh0]     = a0;
        *(float4*)&tile[l][hh * 16 + dh0 + 4] = a1;
    }
    __syncthreads();

    const int wid = t >> 6, lane = t & 63;
    float2 ga  = *(const float2*)&lag[lane * 2];
    float2 ba  = *(const float2*)&lab[lane * 2];
    float2 g1v = *(const float2*)&l1g[lane * 2];
    float2 b1v = *(const float2*)&l1b[lane * 2];

    for (int rr = 0; rr < 16; rr++) {
        int r = wid * 16 + rr;
        float2 vv = *(const float2*)&tile[r][lane * 2];
        float s = vv.x + vv.y, s2 = vv.x * vv.x + vv.y * vv.y;
        #pragma unroll
        for (int m = 1; m < 64; m <<= 1) { s += __shfl_xor(s, m, 64); s2 += __shfl_xor(s2, m, 64); }
        float mu = s * (1.f / 128.f);
        float var = s2 * (1.f / 128.f) - mu * mu;
        float rs = rsqrtf(var + 1e-5f);
        float o0 = (vv.x - mu) * rs * ga.x + ba.x;
        float o1 = (vv.y - mu) * rs * ga.y + ba.y;
        float2 xv = *(const float2*)&xsrc[((size_t)b * LL + l0 + r) * DD + lane * 2];
        float t0 = xv.x + o0, t1 = xv.y + o1;
        s = t0 + t1; s2 = t0 * t0 + t1 * t1;
        #pragma unroll
        for (int m = 1; m < 64; m <<= 1) { s += __shfl_xor(s, m, 64); s2 += __shfl_xor(s2, m, 64); }
        mu = s * (1.f / 128.f);
        var = s2 * (1.f / 128.f) - mu * mu;
        rs = rsqrtf(var + 1e-5f);
        float a0 = (t0 - mu) * rs * g1v.x + b1v.x;
        float a1 = (t1 - mu) * rs * g1v.y + b1v.y;
        float2 o = {a0, a1};
        *(float2*)&att[((size_t)b * LL + l0 + r) * DD + lane * 2] = o;
    }
}

// ---------- ff1 = relu(att @ w1^T + b1) -> bf16, MFMA ----------
__global__ __launch_bounds__(512) void k_ff1(
    const float* __restrict__ att, const __bf16* __restrict__ w1fbf,
    const float* __restrict__ b1f, __bf16* __restrict__ ff1b)
{
    const int lt = blockIdx.x, b = blockIdx.y;
    const int t = threadIdx.x;
    const int l0 = lt * 64;

    __shared__ __align__(16) __bf16 Ax[64 * 128];

    #pragma unroll
    for (int it = 0; it < 4; it++) {
        int e = it * 512 + t;
        int l = e >> 5, d0 = (e & 31) * 4;
        float4 xv = *(const float4*)&att[((size_t)b * LL + l0 + l) * DD + d0];
        union { __bf16 h[4]; float2 f2; } u;
        u.h[0] = (__bf16)xv.x; u.h[1] = (__bf16)xv.y;
        u.h[2] = (__bf16)xv.z; u.h[3] = (__bf16)xv.w;
        *(float2*)&Ax[l * 128 + (d0 ^ (SWZ(l) << 3))] = u.f2;
    }
    __syncthreads();

    const int w = t >> 6, lane = t & 63;
    const int l15 = lane & 15, kg = lane >> 4;

    bf16x8 breg[16];
    #pragma unroll
    for (int nf = 0; nf < 4; nf++)
        #pragma unroll
        for (int kk = 0; kk < 4; kk++)
            breg[nf * 4 + kk] = *(const bf16x8*)&w1fbf[
                (size_t)(w * 64 + nf * 16 + l15) * 128 + kk * 32 + kg * 8];

    f32x4 acc[4][4];
    #pragma unroll
    for (int mf = 0; mf < 4; mf++)
        #pragma unroll
        for (int nf = 0; nf < 4; nf++) acc[mf][nf] = (f32x4){0.f, 0.f, 0.f, 0.f};

    #pragma unroll
    for (int kk = 0; kk < 4; kk++) {
        int kb = kk * 32 + kg * 8;
        bf16x8 af[4];
        #pragma unroll
        for (int mf = 0; mf < 4; mf++) {
            int r = mf * 16 + l15;
            af[mf] = *(const bf16x8*)&Ax[r * 128 + (kb ^ (SWZ(r) << 3))];
        }
        #pragma unroll
        for (int mf = 0; mf < 4; mf++)
            #pragma unroll
            for (int nf = 0; nf < 4; nf++)
                acc[mf][nf] = __builtin_amdgcn_mfma_f32_16x16x32_bf16(
                    af[mf], breg[nf * 4 + kk], acc[mf][nf], 0, 0, 0);
    }

    #pragma unroll
    for (int nf = 0; nf < 4; nf++) {
        int n = w * 64 + nf * 16 + l15;
        float bias = b1f[n];
        #pragma unroll
        for (int mf = 0; mf < 4; mf++) {
            #pragma unroll
            for (int r = 0; r < 4; r++) {
                int l = l0 + mf * 16 + kg * 4 + r;
                float vv = fmaxf(acc[mf][nf][r] + bias, 0.0f);
                ff1b[((size_t)b * LL + l) * DF + n] = (__bf16)vv;
            }
        }
    }
}

// ---------- ff2 (MFMA, K=512) + bias + residual + LN2 + transpose-store ----------
__global__ __launch_bounds__(512) void k_ff2(
    const __bf16* __restrict__ ff1b, const __bf16* __restrict__ w2fbf,
    const float* __restrict__ b2f, const float* __restrict__ att,
    const float* __restrict__ l2g, const float* __restrict__ l2b,
    float* __restrict__ y)
{
    const int lt = blockIdx.x, b = blockIdx.y;
    const int t = threadIdx.x;
    const int l0 = lt * 64;

    __shared__ __align__(16) __bf16 Ax[64 * 512];   // 64KB; reused as yl after GEMM
    float* yl = (float*)Ax;                          // [64][132] overlay

    #pragma unroll
    for (int it = 0; it < 8; it++) {
        int g8 = it * 512 + t;                       // 4096 granules of 8
        int l = g8 >> 6, c8 = g8 & 63;
        bf16x8 v8 = *(const bf16x8*)&ff1b[((size_t)b * LL + l0 + l) * DF + c8 * 8];
        *(bf16x8*)&Ax[l * 512 + ((c8 * 8) ^ (SWZ(l) << 3))] = v8;
    }
    __syncthreads();

    const int w = t >> 6, lane = t & 63;
    const int l15 = lane & 15, kg = lane >> 4;
    const int d = w * 16 + l15;

    bf16x8 breg[16];
    #pragma unroll
    for (int kk = 0; kk < 16; kk++)
        breg[kk] = *(const bf16x8*)&w2fbf[(size_t)d * DF + kk * 32 + kg * 8];

    f32x4 acc[4];
    #pragma unroll
    for (int mf = 0; mf < 4; mf++) acc[mf] = (f32x4){0.f, 0.f, 0.f, 0.f};

    #pragma unroll
    for (int kk = 0; kk < 16; kk++) {
        int kb = kk * 32 + kg * 8;
        #pragma unroll
        for (int mf = 0; mf < 4; mf++) {
            int r = mf * 16 + l15;
            bf16x8 af = *(const bf16x8*)&Ax[r * 512 + (kb ^ (SWZ(r) << 3))];
            acc[mf] = __builtin_amdgcn_mfma_f32_16x16x32_bf16(af, breg[kk], acc[mf], 0, 0, 0);
        }
    }
    __syncthreads();   // Ax reads done; overlay as yl

    {
        float bias = b2f[d];
        #pragma unroll
        for (int mf = 0; mf < 4; mf++) {
            #pragma unroll
            for (int r = 0; r < 4; r++) {
                int l = mf * 16 + kg * 4 + r;
                float res = att[((size_t)b * LL + l0 + l) * DD + d];
                yl[l * 132 + d] = acc[mf][r] + bias + res;
            }
        }
    }
    __syncthreads();

    const int wid = t >> 6;
    float2 gv = *(const float2*)&l2g[lane * 2];
    float2 bv = *(const float2*)&l2b[lane * 2];
    for (int rr = 0; rr < 8; rr++) {
        int r = wid * 8 + rr;
        float2 vv = *(const float2*)&yl[r * 132 + lane * 2];
        float s = vv.x + vv.y, s2 = vv.x * vv.x + vv.y * vv.y;
        #pragma unroll
        for (int m = 1; m < 64; m <<= 1) { s += __shfl_xor(s, m, 64); s2 += __shfl_xor(s2, m, 64); }
        float mu = s * (1.f / 128.f);
        float var = s2 * (1.f / 128.f) - mu * mu;
        float rs = rsqrtf(var + 1e-5f);
        float o0 = (vv.x - mu) * rs * gv.x + bv.x;
        float o1 = (vv.y - mu) * rs * gv.y + bv.y;
        yl[r * 132 + lane * 2]     = o0;
        yl[r * 132 + lane * 2 + 1] = o1;
    }
    __syncthreads();

    {
        int dd = t >> 2, lh = (t & 3) * 16;
        #pragma unroll
        for (int i0 = 0; i0 < 16; i0 += 4) {
            float4 o = { yl[(lh + i0 + 0) * 132 + dd], yl[(lh + i0 + 1) * 132 + dd],
                         yl[(lh + i0 + 2) * 132 + dd], yl[(lh + i0 + 3) * 132 + dd] };
            *(float4*)&y[(size_t)b * DD * LL + (size_t)dd * LL + l0 + lh + i0] = o;
        }
    }
}

extern "C" void kernel_launch(void* const* d_in, const int* in_sizes, int n_in,
                              void* d_out, int out_size, void* d_ws, size_t ws_size,
                              hipStream_t stream)
{
    const float* x   = (const float*)d_in[0];
    const float* c1w = (const float*)d_in[1];
    const float* c1b = (const float*)d_in[2];
    const float* g1  = (const float*)d_in[3];
    const float* bb1 = (const float*)d_in[4];
    const float* c2w = (const float*)d_in[5];
    const float* c2b = (const float*)d_in[6];
    const float* g2  = (const float*)d_in[7];
    const float* bb2 = (const float*)d_in[8];
    const float* wq  = (const float*)d_in[9];
    const float* wk  = (const float*)d_in[10];
    const float* wv  = (const float*)d_in[11];
    const float* rel = (const float*)d_in[12];
    const float* lag = (const float*)d_in[13];
    const float* lab = (const float*)d_in[14];
    const float* l1g = (const float*)d_in[15];
    const float* l1b = (const float*)d_in[16];
    const float* l2g = (const float*)d_in[17];
    const float* l2b = (const float*)d_in[18];
    const float* w1f = (const float*)d_in[19];
    const float* b1f = (const float*)d_in[20];
    const float* w2f = (const float*)d_in[21];
    const float* b2f = (const float*)d_in[22];

    char* W = (char*)d_ws;
    const size_t MB = 1ull << 20;
    float*  xsrc   = (float*)(W);
    float*  abuf   = (float*)(W + 8 * MB);
    float*  attb   = (float*)(W + 16 * MB);
    __bf16* qbuf   = (__bf16*)(W + 24 * MB);
    __bf16* kbuf   = (__bf16*)(W + 28 * MB);
    __bf16* vbuf   = (__bf16*)(W + 32 * MB);
    __bf16* ff1b   = (__bf16*)(W + 36 * MB);
    __bf16* w2bf   = (__bf16*)(W + 52 * MB);
    __bf16* wallbf = (__bf16*)(W + 54 * MB);
    __bf16* w1fbf  = (__bf16*)(W + 54 * MB + 128 * 1024);
    __bf16* w2fbf  = (__bf16*)(W + 54 * MB + 256 * 1024);
    float*  peb    = (float*)(W + 54 * MB + 384 * 1024);
    float*  w1A    = (float*)(W + 54 * MB + 896 * 1024);
    float*  b1A    = (float*)(W + 54 * MB + 912 * 1024);

    k_prep<<<dim3(1457), dim3(256), 0, stream>>>(
        c2w, wq, wk, wv, w1f, w2f, c1w, c1b, g1, bb1,
        w2bf, wallbf, w1fbf, w2fbf, peb, w1A, b1A);
    k_conv<<<dim3(32, 16), dim3(512), 0, stream>>>(x, w1A, b1A, w2bf, c2b, g2, bb2, xsrc);
    k_qkv<<<dim3(16, 16), dim3(384), 0, stream>>>(xsrc, peb, wallbf, qbuf, kbuf, vbuf);
    k_attn<<<dim3(128, 8), dim3(256), 0, stream>>>(qbuf, kbuf, vbuf, rel, abuf);
    k_ln<<<dim3(16, 16), dim3(256), 0, stream>>>(abuf, xsrc, lag, lab, l1g, l1b, attb);
    k_ff1<<<dim3(16, 16), dim3(512), 0, stream>>>(attb, w1fbf, b1f, ff1b);
    k_ff2<<<dim3(16, 16), dim3(512), 0, stream>>>(ff1b, w2fbf, b2f, attb, l2g, l2b, (float*)d_out);
}